// Round 6
// baseline (134.910 us; speedup 1.0000x reference)
//
#include <hip/hip_runtime.h>
#include <hip/hip_bf16.h>
#include <math.h>

#define BB 2
#define CCH 64
#define HH 128
#define WWD 128
#define HWv (HH*WWD)
#define KK 9
#define PPB 16          // om pixels per block
#define KSTEP 18        // 576/32
#define OMK 1152        // om K = 128*9
#define OMROW 1160      // om samp row stride: 1152 + 8
#define OMKS 36         // 1152/32
#define OMC 32          // om_t NHWC channel stride (27 used)
// rconv (3x3 direct conv, 64-px strip)
#define RCOLS 66
#define CSTR 72         // padded channel-run stride (bf16): 64 + 8
// dconv (deform, 32-px)
#define DPX 32
#define DROW 584        // 576 + 8

typedef __attribute__((ext_vector_type(8))) short bf16x8;
typedef __attribute__((ext_vector_type(4))) float f32x4;

__device__ inline unsigned short f2bf(float f) {
  __hip_bfloat16 h = __float2bfloat16(f);
  return *reinterpret_cast<unsigned short*>(&h);
}
__device__ inline unsigned int f2bf2(float lo, float hi) {
  return ((unsigned int)f2bf(hi) << 16) | (unsigned int)f2bf(lo);
}

// ============ y NCHW -> NHWC: yt[b][hw][ci] ================================
__global__ __launch_bounds__(256) void transpose_yk(const float* __restrict__ y,
    float* __restrict__ yt) {
  __shared__ float tile[64][65];
  int blk = blockIdx.x;                 // B*HW/64 = 512
  int hwb = (blk * 64) & (HWv - 1);
  int b   = (blk * 64) >> 14;
  int tx = threadIdx.x & 63;
  int ty = threadIdx.x >> 6;            // 0..3
  const float* src = y + (size_t)b * CCH * HWv;
  #pragma unroll
  for (int i = 0; i < 16; i++) {
    int ci = i * 4 + ty;
    tile[ci][tx] = src[(size_t)ci * HWv + hwb + tx];
  }
  __syncthreads();
  float* dst = yt + ((size_t)b * HWv + hwb) * 64;
  #pragma unroll
  for (int i = 0; i < 16; i++) {
    int row = i * 4 + ty;
    dst[(size_t)row * 64 + tx] = tile[tx][row];
  }
}

// ============ weight pack, ci-major (1x1 conv) =============================
template <int NQ, int NS, int NCO, int NK>
__global__ __launch_bounds__(256) void pack_k(const float* __restrict__ w,
    unsigned short* __restrict__ pack) {
  int idx = blockIdx.x * 256 + threadIdx.x;   // NQ*NS*512
  if (idx >= NQ * NS * 512) return;
  int j = idx & 7;
  int l = (idx >> 3) & 63;
  int s = (idx >> 9) % NS;
  int q = idx / (NS * 512);
  int co = q * 16 + (l & 15);
  int k  = s * 32 + (l >> 4) * 8 + j;
  pack[idx] = (co < NCO && k < NK) ? f2bf(w[co * NK + k]) : (unsigned short)0;
}

// ============ weight pack, tap-major: k' = kk*CIN + ci =====================
template <int NQ, int NS, int NCO, int CIN>
__global__ __launch_bounds__(256) void pack_tap_k(const float* __restrict__ w,
    unsigned short* __restrict__ pack) {
  int idx = blockIdx.x * 256 + threadIdx.x;   // NQ*NS*512
  if (idx >= NQ * NS * 512) return;
  int j = idx & 7;
  int l = (idx >> 3) & 63;
  int s = (idx >> 9) % NS;
  int q = idx / (NS * 512);
  int co = q * 16 + (l & 15);
  int kp = s * 32 + (l >> 4) * 8 + j;
  int ci = kp % CIN;
  int kk = kp / CIN;
  pack[idx] = (co < NCO && kk < KK)
                  ? f2bf(w[(co * CIN + ci) * KK + kk]) : (unsigned short)0;
}

// ============ conv1x1 via MFMA: 64 px x 64 co, K=64, OUT = NHWC x0t ========
__global__ __launch_bounds__(256) void conv1x1_mfma_k(const float* __restrict__ x,
    const unsigned short* __restrict__ wpack, const float* __restrict__ b0,
    float* __restrict__ x0t) {
  #define S1ROW 72
  __shared__ __align__(16) unsigned short samp1[64 * S1ROW];  // 9216 B
  int tid = threadIdx.x;
  int lane = tid & 63, q = tid >> 6;
  int pixbase = blockIdx.x * 64;
  int hwb = pixbase & (HWv - 1);
  int b = pixbase >> 14;
  {
    unsigned short tmp[16];
    #pragma unroll
    for (int i = 0; i < 16; i++) {
      int ci = q * 16 + i;
      tmp[i] = f2bf(x[((size_t)b * CCH + ci) * HWv + hwb + lane]);
    }
    #pragma unroll
    for (int i = 0; i < 2; i++)
      *(bf16x8*)(samp1 + lane * S1ROW + q * 16 + i * 8) = *(bf16x8*)(tmp + i * 8);
  }
  __syncthreads();
  f32x4 acc[4] = {{0,0,0,0},{0,0,0,0},{0,0,0,0},{0,0,0,0}};
  int g = lane >> 4;
  const bf16x8* bp = (const bf16x8*)wpack + (size_t)(q * 2) * 64 + lane;
  #pragma unroll
  for (int s = 0; s < 2; s++) {
    bf16x8 bf = bp[(size_t)s * 64];
    #pragma unroll
    for (int t = 0; t < 4; t++) {
      bf16x8 a = *(const bf16x8*)(samp1 + (t * 16 + (lane & 15)) * S1ROW + g * 8 + s * 32);
      acc[t] = __builtin_amdgcn_mfma_f32_16x16x32_bf16(a, bf, acc[t], 0, 0, 0);
    }
  }
  int co = q * 16 + (lane & 15);
  float bv = b0[co];
  float* dst = x0t + ((size_t)b * HWv + hwb + g * 4) * 64 + co;
  #pragma unroll
  for (int t = 0; t < 4; t++)
    #pragma unroll
    for (int r = 0; r < 4; r++)
      dst[(size_t)(t * 16 + r) * 64] = acc[t][r] + bv;
}

// ==== om conv MFMA: 16 px x 32 co(27), K=1152 tap-major, NHWC in/out =======
__global__ __launch_bounds__(256) void om_mfma_k(const float* __restrict__ x0t,
    const float* __restrict__ yt, const unsigned short* __restrict__ wpack,
    const float* __restrict__ bias, float* __restrict__ om_t) {
  __shared__ __align__(16) unsigned short samp[PPB * OMROW];  // 37,120 B
  __shared__ __align__(16) float red[2 * 64 * 4];             // 2 KB
  unsigned int* samp32 = (unsigned int*)samp;
  int tid = threadIdx.x;
  int pixbase = blockIdx.x * PPB;
  int hwb = pixbase & (HWv - 1);
  int b = pixbase >> 14;
  int h = hwb >> 7, wb = hwb & 127;

  {
    int lane2 = tid & 31, hw8 = tid >> 5;
    const float* x0b = x0t + (size_t)b * HWv * 64 + lane2 * 2;
    const float* ytb = yt  + (size_t)b * HWv * 64 + lane2 * 2;
    #pragma unroll 4
    for (int i = 0; i < 36; i++) {
      int u = hw8 + 8 * i;                 // 0..287
      int half = u & 1;
      int t9 = u >> 1;                     // 0..143
      int kk = t9 % 9, pix = t9 / 9;
      int hh = h - 1 + kk / 3;
      int ww = wb + pix - 1 + kk % 3;
      float2 v = {0.f, 0.f};
      if ((unsigned)hh < HH && (unsigned)ww < WWD) {
        const float* sp = (half ? ytb : x0b) + (size_t)(hh * WWD + ww) * 64;
        v = *(const float2*)sp;
      }
      samp32[pix * (OMROW / 2) + kk * 64 + half * 32 + lane2] = f2bf2(v.x, v.y);
    }
  }
  __syncthreads();

  int lane = tid & 63, q = tid >> 6;
  int cohalf = q & 1, khalf = q >> 1;
  f32x4 acc = {0.f, 0.f, 0.f, 0.f};
  const unsigned short* arow = samp + (lane & 15) * OMROW + khalf * 576 + (lane >> 4) * 8;
  const bf16x8* bp = (const bf16x8*)wpack + (size_t)(cohalf * OMKS + khalf * 18) * 64 + lane;
  #pragma unroll
  for (int s = 0; s < 18; s++) {
    bf16x8 a = *(const bf16x8*)(arow + s * 32);
    bf16x8 bf = bp[(size_t)s * 64];
    acc = __builtin_amdgcn_mfma_f32_16x16x32_bf16(a, bf, acc, 0, 0, 0);
  }
  if (khalf) {
    *(f32x4*)(red + (cohalf * 64 + lane) * 4) = acc;
  }
  __syncthreads();
  if (!khalf) {
    f32x4 o = *(const f32x4*)(red + (cohalf * 64 + lane) * 4);
    int co = cohalf * 16 + (lane & 15);
    if (co < 27) {
      float bv = bias[co];
      int pixr = (lane >> 4) * 4;
      size_t ob_ = ((size_t)b * HWv + hwb + pixr) * OMC + co;
      om_t[ob_]           = acc[0] + o[0] + bv;
      om_t[ob_ + OMC]     = acc[1] + o[1] + bv;
      om_t[ob_ + 2 * OMC] = acc[2] + o[2] + bv;
      om_t[ob_ + 3 * OMC] = acc[3] + o[3] + bv;
    }
  }
}

// ============ deform conv: 32 px, 512 thr, im2col gather + MFMA ============
__global__ __launch_bounds__(512) void dconv_k(const float* __restrict__ yt,
    const float* __restrict__ omt, const float* __restrict__ x0t,
    const unsigned short* __restrict__ wpack, const float* __restrict__ b_dc,
    float* __restrict__ ob) {
  __shared__ __align__(16) unsigned short samp[DPX * DROW];   // 37,376 B
  __shared__ float prm[6][DPX * KK];                          //  6,912 B
  unsigned int* samp32 = (unsigned int*)samp;
  int tid = threadIdx.x;
  int pixbase = blockIdx.x * DPX;
  int hwb = pixbase & (HWv - 1);
  int b = pixbase >> 14;
  int h = hwb >> 7, wb = hwb & 127;

  if (tid < DPX * KK) {
    int pix = tid / KK, k = tid % KK;
    const float* omb = omt + ((size_t)b * HWv + hwb + pix) * OMC;
    float dy = omb[2 * k], dx = omb[2 * k + 1];
    float mk = 2.f / (1.f + expf(-omb[18 + k]));
    float ys = (float)(h - 1 + k / 3) + dy;
    float xs = (float)(wb + pix - 1 + k % 3) + dx;
    float y0f = floorf(ys), x0f = floorf(xs);
    float ty = ys - y0f, tx = xs - x0f;
    prm[0][tid] = y0f;
    prm[1][tid] = x0f;
    prm[2][tid] = (1.f - ty) * (1.f - tx) * mk;
    prm[3][tid] = (1.f - ty) * tx * mk;
    prm[4][tid] = ty * (1.f - tx) * mk;
    prm[5][tid] = ty * tx * mk;
  }
  __syncthreads();
  {
    int lane2 = tid & 31, hw16 = tid >> 5;    // 16 half-waves
    const float* ytb = yt + (size_t)b * HWv * 64 + lane2 * 2;
    #pragma unroll 3
    for (int i = 0; i < 18; i++) {
      int u = hw16 + 16 * i;                  // 0..287
      int k = u % 9, pix = u / 9;
      int e = pix * KK + k;
      int yi = (int)prm[0][e], xi = (int)prm[1][e];
      float w00 = prm[2][e], w01 = prm[3][e];
      float w10 = prm[4][e], w11 = prm[5][e];
      bool y0v = (unsigned)yi < HH, y1v = (unsigned)(yi + 1) < HH;
      bool x0v = (unsigned)xi < WWD, x1v = (unsigned)(xi + 1) < WWD;
      long base = (long)yi * WWD + xi;
      float vx = 0.f, vy = 0.f;
      if (y0v && x0v) { float2 s = *(const float2*)(ytb + base * 64);
        vx = fmaf(s.x, w00, vx); vy = fmaf(s.y, w00, vy); }
      if (y0v && x1v) { float2 s = *(const float2*)(ytb + (base + 1) * 64);
        vx = fmaf(s.x, w01, vx); vy = fmaf(s.y, w01, vy); }
      if (y1v && x0v) { float2 s = *(const float2*)(ytb + (base + WWD) * 64);
        vx = fmaf(s.x, w10, vx); vy = fmaf(s.y, w10, vy); }
      if (y1v && x1v) { float2 s = *(const float2*)(ytb + (base + WWD + 1) * 64);
        vx = fmaf(s.x, w11, vx); vy = fmaf(s.y, w11, vy); }
      samp32[pix * (DROW / 2) + k * 32 + lane2] = f2bf2(vx, vy);
    }
  }
  __syncthreads();

  int lane = tid & 63, q = tid >> 6;          // q 0..7
  int qq = q & 3, pxg = q >> 2;               // co-quadrant, px-group
  f32x4 acc = {0.f, 0.f, 0.f, 0.f};
  const unsigned short* arow = samp + (pxg * 16 + (lane & 15)) * DROW + (lane >> 4) * 8;
  const bf16x8* bp = (const bf16x8*)wpack + (size_t)(qq * KSTEP) * 64 + lane;
  #pragma unroll
  for (int s = 0; s < KSTEP; s++) {
    bf16x8 a = *(const bf16x8*)(arow + s * 32);
    bf16x8 bf = bp[(size_t)s * 64];
    acc = __builtin_amdgcn_mfma_f32_16x16x32_bf16(a, bf, acc, 0, 0, 0);
  }
  int co = qq * 16 + (lane & 15);
  int px = pxg * 16 + (lane >> 4) * 4;
  float bv = b_dc[co];
  size_t obase = ((size_t)b * HWv + hwb + px) * 64 + co;
  ob[obase]       = acc[0] + bv + x0t[obase];
  ob[obase + 64]  = acc[1] + bv + x0t[obase + 64];
  ob[obase + 128] = acc[2] + bv + x0t[obase + 128];
  ob[obase + 192] = acc[3] + bv + x0t[obase + 192];
}

// ====== 3x3 direct conv on 64-px strip, no im2col; 512 thr, NHWC in =======
// MODE 1: +leaky -> NHWC. MODE 2: +res(NHWC) -> NCHW (final, LDS transpose)
template <int MODE>
__global__ __launch_bounds__(512) void rconv_k(const float* __restrict__ in,
    const float* __restrict__ res, const unsigned short* __restrict__ wpack,
    const float* __restrict__ bias, float* __restrict__ outp) {
  __shared__ __align__(16) unsigned short samp[3 * RCOLS * CSTR];  // 28,512 B
  unsigned int* samp32 = (unsigned int*)samp;
  int tid = threadIdx.x;
  int pixbase = blockIdx.x * 64;
  int hwb = pixbase & (HWv - 1);
  int b = pixbase >> 14;
  int h = hwb >> 7, wb = hwb & 127;

  // stage raw tile [3 rows][66 cols][64 ch] (bf16, padded col stride 72)
  {
    int lane2 = tid & 31, hw16 = tid >> 5;
    const float* inb = in + (size_t)b * HWv * 64 + lane2 * 2;
    #pragma unroll
    for (int i = 0; i < 13; i++) {
      int u = hw16 + 16 * i;
      if (u < 198) {
        int r = u / 66, c = u % 66;
        int hh = h - 1 + r, ww = wb - 1 + c;
        float2 v = {0.f, 0.f};
        if ((unsigned)hh < HH && (unsigned)ww < WWD)
          v = *(const float2*)(inb + (size_t)(hh * WWD + ww) * 64);
        samp32[(r * 66 + c) * (CSTR / 2) + lane2] = f2bf2(v.x, v.y);
      }
    }
  }
  __syncthreads();

  int lane = tid & 63, q = tid >> 6;
  int copair = q & 1, pxg = q >> 1;           // co-half, px-group (0..3)
  f32x4 acc[2] = {{0,0,0,0},{0,0,0,0}};
  const bf16x8* bp = (const bf16x8*)wpack + (size_t)(copair * 2 * KSTEP) * 64 + lane;
  #pragma unroll
  for (int s = 0; s < KSTEP; s++) {
    int kk = s >> 1;
    int addr = ((kk / 3) * 66 + pxg * 16 + (lane & 15) + (kk % 3)) * CSTR
               + (s & 1) * 32 + (lane >> 4) * 8;
    bf16x8 a = *(const bf16x8*)(samp + addr);
    acc[0] = __builtin_amdgcn_mfma_f32_16x16x32_bf16(a, bp[(size_t)s * 64], acc[0], 0, 0, 0);
    acc[1] = __builtin_amdgcn_mfma_f32_16x16x32_bf16(a, bp[(size_t)(KSTEP + s) * 64], acc[1], 0, 0, 0);
  }

  int px = pxg * 16 + (lane >> 4) * 4;
  if (MODE == 1) {
    #pragma unroll
    for (int t = 0; t < 2; t++) {
      int co = copair * 32 + t * 16 + (lane & 15);
      float bv = bias[co];
      size_t obase = ((size_t)b * HWv + hwb + px) * 64 + co;
      #pragma unroll
      for (int r = 0; r < 4; r++) {
        float v = acc[t][r] + bv;
        outp[obase + (size_t)r * 64] = v >= 0.f ? v : 0.2f * v;
      }
    }
  } else {
    float* ot = (float*)samp;                 // [64 co][68] = 17,408 B
    __syncthreads();                          // tile reads done
    #pragma unroll
    for (int t = 0; t < 2; t++) {
      int co = copair * 32 + t * 16 + (lane & 15);
      float bv = bias[co];
      size_t rbase = ((size_t)b * HWv + hwb + px) * 64 + co;
      #pragma unroll
      for (int r = 0; r < 4; r++)
        ot[co * 68 + px + r] = acc[t][r] + bv + res[rbase + (size_t)r * 64];
    }
    __syncthreads();
    int co = tid >> 3, seg = tid & 7;         // 64 co x 8 px-segments
    const float4* src4 = (const float4*)(ot + co * 68 + seg * 8);
    float4 v0 = src4[0], v1 = src4[1];
    float* dst = outp + ((size_t)b * CCH + co) * HWv + hwb + seg * 8;
    *(float4*)dst = v0;
    *(float4*)(dst + 4) = v1;
  }
}

extern "C" void kernel_launch(void* const* d_in, const int* in_sizes, int n_in,
                              void* d_out, int out_size, void* d_ws, size_t ws_size,
                              hipStream_t stream) {
  const float* x    = (const float*)d_in[0];
  const float* y    = (const float*)d_in[1];
  const float* w0   = (const float*)d_in[2];
  const float* b0   = (const float*)d_in[3];
  const float* w_om = (const float*)d_in[4];
  const float* b_om = (const float*)d_in[5];
  const float* w_dc = (const float*)d_in[6];
  const float* b_dc = (const float*)d_in[7];
  const float* w1   = (const float*)d_in[8];
  const float* b1   = (const float*)d_in[9];
  const float* w2   = (const float*)d_in[10];
  const float* b2   = (const float*)d_in[11];
  float* out = (float*)d_out;

  const size_t NFULL = (size_t)BB * CCH * HWv;   // 2,097,152 floats
  const size_t NOMT  = (size_t)BB * HWv * OMC;   // 1,048,576
  const size_t NPACK = 4 * KSTEP * 64 * 8;       // 36,864 bf16
  const size_t NPACKOM = 2 * OMKS * 64 * 8;      // 36,864
  const size_t NPACK1  = 4 * 2 * 64 * 8;         //  4,096
  float* x0t = (float*)d_ws;
  float* omt = x0t + NFULL;
  float* ob  = omt + NOMT;
  float* z1  = ob + NFULL;
  float* yt  = z1;                               // alias: yt dead before z1 written
  unsigned short* pk_dc = (unsigned short*)(z1 + NFULL);
  unsigned short* pk_w1 = pk_dc + NPACK;
  unsigned short* pk_w2 = pk_w1 + NPACK;
  unsigned short* pk_om = pk_w2 + NPACK;
  unsigned short* pk_0  = pk_om + NPACKOM;

  pack_tap_k<4, KSTEP, 64, 64><<<(int)(NPACK / 256), 256, 0, stream>>>(w_dc, pk_dc);
  pack_tap_k<4, KSTEP, 64, 64><<<(int)(NPACK / 256), 256, 0, stream>>>(w1, pk_w1);
  pack_tap_k<4, KSTEP, 64, 64><<<(int)(NPACK / 256), 256, 0, stream>>>(w2, pk_w2);
  pack_tap_k<2, OMKS, 27, 128><<<(int)(NPACKOM / 256), 256, 0, stream>>>(w_om, pk_om);
  pack_k<4, 2, 64, 64><<<(int)(NPACK1 / 256), 256, 0, stream>>>(w0, pk_0);

  // 0. y -> NHWC (into z1's buffer; consumed before z1 is written)
  transpose_yk<<<(int)((size_t)BB * HWv / 64), 256, 0, stream>>>(y, yt);
  // 1. conv1x1 -> x0t (NHWC)
  conv1x1_mfma_k<<<(int)((size_t)BB * HWv / 64), 256, 0, stream>>>(x, pk_0, b0, x0t);
  // 2. offset/mask conv -> om_t (NHWC, stride 32)
  om_mfma_k<<<(int)((size_t)BB * HWv / PPB), 256, 0, stream>>>(x0t, yt, pk_om, b_om, omt);
  // 3. deformable conv + x0t residual -> ob (NHWC)
  dconv_k<<<(int)((size_t)BB * HWv / DPX), 512, 0, stream>>>(yt, omt, x0t, pk_dc, b_dc, ob);
  // 4. conv w1 + leaky -> z1 (NHWC)
  rconv_k<1><<<(int)((size_t)BB * HWv / 64), 512, 0, stream>>>(ob, nullptr, pk_w1, b1, z1);
  // 5. conv w2 + residual ob -> out (NCHW final)
  rconv_k<2><<<(int)((size_t)BB * HWv / 64), 512, 0, stream>>>(z1, ob, pk_w2, b2, out);
}

// Round 7
// 117.200 us; speedup vs baseline: 1.1511x; 1.1511x over previous
//
#include <hip/hip_runtime.h>
#include <hip/hip_bf16.h>
#include <math.h>

#define BB 2
#define CCH 64
#define HH 128
#define WWD 128
#define HWv (HH*WWD)
#define KK 9
#define PPB 16          // om pixels per block
#define KSTEP 18        // 576/32
#define OMK 1152        // om K = 128*9
#define OMROW 1160      // om samp row stride: 1152 + 8
#define OMKS 36         // 1152/32
#define OMC 32          // om_t NHWC channel stride (27 used)
// rconv (3x3 direct conv, 64-px strip)
#define RCOLS 66
#define CSTR 72         // padded channel-run stride (bf16): 64 + 8
// dconv (deform, 32-px)
#define DPX 32
#define DROW 584        // 576 + 8

typedef __attribute__((ext_vector_type(8))) short bf16x8;
typedef __attribute__((ext_vector_type(4))) float f32x4;
typedef unsigned short u16;
typedef unsigned int u32;

__device__ inline u16 f2bf(float f) {
  __hip_bfloat16 h = __float2bfloat16(f);
  return *reinterpret_cast<u16*>(&h);
}
__device__ inline u32 f2bf2(float lo, float hi) {
  return ((u32)f2bf(hi) << 16) | (u32)f2bf(lo);
}
__device__ inline float bfLO(u32 v) { return __uint_as_float(v << 16); }
__device__ inline float bfHI(u32 v) { return __uint_as_float(v & 0xffff0000u); }
__device__ inline float bf2f(u16 v) { return __uint_as_float((u32)v << 16); }

// ============ y NCHW -> NHWC bf16: yt[b][hw][ci] ===========================
__global__ __launch_bounds__(256) void transpose_yk(const float* __restrict__ y,
    u16* __restrict__ yt) {
  __shared__ float tile[64][65];
  int blk = blockIdx.x;                 // B*HW/64 = 512
  int hwb = (blk * 64) & (HWv - 1);
  int b   = (blk * 64) >> 14;
  int tx = threadIdx.x & 63;
  int ty = threadIdx.x >> 6;            // 0..3
  const float* src = y + (size_t)b * CCH * HWv;
  #pragma unroll
  for (int i = 0; i < 16; i++) {
    int ci = i * 4 + ty;
    tile[ci][tx] = src[(size_t)ci * HWv + hwb + tx];
  }
  __syncthreads();
  u32* dst32 = (u32*)(yt + ((size_t)b * HWv + hwb) * 64);
  int lane2 = threadIdx.x & 31, rr = threadIdx.x >> 5;  // 8 rows/pass
  #pragma unroll
  for (int i = 0; i < 8; i++) {
    int row = i * 8 + rr;
    dst32[row * 32 + lane2] = f2bf2(tile[2 * lane2][row], tile[2 * lane2 + 1][row]);
  }
}

// ============ weight pack, ci-major (1x1 conv) =============================
template <int NQ, int NS, int NCO, int NK>
__global__ __launch_bounds__(256) void pack_k(const float* __restrict__ w,
    u16* __restrict__ pack) {
  int idx = blockIdx.x * 256 + threadIdx.x;   // NQ*NS*512
  if (idx >= NQ * NS * 512) return;
  int j = idx & 7;
  int l = (idx >> 3) & 63;
  int s = (idx >> 9) % NS;
  int q = idx / (NS * 512);
  int co = q * 16 + (l & 15);
  int k  = s * 32 + (l >> 4) * 8 + j;
  pack[idx] = (co < NCO && k < NK) ? f2bf(w[co * NK + k]) : (u16)0;
}

// ============ weight pack, tap-major: k' = kk*CIN + ci =====================
template <int NQ, int NS, int NCO, int CIN>
__global__ __launch_bounds__(256) void pack_tap_k(const float* __restrict__ w,
    u16* __restrict__ pack) {
  int idx = blockIdx.x * 256 + threadIdx.x;   // NQ*NS*512
  if (idx >= NQ * NS * 512) return;
  int j = idx & 7;
  int l = (idx >> 3) & 63;
  int s = (idx >> 9) % NS;
  int q = idx / (NS * 512);
  int co = q * 16 + (l & 15);
  int kp = s * 32 + (l >> 4) * 8 + j;
  int ci = kp % CIN;
  int kk = kp / CIN;
  pack[idx] = (co < NCO && kk < KK)
                  ? f2bf(w[(co * CIN + ci) * KK + kk]) : (u16)0;
}

// ============ conv1x1 via MFMA: 64 px x 64 co, K=64, OUT = NHWC x0t (f32) ==
__global__ __launch_bounds__(256) void conv1x1_mfma_k(const float* __restrict__ x,
    const u16* __restrict__ wpack, const float* __restrict__ b0,
    float* __restrict__ x0t) {
  #define S1ROW 72
  __shared__ __align__(16) u16 samp1[64 * S1ROW];  // 9216 B
  int tid = threadIdx.x;
  int lane = tid & 63, q = tid >> 6;
  int pixbase = blockIdx.x * 64;
  int hwb = pixbase & (HWv - 1);
  int b = pixbase >> 14;
  {
    u16 tmp[16];
    #pragma unroll
    for (int i = 0; i < 16; i++) {
      int ci = q * 16 + i;
      tmp[i] = f2bf(x[((size_t)b * CCH + ci) * HWv + hwb + lane]);
    }
    #pragma unroll
    for (int i = 0; i < 2; i++)
      *(bf16x8*)(samp1 + lane * S1ROW + q * 16 + i * 8) = *(bf16x8*)(tmp + i * 8);
  }
  __syncthreads();
  f32x4 acc[4] = {{0,0,0,0},{0,0,0,0},{0,0,0,0},{0,0,0,0}};
  int g = lane >> 4;
  const bf16x8* bp = (const bf16x8*)wpack + (size_t)(q * 2) * 64 + lane;
  #pragma unroll
  for (int s = 0; s < 2; s++) {
    bf16x8 bf = bp[(size_t)s * 64];
    #pragma unroll
    for (int t = 0; t < 4; t++) {
      bf16x8 a = *(const bf16x8*)(samp1 + (t * 16 + (lane & 15)) * S1ROW + g * 8 + s * 32);
      acc[t] = __builtin_amdgcn_mfma_f32_16x16x32_bf16(a, bf, acc[t], 0, 0, 0);
    }
  }
  int co = q * 16 + (lane & 15);
  float bv = b0[co];
  float* dst = x0t + ((size_t)b * HWv + hwb + g * 4) * 64 + co;
  #pragma unroll
  for (int t = 0; t < 4; t++)
    #pragma unroll
    for (int r = 0; r < 4; r++)
      dst[(size_t)(t * 16 + r) * 64] = acc[t][r] + bv;
}

// ==== om conv MFMA: 16 px x 32 co(27), K=1152 tap-major ====================
__global__ __launch_bounds__(256) void om_mfma_k(const float* __restrict__ x0t,
    const u16* __restrict__ yt, const u16* __restrict__ wpack,
    const float* __restrict__ bias, float* __restrict__ om_t) {
  __shared__ __align__(16) u16 samp[PPB * OMROW];  // 37,120 B
  __shared__ __align__(16) float red[2 * 64 * 4];  // 2 KB
  u32* samp32 = (u32*)samp;
  int tid = threadIdx.x;
  int pixbase = blockIdx.x * PPB;
  int hwb = pixbase & (HWv - 1);
  int b = pixbase >> 14;
  int h = hwb >> 7, wb = hwb & 127;

  {
    int lane2 = tid & 31, hw8 = tid >> 5;
    const float* x0b = x0t + (size_t)b * HWv * 64 + lane2 * 2;
    const u32* ytb = (const u32*)yt + (size_t)b * HWv * 32 + lane2;
    #pragma unroll 4
    for (int i = 0; i < 36; i++) {
      int u = hw8 + 8 * i;                 // 0..287
      int half = u & 1;
      int t9 = u >> 1;                     // 0..143
      int kk = t9 % 9, pix = t9 / 9;
      int hh = h - 1 + kk / 3;
      int ww = wb + pix - 1 + kk % 3;
      bool ok = (unsigned)hh < HH && (unsigned)ww < WWD;
      u32 outv = 0;
      if (half) {
        if (ok) outv = ytb[(hh * WWD + ww) * 32];
      } else {
        float2 v = {0.f, 0.f};
        if (ok) v = *(const float2*)(x0b + (size_t)(hh * WWD + ww) * 64);
        outv = f2bf2(v.x, v.y);
      }
      samp32[pix * (OMROW / 2) + kk * 64 + half * 32 + lane2] = outv;
    }
  }
  __syncthreads();

  int lane = tid & 63, q = tid >> 6;
  int cohalf = q & 1, khalf = q >> 1;
  f32x4 acc = {0.f, 0.f, 0.f, 0.f};
  const u16* arow = samp + (lane & 15) * OMROW + khalf * 576 + (lane >> 4) * 8;
  const bf16x8* bp = (const bf16x8*)wpack + (size_t)(cohalf * OMKS + khalf * 18) * 64 + lane;
  #pragma unroll
  for (int s = 0; s < 18; s++) {
    bf16x8 a = *(const bf16x8*)(arow + s * 32);
    bf16x8 bf = bp[(size_t)s * 64];
    acc = __builtin_amdgcn_mfma_f32_16x16x32_bf16(a, bf, acc, 0, 0, 0);
  }
  if (khalf) {
    *(f32x4*)(red + (cohalf * 64 + lane) * 4) = acc;
  }
  __syncthreads();
  if (!khalf) {
    f32x4 o = *(const f32x4*)(red + (cohalf * 64 + lane) * 4);
    int co = cohalf * 16 + (lane & 15);
    if (co < 27) {
      float bv = bias[co];
      int pixr = (lane >> 4) * 4;
      size_t ob_ = ((size_t)b * HWv + hwb + pixr) * OMC + co;
      om_t[ob_]           = acc[0] + o[0] + bv;
      om_t[ob_ + OMC]     = acc[1] + o[1] + bv;
      om_t[ob_ + 2 * OMC] = acc[2] + o[2] + bv;
      om_t[ob_ + 3 * OMC] = acc[3] + o[3] + bv;
    }
  }
}

// ============ deform conv: branch-free gather + MFMA, bf16 yt/ob ===========
__global__ __launch_bounds__(512) void dconv_k(const u16* __restrict__ yt,
    const float* __restrict__ omt, const float* __restrict__ x0t,
    const u16* __restrict__ wpack, const float* __restrict__ b_dc,
    u16* __restrict__ ob) {
  __shared__ __align__(16) u16 samp[DPX * DROW];   // 37,376 B
  __shared__ __align__(16) int prm[DPX * KK][8];   //  9,216 B
  u32* samp32 = (u32*)samp;
  int tid = threadIdx.x;
  int pixbase = blockIdx.x * DPX;
  int hwb = pixbase & (HWv - 1);
  int b = pixbase >> 14;
  int h = hwb >> 7, wb = hwb & 127;

  if (tid < DPX * KK) {
    int pix = tid / KK, k = tid % KK;
    const float* omb = omt + ((size_t)b * HWv + hwb + pix) * OMC;
    float dy = omb[2 * k], dx = omb[2 * k + 1];
    float mk = 2.f / (1.f + expf(-omb[18 + k]));
    float ys = (float)(h - 1 + k / 3) + dy;
    float xs = (float)(wb + pix - 1 + k % 3) + dx;
    float y0f = floorf(ys), x0f = floorf(xs);
    float ty = ys - y0f, tx = xs - x0f;
    int yi = (int)y0f, xi = (int)x0f;
    bool y0v = (unsigned)yi < HH, y1v = (unsigned)(yi + 1) < HH;
    bool x0v = (unsigned)xi < WWD, x1v = (unsigned)(xi + 1) < WWD;
    float w00 = (1.f - ty) * (1.f - tx) * mk * ((y0v && x0v) ? 1.f : 0.f);
    float w01 = (1.f - ty) * tx * mk * ((y0v && x1v) ? 1.f : 0.f);
    float w10 = ty * (1.f - tx) * mk * ((y1v && x0v) ? 1.f : 0.f);
    float w11 = ty * tx * mk * ((y1v && x1v) ? 1.f : 0.f);
    int* p = prm[tid];
    // offsets in u32 units of NHWC bf16: row = 128*32, col = 32
    *(int4*)p = make_int4(min(max(yi, 0), HH - 1) * (WWD * 32),
                          min(max(yi + 1, 0), HH - 1) * (WWD * 32),
                          min(max(xi, 0), WWD - 1) * 32,
                          min(max(xi + 1, 0), WWD - 1) * 32);
    *(int4*)(p + 4) = make_int4(__float_as_int(w00), __float_as_int(w01),
                                __float_as_int(w10), __float_as_int(w11));
  }
  __syncthreads();
  {
    int lane2 = tid & 31, hw16 = tid >> 5;    // 16 half-waves
    const u32* ytb = (const u32*)yt + (size_t)b * HWv * 32 + lane2;
    #pragma unroll 9
    for (int i = 0; i < 18; i++) {
      int u = hw16 + 16 * i;                  // 0..287
      int k = u % 9, pix = u / 9;
      int4 pa = *(const int4*)prm[u];
      int4 pb = *(const int4*)(prm[u] + 4);
      u32 v00 = ytb[pa.x + pa.z];
      u32 v01 = ytb[pa.x + pa.w];
      u32 v10 = ytb[pa.y + pa.z];
      u32 v11 = ytb[pa.y + pa.w];
      float w00 = __int_as_float(pb.x), w01 = __int_as_float(pb.y);
      float w10 = __int_as_float(pb.z), w11 = __int_as_float(pb.w);
      float vx = fmaf(bfLO(v00), w00, fmaf(bfLO(v01), w01,
                 fmaf(bfLO(v10), w10, bfLO(v11) * w11)));
      float vy = fmaf(bfHI(v00), w00, fmaf(bfHI(v01), w01,
                 fmaf(bfHI(v10), w10, bfHI(v11) * w11)));
      samp32[pix * (DROW / 2) + k * 32 + lane2] = f2bf2(vx, vy);
    }
  }
  __syncthreads();

  int lane = tid & 63, q = tid >> 6;          // q 0..7
  int qq = q & 3, pxg = q >> 2;               // co-quadrant, px-group
  f32x4 acc = {0.f, 0.f, 0.f, 0.f};
  const u16* arow = samp + (pxg * 16 + (lane & 15)) * DROW + (lane >> 4) * 8;
  const bf16x8* bp = (const bf16x8*)wpack + (size_t)(qq * KSTEP) * 64 + lane;
  #pragma unroll
  for (int s = 0; s < KSTEP; s++) {
    bf16x8 a = *(const bf16x8*)(arow + s * 32);
    bf16x8 bf = bp[(size_t)s * 64];
    acc = __builtin_amdgcn_mfma_f32_16x16x32_bf16(a, bf, acc, 0, 0, 0);
  }
  int co = qq * 16 + (lane & 15);
  int px = pxg * 16 + (lane >> 4) * 4;
  float bv = b_dc[co];
  size_t obase = ((size_t)b * HWv + hwb + px) * 64 + co;
  #pragma unroll
  for (int r = 0; r < 4; r++)
    ob[obase + (size_t)r * 64] = f2bf(acc[r] + bv + x0t[obase + (size_t)r * 64]);
}

// ====== 3x3 direct conv, 64-px strip, bf16 NHWC in (pure-copy stage) ======
// MODE 1: +leaky -> z1 bf16 NHWC. MODE 2: +res(ob bf16) -> out f32 NCHW
template <int MODE>
__global__ __launch_bounds__(512) void rconv_k(const u16* __restrict__ in,
    const u16* __restrict__ res, const u16* __restrict__ wpack,
    const float* __restrict__ bias, void* __restrict__ outp) {
  __shared__ __align__(16) u16 samp[3 * RCOLS * CSTR];  // 28,512 B
  u32* samp32 = (u32*)samp;
  int tid = threadIdx.x;
  int pixbase = blockIdx.x * 64;
  int hwb = pixbase & (HWv - 1);
  int b = pixbase >> 14;
  int h = hwb >> 7, wb = hwb & 127;

  // stage raw tile [3 rows][66 cols][64 ch] bf16 — pure u32 copy
  {
    int lane2 = tid & 31, hw16 = tid >> 5;
    const u32* inb = (const u32*)in + (size_t)b * HWv * 32 + lane2;
    #pragma unroll
    for (int i = 0; i < 13; i++) {
      int u = hw16 + 16 * i;
      if (u < 198) {
        int r = u / 66, c = u % 66;
        int hh = h - 1 + r, ww = wb - 1 + c;
        u32 v = 0;
        if ((unsigned)hh < HH && (unsigned)ww < WWD)
          v = inb[(hh * WWD + ww) * 32];
        samp32[(r * 66 + c) * (CSTR / 2) + lane2] = v;
      }
    }
  }
  __syncthreads();

  int lane = tid & 63, q = tid >> 6;
  int copair = q & 1, pxg = q >> 1;           // co-half, px-group (0..3)
  f32x4 acc[2] = {{0,0,0,0},{0,0,0,0}};
  const bf16x8* bp = (const bf16x8*)wpack + (size_t)(copair * 2 * KSTEP) * 64 + lane;
  #pragma unroll
  for (int s = 0; s < KSTEP; s++) {
    int kk = s >> 1;
    int addr = ((kk / 3) * 66 + pxg * 16 + (lane & 15) + (kk % 3)) * CSTR
               + (s & 1) * 32 + (lane >> 4) * 8;
    bf16x8 a = *(const bf16x8*)(samp + addr);
    acc[0] = __builtin_amdgcn_mfma_f32_16x16x32_bf16(a, bp[(size_t)s * 64], acc[0], 0, 0, 0);
    acc[1] = __builtin_amdgcn_mfma_f32_16x16x32_bf16(a, bp[(size_t)(KSTEP + s) * 64], acc[1], 0, 0, 0);
  }

  int px = pxg * 16 + (lane >> 4) * 4;
  if (MODE == 1) {
    u16* outb = (u16*)outp;
    #pragma unroll
    for (int t = 0; t < 2; t++) {
      int co = copair * 32 + t * 16 + (lane & 15);
      float bv = bias[co];
      size_t obase = ((size_t)b * HWv + hwb + px) * 64 + co;
      #pragma unroll
      for (int r = 0; r < 4; r++) {
        float v = acc[t][r] + bv;
        outb[obase + (size_t)r * 64] = f2bf(v >= 0.f ? v : 0.2f * v);
      }
    }
  } else {
    float* outf = (float*)outp;
    float* ot = (float*)samp;                 // [64 co][68] = 17,408 B
    __syncthreads();                          // tile reads done
    #pragma unroll
    for (int t = 0; t < 2; t++) {
      int co = copair * 32 + t * 16 + (lane & 15);
      float bv = bias[co];
      size_t rbase = ((size_t)b * HWv + hwb + px) * 64 + co;
      #pragma unroll
      for (int r = 0; r < 4; r++)
        ot[co * 68 + px + r] = acc[t][r] + bv + bf2f(res[rbase + (size_t)r * 64]);
    }
    __syncthreads();
    int co = tid >> 3, seg = tid & 7;         // 64 co x 8 px-segments
    const float4* src4 = (const float4*)(ot + co * 68 + seg * 8);
    float4 v0 = src4[0], v1 = src4[1];
    float* dst = outf + ((size_t)b * CCH + co) * HWv + hwb + seg * 8;
    *(float4*)dst = v0;
    *(float4*)(dst + 4) = v1;
  }
}

extern "C" void kernel_launch(void* const* d_in, const int* in_sizes, int n_in,
                              void* d_out, int out_size, void* d_ws, size_t ws_size,
                              hipStream_t stream) {
  const float* x    = (const float*)d_in[0];
  const float* y    = (const float*)d_in[1];
  const float* w0   = (const float*)d_in[2];
  const float* b0   = (const float*)d_in[3];
  const float* w_om = (const float*)d_in[4];
  const float* b_om = (const float*)d_in[5];
  const float* w_dc = (const float*)d_in[6];
  const float* b_dc = (const float*)d_in[7];
  const float* w1   = (const float*)d_in[8];
  const float* b1   = (const float*)d_in[9];
  const float* w2   = (const float*)d_in[10];
  const float* b2   = (const float*)d_in[11];
  float* out = (float*)d_out;

  const size_t NFULL = (size_t)BB * CCH * HWv;   // 2,097,152
  const size_t NOMT  = (size_t)BB * HWv * OMC;   // 1,048,576
  const size_t NPACK = 4 * KSTEP * 64 * 8;       // 36,864 bf16
  const size_t NPACKOM = 2 * OMKS * 64 * 8;      // 36,864
  const size_t NPACK1  = 4 * 2 * 64 * 8;         //  4,096
  float* x0t = (float*)d_ws;                     // NFULL f32
  float* omt = x0t + NFULL;                      // NOMT f32
  u16* ob = (u16*)(omt + NOMT);                  // NFULL bf16
  u16* z1 = ob + NFULL;                          // NFULL bf16
  u16* yt = z1;                                  // alias: yt dead before z1 written
  u16* pk_dc = z1 + NFULL;
  u16* pk_w1 = pk_dc + NPACK;
  u16* pk_w2 = pk_w1 + NPACK;
  u16* pk_om = pk_w2 + NPACK;
  u16* pk_0  = pk_om + NPACKOM;

  pack_tap_k<4, KSTEP, 64, 64><<<(int)(NPACK / 256), 256, 0, stream>>>(w_dc, pk_dc);
  pack_tap_k<4, KSTEP, 64, 64><<<(int)(NPACK / 256), 256, 0, stream>>>(w1, pk_w1);
  pack_tap_k<4, KSTEP, 64, 64><<<(int)(NPACK / 256), 256, 0, stream>>>(w2, pk_w2);
  pack_tap_k<2, OMKS, 27, 128><<<(int)(NPACKOM / 256), 256, 0, stream>>>(w_om, pk_om);
  pack_k<4, 2, 64, 64><<<(int)(NPACK1 / 256), 256, 0, stream>>>(w0, pk_0);

  // 0. y -> NHWC bf16 (into z1's buffer; consumed before z1 is written)
  transpose_yk<<<(int)((size_t)BB * HWv / 64), 256, 0, stream>>>(y, yt);
  // 1. conv1x1 -> x0t (NHWC f32)
  conv1x1_mfma_k<<<(int)((size_t)BB * HWv / 64), 256, 0, stream>>>(x, pk_0, b0, x0t);
  // 2. offset/mask conv -> om_t (NHWC f32, stride 32)
  om_mfma_k<<<(int)((size_t)BB * HWv / PPB), 256, 0, stream>>>(x0t, yt, pk_om, b_om, omt);
  // 3. deformable conv + x0t residual -> ob (NHWC bf16)
  dconv_k<<<(int)((size_t)BB * HWv / DPX), 512, 0, stream>>>(yt, omt, x0t, pk_dc, b_dc, ob);
  // 4. conv w1 + leaky -> z1 (NHWC bf16)
  rconv_k<1><<<(int)((size_t)BB * HWv / 64), 512, 0, stream>>>(ob, nullptr, pk_w1, b1, z1);
  // 5. conv w2 + residual ob -> out (NCHW f32 final)
  rconv_k<2><<<(int)((size_t)BB * HWv / 64), 512, 0, stream>>>(z1, ob, pk_w2, b2, out);
}

// Round 8
// 83.058 us; speedup vs baseline: 1.6243x; 1.4111x over previous
//
#include <hip/hip_runtime.h>
#include <hip/hip_bf16.h>
#include <math.h>

#define BB 2
#define CCH 64
#define HH 128
#define WWD 128
#define HWv (HH*WWD)
#define KK 9
#define KSTEP 18        // 576/32
#define OMKS 36         // 1152/32
#define OMC 32          // om_t NHWC channel stride (27 used)
// rconv (3x3 direct conv, 64-px strip)
#define RCOLS 66
#define CSTR 72         // padded 64-ch run stride (bf16): 64 + 8
// om2 (3x3 direct conv, 128ch in, 64-px strip)
#define CSTR2 136       // padded 128-ch run stride (bf16): 128 + 8
// dconv (deform, 32-px)
#define DPX 32
#define DROW 584        // 576 + 8

typedef __attribute__((ext_vector_type(8))) short bf16x8;
typedef __attribute__((ext_vector_type(4))) float f32x4;
typedef unsigned short u16;
typedef unsigned int u32;

__device__ inline u16 f2bf(float f) {
  __hip_bfloat16 h = __float2bfloat16(f);
  return *reinterpret_cast<u16*>(&h);
}
__device__ inline u32 f2bf2(float lo, float hi) {
  return ((u32)f2bf(hi) << 16) | (u32)f2bf(lo);
}
__device__ inline float bfLO(u32 v) { return __uint_as_float(v << 16); }
__device__ inline float bfHI(u32 v) { return __uint_as_float(v & 0xffff0000u); }
__device__ inline float bf2f(u16 v) { return __uint_as_float((u32)v << 16); }

// ============ y NCHW -> NHWC bf16: yt[b][hw][ci] ===========================
__global__ __launch_bounds__(256) void transpose_yk(const float* __restrict__ y,
    u16* __restrict__ yt) {
  __shared__ float tile[64][65];
  int blk = blockIdx.x;                 // B*HW/64 = 512
  int hwb = (blk * 64) & (HWv - 1);
  int b   = (blk * 64) >> 14;
  int tx = threadIdx.x & 63;
  int ty = threadIdx.x >> 6;            // 0..3
  const float* src = y + (size_t)b * CCH * HWv;
  #pragma unroll
  for (int i = 0; i < 16; i++) {
    int ci = i * 4 + ty;
    tile[ci][tx] = src[(size_t)ci * HWv + hwb + tx];
  }
  __syncthreads();
  u32* dst32 = (u32*)(yt + ((size_t)b * HWv + hwb) * 64);
  int lane2 = threadIdx.x & 31, rr = threadIdx.x >> 5;  // 8 rows/pass
  #pragma unroll
  for (int i = 0; i < 8; i++) {
    int row = i * 8 + rr;
    dst32[row * 32 + lane2] = f2bf2(tile[2 * lane2][row], tile[2 * lane2 + 1][row]);
  }
}

// ============ weight pack, ci-major (1x1 conv) =============================
template <int NQ, int NS, int NCO, int NK>
__global__ __launch_bounds__(256) void pack_k(const float* __restrict__ w,
    u16* __restrict__ pack) {
  int idx = blockIdx.x * 256 + threadIdx.x;   // NQ*NS*512
  if (idx >= NQ * NS * 512) return;
  int j = idx & 7;
  int l = (idx >> 3) & 63;
  int s = (idx >> 9) % NS;
  int q = idx / (NS * 512);
  int co = q * 16 + (l & 15);
  int k  = s * 32 + (l >> 4) * 8 + j;
  pack[idx] = (co < NCO && k < NK) ? f2bf(w[co * NK + k]) : (u16)0;
}

// ============ weight pack, tap-major: k' = kk*CIN + ci =====================
template <int NQ, int NS, int NCO, int CIN>
__global__ __launch_bounds__(256) void pack_tap_k(const float* __restrict__ w,
    u16* __restrict__ pack) {
  int idx = blockIdx.x * 256 + threadIdx.x;   // NQ*NS*512
  if (idx >= NQ * NS * 512) return;
  int j = idx & 7;
  int l = (idx >> 3) & 63;
  int s = (idx >> 9) % NS;
  int q = idx / (NS * 512);
  int co = q * 16 + (l & 15);
  int kp = s * 32 + (l >> 4) * 8 + j;
  int ci = kp % CIN;
  int kk = kp / CIN;
  pack[idx] = (co < NCO && kk < KK)
                  ? f2bf(w[(co * CIN + ci) * KK + kk]) : (u16)0;
}

// ==== conv1x1 via MFMA: 64 px x 64 co, K=64, OUT = NHWC bf16 x0bf ==========
__global__ __launch_bounds__(256) void conv1x1_mfma_k(const float* __restrict__ x,
    const u16* __restrict__ wpack, const float* __restrict__ b0,
    u16* __restrict__ x0bf) {
  #define S1ROW 72
  __shared__ __align__(16) u16 samp1[64 * S1ROW];  // 9216 B
  int tid = threadIdx.x;
  int lane = tid & 63, q = tid >> 6;
  int pixbase = blockIdx.x * 64;
  int hwb = pixbase & (HWv - 1);
  int b = pixbase >> 14;
  {
    u16 tmp[16];
    #pragma unroll
    for (int i = 0; i < 16; i++) {
      int ci = q * 16 + i;
      tmp[i] = f2bf(x[((size_t)b * CCH + ci) * HWv + hwb + lane]);
    }
    #pragma unroll
    for (int i = 0; i < 2; i++)
      *(bf16x8*)(samp1 + lane * S1ROW + q * 16 + i * 8) = *(bf16x8*)(tmp + i * 8);
  }
  __syncthreads();
  f32x4 acc[4] = {{0,0,0,0},{0,0,0,0},{0,0,0,0},{0,0,0,0}};
  int g = lane >> 4;
  const bf16x8* bp = (const bf16x8*)wpack + (size_t)(q * 2) * 64 + lane;
  #pragma unroll
  for (int s = 0; s < 2; s++) {
    bf16x8 bf = bp[(size_t)s * 64];
    #pragma unroll
    for (int t = 0; t < 4; t++) {
      bf16x8 a = *(const bf16x8*)(samp1 + (t * 16 + (lane & 15)) * S1ROW + g * 8 + s * 32);
      acc[t] = __builtin_amdgcn_mfma_f32_16x16x32_bf16(a, bf, acc[t], 0, 0, 0);
    }
  }
  int co = q * 16 + (lane & 15);
  float bv = b0[co];
  u16* dst = x0bf + ((size_t)b * HWv + hwb + g * 4) * 64 + co;
  #pragma unroll
  for (int t = 0; t < 4; t++)
    #pragma unroll
    for (int r = 0; r < 4; r++)
      dst[(size_t)(t * 16 + r) * 64] = f2bf(acc[t][r] + bv);
}

// ==== om conv: 64-px strip, raw [3][66][128ch] tile, K=1152 tap-major ======
__global__ __launch_bounds__(512) void om2_k(const u16* __restrict__ x0bf,
    const u16* __restrict__ yt, const u16* __restrict__ wpack,
    const float* __restrict__ bias, float* __restrict__ om_t) {
  __shared__ __align__(16) u16 samp[3 * RCOLS * CSTR2];  // 53,856 B
  u32* samp32 = (u32*)samp;
  int tid = threadIdx.x;
  int pixbase = blockIdx.x * 64;
  int hwb = pixbase & (HWv - 1);
  int b = pixbase >> 14;
  int h = hwb >> 7, wb = hwb & 127;

  // stage raw tile: unit = (rc 0..197, half 0..1); pure u32 copy
  {
    int lane2 = tid & 31, hw16 = tid >> 5;
    const u32* x0b = (const u32*)x0bf + (size_t)b * HWv * 32 + lane2;
    const u32* ytb = (const u32*)yt + (size_t)b * HWv * 32 + lane2;
    #pragma unroll
    for (int i = 0; i < 25; i++) {
      int u = hw16 + 16 * i;
      if (u < 396) {
        int half = u & 1, rc = u >> 1;
        int r = rc / 66, c = rc % 66;
        int hh = h - 1 + r, ww = wb - 1 + c;
        u32 v = 0;
        if ((unsigned)hh < HH && (unsigned)ww < WWD)
          v = (half ? ytb : x0b)[(hh * WWD + ww) * 32];
        samp32[rc * (CSTR2 / 2) + half * 32 + lane2] = v;
      }
    }
  }
  __syncthreads();

  int lane = tid & 63, q = tid >> 6;
  int cohalf = q & 1, pxg = q >> 1;           // co-half (16), px-group (0..3)
  f32x4 acc = {0.f, 0.f, 0.f, 0.f};
  const bf16x8* bp = (const bf16x8*)wpack + (size_t)(cohalf * OMKS) * 64 + lane;
  #pragma unroll
  for (int s = 0; s < OMKS; s++) {
    int kk = s >> 2;                          // tap (4 ksteps per 128-ch tap)
    int addr = ((kk / 3) * 66 + pxg * 16 + (lane & 15) + (kk % 3)) * CSTR2
               + (s & 3) * 32 + (lane >> 4) * 8;
    bf16x8 a = *(const bf16x8*)(samp + addr);
    acc = __builtin_amdgcn_mfma_f32_16x16x32_bf16(a, bp[(size_t)s * 64], acc, 0, 0, 0);
  }
  int co = cohalf * 16 + (lane & 15);
  if (co < 27) {
    float bv = bias[co];
    int px = pxg * 16 + (lane >> 4) * 4;
    size_t ob_ = ((size_t)b * HWv + hwb + px) * OMC + co;
    #pragma unroll
    for (int r = 0; r < 4; r++)
      om_t[ob_ + (size_t)r * OMC] = acc[r] + bv;
  }
}

// ============ deform conv: branch-free gather + MFMA, bf16 yt/x0/ob ========
__global__ __launch_bounds__(512) void dconv_k(const u16* __restrict__ yt,
    const float* __restrict__ omt, const u16* __restrict__ x0bf,
    const u16* __restrict__ wpack, const float* __restrict__ b_dc,
    u16* __restrict__ ob) {
  __shared__ __align__(16) u16 samp[DPX * DROW];   // 37,376 B
  __shared__ __align__(16) int prm[DPX * KK][8];   //  9,216 B
  u32* samp32 = (u32*)samp;
  int tid = threadIdx.x;
  int pixbase = blockIdx.x * DPX;
  int hwb = pixbase & (HWv - 1);
  int b = pixbase >> 14;
  int h = hwb >> 7, wb = hwb & 127;

  if (tid < DPX * KK) {
    int pix = tid / KK, k = tid % KK;
    const float* omb = omt + ((size_t)b * HWv + hwb + pix) * OMC;
    float dy = omb[2 * k], dx = omb[2 * k + 1];
    float mk = 2.f / (1.f + expf(-omb[18 + k]));
    float ys = (float)(h - 1 + k / 3) + dy;
    float xs = (float)(wb + pix - 1 + k % 3) + dx;
    float y0f = floorf(ys), x0f = floorf(xs);
    float ty = ys - y0f, tx = xs - x0f;
    int yi = (int)y0f, xi = (int)x0f;
    bool y0v = (unsigned)yi < HH, y1v = (unsigned)(yi + 1) < HH;
    bool x0v = (unsigned)xi < WWD, x1v = (unsigned)(xi + 1) < WWD;
    float w00 = (1.f - ty) * (1.f - tx) * mk * ((y0v && x0v) ? 1.f : 0.f);
    float w01 = (1.f - ty) * tx * mk * ((y0v && x1v) ? 1.f : 0.f);
    float w10 = ty * (1.f - tx) * mk * ((y1v && x0v) ? 1.f : 0.f);
    float w11 = ty * tx * mk * ((y1v && x1v) ? 1.f : 0.f);
    int* p = prm[tid];
    // offsets in u32 units of NHWC bf16: row = 128*32, col = 32
    *(int4*)p = make_int4(min(max(yi, 0), HH - 1) * (WWD * 32),
                          min(max(yi + 1, 0), HH - 1) * (WWD * 32),
                          min(max(xi, 0), WWD - 1) * 32,
                          min(max(xi + 1, 0), WWD - 1) * 32);
    *(int4*)(p + 4) = make_int4(__float_as_int(w00), __float_as_int(w01),
                                __float_as_int(w10), __float_as_int(w11));
  }
  __syncthreads();
  {
    int lane2 = tid & 31, hw16 = tid >> 5;    // 16 half-waves
    const u32* ytb = (const u32*)yt + (size_t)b * HWv * 32 + lane2;
    #pragma unroll 9
    for (int i = 0; i < 18; i++) {
      int u = hw16 + 16 * i;                  // 0..287
      int k = u % 9, pix = u / 9;
      int4 pa = *(const int4*)prm[u];
      int4 pb = *(const int4*)(prm[u] + 4);
      u32 v00 = ytb[pa.x + pa.z];
      u32 v01 = ytb[pa.x + pa.w];
      u32 v10 = ytb[pa.y + pa.z];
      u32 v11 = ytb[pa.y + pa.w];
      float w00 = __int_as_float(pb.x), w01 = __int_as_float(pb.y);
      float w10 = __int_as_float(pb.z), w11 = __int_as_float(pb.w);
      float vx = fmaf(bfLO(v00), w00, fmaf(bfLO(v01), w01,
                 fmaf(bfLO(v10), w10, bfLO(v11) * w11)));
      float vy = fmaf(bfHI(v00), w00, fmaf(bfHI(v01), w01,
                 fmaf(bfHI(v10), w10, bfHI(v11) * w11)));
      samp32[pix * (DROW / 2) + k * 32 + lane2] = f2bf2(vx, vy);
    }
  }
  __syncthreads();

  int lane = tid & 63, q = tid >> 6;          // q 0..7
  int qq = q & 3, pxg = q >> 2;               // co-quadrant, px-group
  f32x4 acc = {0.f, 0.f, 0.f, 0.f};
  const u16* arow = samp + (pxg * 16 + (lane & 15)) * DROW + (lane >> 4) * 8;
  const bf16x8* bp = (const bf16x8*)wpack + (size_t)(qq * KSTEP) * 64 + lane;
  #pragma unroll
  for (int s = 0; s < KSTEP; s++) {
    bf16x8 a = *(const bf16x8*)(arow + s * 32);
    bf16x8 bf = bp[(size_t)s * 64];
    acc = __builtin_amdgcn_mfma_f32_16x16x32_bf16(a, bf, acc, 0, 0, 0);
  }
  int co = qq * 16 + (lane & 15);
  int px = pxg * 16 + (lane >> 4) * 4;
  float bv = b_dc[co];
  size_t obase = ((size_t)b * HWv + hwb + px) * 64 + co;
  #pragma unroll
  for (int r = 0; r < 4; r++)
    ob[obase + (size_t)r * 64] =
        f2bf(acc[r] + bv + bf2f(x0bf[obase + (size_t)r * 64]));
}

// ====== 3x3 direct conv, 64-px strip, bf16 NHWC in (pure-copy stage) ======
// MODE 1: +leaky -> z1 bf16 NHWC. MODE 2: +res(ob bf16) -> out f32 NCHW
template <int MODE>
__global__ __launch_bounds__(512) void rconv_k(const u16* __restrict__ in,
    const u16* __restrict__ res, const u16* __restrict__ wpack,
    const float* __restrict__ bias, void* __restrict__ outp) {
  __shared__ __align__(16) u16 samp[3 * RCOLS * CSTR];  // 28,512 B
  u32* samp32 = (u32*)samp;
  int tid = threadIdx.x;
  int pixbase = blockIdx.x * 64;
  int hwb = pixbase & (HWv - 1);
  int b = pixbase >> 14;
  int h = hwb >> 7, wb = hwb & 127;

  // stage raw tile [3 rows][66 cols][64 ch] bf16 — pure u32 copy
  {
    int lane2 = tid & 31, hw16 = tid >> 5;
    const u32* inb = (const u32*)in + (size_t)b * HWv * 32 + lane2;
    #pragma unroll
    for (int i = 0; i < 13; i++) {
      int u = hw16 + 16 * i;
      if (u < 198) {
        int r = u / 66, c = u % 66;
        int hh = h - 1 + r, ww = wb - 1 + c;
        u32 v = 0;
        if ((unsigned)hh < HH && (unsigned)ww < WWD)
          v = inb[(hh * WWD + ww) * 32];
        samp32[(r * 66 + c) * (CSTR / 2) + lane2] = v;
      }
    }
  }
  __syncthreads();

  int lane = tid & 63, q = tid >> 6;
  int copair = q & 1, pxg = q >> 1;           // co-half, px-group (0..3)
  f32x4 acc[2] = {{0,0,0,0},{0,0,0,0}};
  const bf16x8* bp = (const bf16x8*)wpack + (size_t)(copair * 2 * KSTEP) * 64 + lane;
  #pragma unroll
  for (int s = 0; s < KSTEP; s++) {
    int kk = s >> 1;
    int addr = ((kk / 3) * 66 + pxg * 16 + (lane & 15) + (kk % 3)) * CSTR
               + (s & 1) * 32 + (lane >> 4) * 8;
    bf16x8 a = *(const bf16x8*)(samp + addr);
    acc[0] = __builtin_amdgcn_mfma_f32_16x16x32_bf16(a, bp[(size_t)s * 64], acc[0], 0, 0, 0);
    acc[1] = __builtin_amdgcn_mfma_f32_16x16x32_bf16(a, bp[(size_t)(KSTEP + s) * 64], acc[1], 0, 0, 0);
  }

  int px = pxg * 16 + (lane >> 4) * 4;
  if (MODE == 1) {
    u16* outb = (u16*)outp;
    #pragma unroll
    for (int t = 0; t < 2; t++) {
      int co = copair * 32 + t * 16 + (lane & 15);
      float bv = bias[co];
      size_t obase = ((size_t)b * HWv + hwb + px) * 64 + co;
      #pragma unroll
      for (int r = 0; r < 4; r++) {
        float v = acc[t][r] + bv;
        outb[obase + (size_t)r * 64] = f2bf(v >= 0.f ? v : 0.2f * v);
      }
    }
  } else {
    float* outf = (float*)outp;
    float* ot = (float*)samp;                 // [64 co][68] = 17,408 B
    __syncthreads();                          // tile reads done
    #pragma unroll
    for (int t = 0; t < 2; t++) {
      int co = copair * 32 + t * 16 + (lane & 15);
      float bv = bias[co];
      size_t rbase = ((size_t)b * HWv + hwb + px) * 64 + co;
      #pragma unroll
      for (int r = 0; r < 4; r++)
        ot[co * 68 + px + r] = acc[t][r] + bv + bf2f(res[rbase + (size_t)r * 64]);
    }
    __syncthreads();
    int co = tid >> 3, seg = tid & 7;         // 64 co x 8 px-segments
    const float4* src4 = (const float4*)(ot + co * 68 + seg * 8);
    float4 v0 = src4[0], v1 = src4[1];
    float* dst = outf + ((size_t)b * CCH + co) * HWv + hwb + seg * 8;
    *(float4*)dst = v0;
    *(float4*)(dst + 4) = v1;
  }
}

extern "C" void kernel_launch(void* const* d_in, const int* in_sizes, int n_in,
                              void* d_out, int out_size, void* d_ws, size_t ws_size,
                              hipStream_t stream) {
  const float* x    = (const float*)d_in[0];
  const float* y    = (const float*)d_in[1];
  const float* w0   = (const float*)d_in[2];
  const float* b0   = (const float*)d_in[3];
  const float* w_om = (const float*)d_in[4];
  const float* b_om = (const float*)d_in[5];
  const float* w_dc = (const float*)d_in[6];
  const float* b_dc = (const float*)d_in[7];
  const float* w1   = (const float*)d_in[8];
  const float* b1   = (const float*)d_in[9];
  const float* w2   = (const float*)d_in[10];
  const float* b2   = (const float*)d_in[11];
  float* out = (float*)d_out;

  const size_t NFULL = (size_t)BB * CCH * HWv;   // 2,097,152
  const size_t NOMT  = (size_t)BB * HWv * OMC;   // 1,048,576
  const size_t NPACK = 4 * KSTEP * 64 * 8;       // 36,864 bf16
  const size_t NPACKOM = 2 * OMKS * 64 * 8;      // 36,864
  const size_t NPACK1  = 4 * 2 * 64 * 8;         //  4,096
  float* omt = (float*)d_ws;                     // NOMT f32
  u16* x0bf = (u16*)(omt + NOMT);                // NFULL bf16
  u16* ob   = x0bf + NFULL;                      // NFULL bf16
  u16* z1   = ob + NFULL;                        // NFULL bf16
  u16* yt   = z1;                                // alias: yt dead before z1 written
  u16* pk_dc = z1 + NFULL;
  u16* pk_w1 = pk_dc + NPACK;
  u16* pk_w2 = pk_w1 + NPACK;
  u16* pk_om = pk_w2 + NPACK;
  u16* pk_0  = pk_om + NPACKOM;

  pack_tap_k<4, KSTEP, 64, 64><<<(int)(NPACK / 256), 256, 0, stream>>>(w_dc, pk_dc);
  pack_tap_k<4, KSTEP, 64, 64><<<(int)(NPACK / 256), 256, 0, stream>>>(w1, pk_w1);
  pack_tap_k<4, KSTEP, 64, 64><<<(int)(NPACK / 256), 256, 0, stream>>>(w2, pk_w2);
  pack_tap_k<2, OMKS, 27, 128><<<(int)(NPACKOM / 256), 256, 0, stream>>>(w_om, pk_om);
  pack_k<4, 2, 64, 64><<<(int)(NPACK1 / 256), 256, 0, stream>>>(w0, pk_0);

  // 0. y -> NHWC bf16 (into z1's buffer; consumed before z1 is written)
  transpose_yk<<<(int)((size_t)BB * HWv / 64), 256, 0, stream>>>(y, yt);
  // 1. conv1x1 -> x0bf (NHWC bf16)
  conv1x1_mfma_k<<<(int)((size_t)BB * HWv / 64), 256, 0, stream>>>(x, pk_0, b0, x0bf);
  // 2. offset/mask conv -> om_t (NHWC f32, stride 32) — raw-tile MFMA
  om2_k<<<(int)((size_t)BB * HWv / 64), 512, 0, stream>>>(x0bf, yt, pk_om, b_om, omt);
  // 3. deformable conv + x0 residual -> ob (NHWC bf16)
  dconv_k<<<(int)((size_t)BB * HWv / DPX), 512, 0, stream>>>(yt, omt, x0bf, pk_dc, b_dc, ob);
  // 4. conv w1 + leaky -> z1 (NHWC bf16)
  rconv_k<1><<<(int)((size_t)BB * HWv / 64), 512, 0, stream>>>(ob, nullptr, pk_w1, b1, z1);
  // 5. conv w2 + residual ob -> out (NCHW f32 final)
  rconv_k<2><<<(int)((size_t)BB * HWv / 64), 512, 0, stream>>>(z1, ob, pk_w2, b2, out);
}

// Round 9
// 71.784 us; speedup vs baseline: 1.8794x; 1.1570x over previous
//
#include <hip/hip_runtime.h>
#include <hip/hip_bf16.h>
#include <math.h>

#define BB 2
#define CCH 64
#define HH 128
#define WWD 128
#define HWv (HH*WWD)
#define KK 9
#define KSTEP 18        // 576/32
#define OMKS 36         // 1152/32
#define OMC 32          // om_t NHWC channel stride (27 used)
// rconv (3x3 direct conv, 64-px strip)
#define RCOLS 66
#define CSTR 72         // padded 64-ch run stride (bf16): 64 + 8
// om2 (3x3 direct conv, 128ch in, 64-px strip)
#define CSTR2 136       // padded 128-ch run stride (bf16): 128 + 8
// dconv (deform, 32-px)
#define DPX 32
#define DROW 584        // 576 + 8

typedef __attribute__((ext_vector_type(8))) short bf16x8;
typedef __attribute__((ext_vector_type(4))) float f32x4;
typedef unsigned short u16;
typedef unsigned int u32;

__device__ inline u16 f2bf(float f) {
  __hip_bfloat16 h = __float2bfloat16(f);
  return *reinterpret_cast<u16*>(&h);
}
__device__ inline u32 f2bf2(float lo, float hi) {
  return ((u32)f2bf(hi) << 16) | (u32)f2bf(lo);
}
__device__ inline float bfLO(u32 v) { return __uint_as_float(v << 16); }
__device__ inline float bfHI(u32 v) { return __uint_as_float(v & 0xffff0000u); }
__device__ inline float bf2f(u16 v) { return __uint_as_float((u32)v << 16); }

// ============ ALL weight packs in one launch ===============================
// blocks [0,144) w_dc, [144,288) w1, [288,432) w2 (tap-major, CIN=64)
// blocks [432,576) w_om (tap-major, CIN=128, co<27), [576,592) w0 (ci-major)
__global__ __launch_bounds__(256) void pack_all_k(
    const float* __restrict__ w_dc, const float* __restrict__ w1,
    const float* __restrict__ w2, const float* __restrict__ w_om,
    const float* __restrict__ w0, u16* __restrict__ pk_dc,
    u16* __restrict__ pk_w1, u16* __restrict__ pk_w2,
    u16* __restrict__ pk_om, u16* __restrict__ pk_0) {
  int blk = blockIdx.x;
  int tid = threadIdx.x;
  if (blk < 432) {
    const float* w = blk < 144 ? w_dc : (blk < 288 ? w1 : w2);
    u16* dst = blk < 144 ? pk_dc : (blk < 288 ? pk_w1 : pk_w2);
    int idx = (blk % 144) * 256 + tid;
    int j = idx & 7, l = (idx >> 3) & 63;
    int s = (idx >> 9) % 18, q = idx / 9216;
    int co = q * 16 + (l & 15);
    int kp = s * 32 + (l >> 4) * 8 + j;          // < 576
    dst[idx] = f2bf(w[(co * 64 + (kp & 63)) * 9 + (kp >> 6)]);
  } else if (blk < 576) {
    int idx = (blk - 432) * 256 + tid;
    int j = idx & 7, l = (idx >> 3) & 63;
    int s = (idx >> 9) % 36, q = idx / 18432;
    int co = q * 16 + (l & 15);
    int kp = s * 32 + (l >> 4) * 8 + j;          // < 1152
    pk_om[idx] = (co < 27)
        ? f2bf(w_om[(co * 128 + (kp & 127)) * 9 + (kp >> 7)]) : (u16)0;
  } else {
    int idx = (blk - 576) * 256 + tid;
    int j = idx & 7, l = (idx >> 3) & 63;
    int s = (idx >> 9) & 1, q = idx / 1024;
    int co = q * 16 + (l & 15);
    int k = s * 32 + (l >> 4) * 8 + j;           // < 64
    pk_0[idx] = f2bf(w0[co * 64 + k]);
  }
}

// ==== fused: y NCHW->NHWC bf16 + conv1x1 MFMA (64 px, K=64) -> x0bf ========
__global__ __launch_bounds__(256) void conv1x1y_k(const float* __restrict__ x,
    const float* __restrict__ y, const u16* __restrict__ wpack,
    const float* __restrict__ b0, u16* __restrict__ x0bf,
    u16* __restrict__ yt) {
  #define S1ROW 72
  __shared__ __align__(16) float smem[64 * 65];    // 16,640 B; aliased below
  u16* samp1 = (u16*)smem;                         // needs 9,216 B
  int tid = threadIdx.x;
  int lane = tid & 63, q = tid >> 6;
  int pixbase = blockIdx.x * 64;
  int hwb = pixbase & (HWv - 1);
  int b = pixbase >> 14;

  // ---- phase Y: transpose y for these 64 px ----
  {
    const float* src = y + (size_t)b * CCH * HWv;
    #pragma unroll
    for (int i = 0; i < 16; i++) {
      int ci = i * 4 + q;
      smem[ci * 65 + lane] = src[(size_t)ci * HWv + hwb + lane];
    }
    __syncthreads();
    u32* dst32 = (u32*)(yt + ((size_t)b * HWv + hwb) * 64);
    int lane2 = tid & 31, rr = tid >> 5;
    #pragma unroll
    for (int i = 0; i < 8; i++) {
      int row = i * 8 + rr;
      dst32[row * 32 + lane2] = f2bf2(smem[(2 * lane2) * 65 + row],
                                      smem[(2 * lane2 + 1) * 65 + row]);
    }
    __syncthreads();                               // smem dead -> reuse
  }

  // ---- phase X: conv1x1 ----
  {
    u16 tmp[16];
    #pragma unroll
    for (int i = 0; i < 16; i++) {
      int ci = q * 16 + i;
      tmp[i] = f2bf(x[((size_t)b * CCH + ci) * HWv + hwb + lane]);
    }
    #pragma unroll
    for (int i = 0; i < 2; i++)
      *(bf16x8*)(samp1 + lane * S1ROW + q * 16 + i * 8) = *(bf16x8*)(tmp + i * 8);
  }
  __syncthreads();
  f32x4 acc[4] = {{0,0,0,0},{0,0,0,0},{0,0,0,0},{0,0,0,0}};
  int g = lane >> 4;
  const bf16x8* bp = (const bf16x8*)wpack + (size_t)(q * 2) * 64 + lane;
  #pragma unroll
  for (int s = 0; s < 2; s++) {
    bf16x8 bf = bp[(size_t)s * 64];
    #pragma unroll
    for (int t = 0; t < 4; t++) {
      bf16x8 a = *(const bf16x8*)(samp1 + (t * 16 + (lane & 15)) * S1ROW + g * 8 + s * 32);
      acc[t] = __builtin_amdgcn_mfma_f32_16x16x32_bf16(a, bf, acc[t], 0, 0, 0);
    }
  }
  int co = q * 16 + (lane & 15);
  float bv = b0[co];
  u16* dst = x0bf + ((size_t)b * HWv + hwb + g * 4) * 64 + co;
  #pragma unroll
  for (int t = 0; t < 4; t++)
    #pragma unroll
    for (int r = 0; r < 4; r++)
      dst[(size_t)(t * 16 + r) * 64] = f2bf(acc[t][r] + bv);
}

// ==== om conv: 64-px strip, raw [3][66][128ch] tile, K=1152 tap-major ======
__global__ __launch_bounds__(512) void om2_k(const u16* __restrict__ x0bf,
    const u16* __restrict__ yt, const u16* __restrict__ wpack,
    const float* __restrict__ bias, float* __restrict__ om_t) {
  __shared__ __align__(16) u16 samp[3 * RCOLS * CSTR2];  // 53,856 B
  u32* samp32 = (u32*)samp;
  int tid = threadIdx.x;
  int pixbase = blockIdx.x * 64;
  int hwb = pixbase & (HWv - 1);
  int b = pixbase >> 14;
  int h = hwb >> 7, wb = hwb & 127;

  // stage raw tile: unit = (rc 0..197, half 0..1); pure u32 copy
  {
    int lane2 = tid & 31, hw16 = tid >> 5;
    const u32* x0b = (const u32*)x0bf + (size_t)b * HWv * 32 + lane2;
    const u32* ytb = (const u32*)yt + (size_t)b * HWv * 32 + lane2;
    #pragma unroll
    for (int i = 0; i < 25; i++) {
      int u = hw16 + 16 * i;
      if (u < 396) {
        int half = u & 1, rc = u >> 1;
        int r = rc / 66, c = rc % 66;
        int hh = h - 1 + r, ww = wb - 1 + c;
        u32 v = 0;
        if ((unsigned)hh < HH && (unsigned)ww < WWD)
          v = (half ? ytb : x0b)[(hh * WWD + ww) * 32];
        samp32[rc * (CSTR2 / 2) + half * 32 + lane2] = v;
      }
    }
  }
  __syncthreads();

  int lane = tid & 63, q = tid >> 6;
  int cohalf = q & 1, pxg = q >> 1;           // co-half (16), px-group (0..3)
  f32x4 acc = {0.f, 0.f, 0.f, 0.f};
  const bf16x8* bp = (const bf16x8*)wpack + (size_t)(cohalf * OMKS) * 64 + lane;
  #pragma unroll
  for (int s = 0; s < OMKS; s++) {
    int kk = s >> 2;                          // tap (4 ksteps per 128-ch tap)
    int addr = ((kk / 3) * 66 + pxg * 16 + (lane & 15) + (kk % 3)) * CSTR2
               + (s & 3) * 32 + (lane >> 4) * 8;
    bf16x8 a = *(const bf16x8*)(samp + addr);
    acc = __builtin_amdgcn_mfma_f32_16x16x32_bf16(a, bp[(size_t)s * 64], acc, 0, 0, 0);
  }
  int co = cohalf * 16 + (lane & 15);
  if (co < 27) {
    float bv = bias[co];
    int px = pxg * 16 + (lane >> 4) * 4;
    size_t ob_ = ((size_t)b * HWv + hwb + px) * OMC + co;
    #pragma unroll
    for (int r = 0; r < 4; r++)
      om_t[ob_ + (size_t)r * OMC] = acc[r] + bv;
  }
}

// ============ deform conv: branch-free gather + MFMA, bf16 yt/x0/ob ========
__global__ __launch_bounds__(512) void dconv_k(const u16* __restrict__ yt,
    const float* __restrict__ omt, const u16* __restrict__ x0bf,
    const u16* __restrict__ wpack, const float* __restrict__ b_dc,
    u16* __restrict__ ob) {
  __shared__ __align__(16) u16 samp[DPX * DROW];   // 37,376 B
  __shared__ __align__(16) int prm[DPX * KK][8];   //  9,216 B
  u32* samp32 = (u32*)samp;
  int tid = threadIdx.x;
  int pixbase = blockIdx.x * DPX;
  int hwb = pixbase & (HWv - 1);
  int b = pixbase >> 14;
  int h = hwb >> 7, wb = hwb & 127;

  if (tid < DPX * KK) {
    int pix = tid / KK, k = tid % KK;
    const float* omb = omt + ((size_t)b * HWv + hwb + pix) * OMC;
    float dy = omb[2 * k], dx = omb[2 * k + 1];
    float mk = 2.f / (1.f + expf(-omb[18 + k]));
    float ys = (float)(h - 1 + k / 3) + dy;
    float xs = (float)(wb + pix - 1 + k % 3) + dx;
    float y0f = floorf(ys), x0f = floorf(xs);
    float ty = ys - y0f, tx = xs - x0f;
    int yi = (int)y0f, xi = (int)x0f;
    bool y0v = (unsigned)yi < HH, y1v = (unsigned)(yi + 1) < HH;
    bool x0v = (unsigned)xi < WWD, x1v = (unsigned)(xi + 1) < WWD;
    float w00 = (1.f - ty) * (1.f - tx) * mk * ((y0v && x0v) ? 1.f : 0.f);
    float w01 = (1.f - ty) * tx * mk * ((y0v && x1v) ? 1.f : 0.f);
    float w10 = ty * (1.f - tx) * mk * ((y1v && x0v) ? 1.f : 0.f);
    float w11 = ty * tx * mk * ((y1v && x1v) ? 1.f : 0.f);
    int* p = prm[tid];
    // offsets in u32 units of NHWC bf16: row = 128*32, col = 32
    *(int4*)p = make_int4(min(max(yi, 0), HH - 1) * (WWD * 32),
                          min(max(yi + 1, 0), HH - 1) * (WWD * 32),
                          min(max(xi, 0), WWD - 1) * 32,
                          min(max(xi + 1, 0), WWD - 1) * 32);
    *(int4*)(p + 4) = make_int4(__float_as_int(w00), __float_as_int(w01),
                                __float_as_int(w10), __float_as_int(w11));
  }
  __syncthreads();
  {
    int lane2 = tid & 31, hw16 = tid >> 5;    // 16 half-waves
    const u32* ytb = (const u32*)yt + (size_t)b * HWv * 32 + lane2;
    #pragma unroll 9
    for (int i = 0; i < 18; i++) {
      int u = hw16 + 16 * i;                  // 0..287
      int k = u % 9, pix = u / 9;
      int4 pa = *(const int4*)prm[u];
      int4 pb = *(const int4*)(prm[u] + 4);
      u32 v00 = ytb[pa.x + pa.z];
      u32 v01 = ytb[pa.x + pa.w];
      u32 v10 = ytb[pa.y + pa.z];
      u32 v11 = ytb[pa.y + pa.w];
      float w00 = __int_as_float(pb.x), w01 = __int_as_float(pb.y);
      float w10 = __int_as_float(pb.z), w11 = __int_as_float(pb.w);
      float vx = fmaf(bfLO(v00), w00, fmaf(bfLO(v01), w01,
                 fmaf(bfLO(v10), w10, bfLO(v11) * w11)));
      float vy = fmaf(bfHI(v00), w00, fmaf(bfHI(v01), w01,
                 fmaf(bfHI(v10), w10, bfHI(v11) * w11)));
      samp32[pix * (DROW / 2) + k * 32 + lane2] = f2bf2(vx, vy);
    }
  }
  __syncthreads();

  int lane = tid & 63, q = tid >> 6;          // q 0..7
  int qq = q & 3, pxg = q >> 2;               // co-quadrant, px-group
  f32x4 acc = {0.f, 0.f, 0.f, 0.f};
  const u16* arow = samp + (pxg * 16 + (lane & 15)) * DROW + (lane >> 4) * 8;
  const bf16x8* bp = (const bf16x8*)wpack + (size_t)(qq * KSTEP) * 64 + lane;
  #pragma unroll
  for (int s = 0; s < KSTEP; s++) {
    bf16x8 a = *(const bf16x8*)(arow + s * 32);
    bf16x8 bf = bp[(size_t)s * 64];
    acc = __builtin_amdgcn_mfma_f32_16x16x32_bf16(a, bf, acc, 0, 0, 0);
  }
  int co = qq * 16 + (lane & 15);
  int px = pxg * 16 + (lane >> 4) * 4;
  float bv = b_dc[co];
  size_t obase = ((size_t)b * HWv + hwb + px) * 64 + co;
  #pragma unroll
  for (int r = 0; r < 4; r++)
    ob[obase + (size_t)r * 64] =
        f2bf(acc[r] + bv + bf2f(x0bf[obase + (size_t)r * 64]));
}

// ====== 3x3 direct conv, 64-px strip, bf16 NHWC in (pure-copy stage) ======
// MODE 1: +leaky -> z1 bf16 NHWC. MODE 2: +res(ob bf16) -> out f32 NCHW
template <int MODE>
__global__ __launch_bounds__(512) void rconv_k(const u16* __restrict__ in,
    const u16* __restrict__ res, const u16* __restrict__ wpack,
    const float* __restrict__ bias, void* __restrict__ outp) {
  __shared__ __align__(16) u16 samp[3 * RCOLS * CSTR];  // 28,512 B
  u32* samp32 = (u32*)samp;
  int tid = threadIdx.x;
  int pixbase = blockIdx.x * 64;
  int hwb = pixbase & (HWv - 1);
  int b = pixbase >> 14;
  int h = hwb >> 7, wb = hwb & 127;

  // stage raw tile [3 rows][66 cols][64 ch] bf16 — pure u32 copy
  {
    int lane2 = tid & 31, hw16 = tid >> 5;
    const u32* inb = (const u32*)in + (size_t)b * HWv * 32 + lane2;
    #pragma unroll
    for (int i = 0; i < 13; i++) {
      int u = hw16 + 16 * i;
      if (u < 198) {
        int r = u / 66, c = u % 66;
        int hh = h - 1 + r, ww = wb - 1 + c;
        u32 v = 0;
        if ((unsigned)hh < HH && (unsigned)ww < WWD)
          v = inb[(hh * WWD + ww) * 32];
        samp32[(r * 66 + c) * (CSTR / 2) + lane2] = v;
      }
    }
  }
  __syncthreads();

  int lane = tid & 63, q = tid >> 6;
  int copair = q & 1, pxg = q >> 1;           // co-half, px-group (0..3)
  f32x4 acc[2] = {{0,0,0,0},{0,0,0,0}};
  const bf16x8* bp = (const bf16x8*)wpack + (size_t)(copair * 2 * KSTEP) * 64 + lane;
  #pragma unroll
  for (int s = 0; s < KSTEP; s++) {
    int kk = s >> 1;
    int addr = ((kk / 3) * 66 + pxg * 16 + (lane & 15) + (kk % 3)) * CSTR
               + (s & 1) * 32 + (lane >> 4) * 8;
    bf16x8 a = *(const bf16x8*)(samp + addr);
    acc[0] = __builtin_amdgcn_mfma_f32_16x16x32_bf16(a, bp[(size_t)s * 64], acc[0], 0, 0, 0);
    acc[1] = __builtin_amdgcn_mfma_f32_16x16x32_bf16(a, bp[(size_t)(KSTEP + s) * 64], acc[1], 0, 0, 0);
  }

  int px = pxg * 16 + (lane >> 4) * 4;
  if (MODE == 1) {
    u16* outb = (u16*)outp;
    #pragma unroll
    for (int t = 0; t < 2; t++) {
      int co = copair * 32 + t * 16 + (lane & 15);
      float bv = bias[co];
      size_t obase = ((size_t)b * HWv + hwb + px) * 64 + co;
      #pragma unroll
      for (int r = 0; r < 4; r++) {
        float v = acc[t][r] + bv;
        outb[obase + (size_t)r * 64] = f2bf(v >= 0.f ? v : 0.2f * v);
      }
    }
  } else {
    float* outf = (float*)outp;
    float* ot = (float*)samp;                 // [64 co][68] = 17,408 B
    __syncthreads();                          // tile reads done
    #pragma unroll
    for (int t = 0; t < 2; t++) {
      int co = copair * 32 + t * 16 + (lane & 15);
      float bv = bias[co];
      size_t rbase = ((size_t)b * HWv + hwb + px) * 64 + co;
      #pragma unroll
      for (int r = 0; r < 4; r++)
        ot[co * 68 + px + r] = acc[t][r] + bv + bf2f(res[rbase + (size_t)r * 64]);
    }
    __syncthreads();
    int co = tid >> 3, seg = tid & 7;         // 64 co x 8 px-segments
    const float4* src4 = (const float4*)(ot + co * 68 + seg * 8);
    float4 v0 = src4[0], v1 = src4[1];
    float* dst = outf + ((size_t)b * CCH + co) * HWv + hwb + seg * 8;
    *(float4*)dst = v0;
    *(float4*)(dst + 4) = v1;
  }
}

extern "C" void kernel_launch(void* const* d_in, const int* in_sizes, int n_in,
                              void* d_out, int out_size, void* d_ws, size_t ws_size,
                              hipStream_t stream) {
  const float* x    = (const float*)d_in[0];
  const float* y    = (const float*)d_in[1];
  const float* w0   = (const float*)d_in[2];
  const float* b0   = (const float*)d_in[3];
  const float* w_om = (const float*)d_in[4];
  const float* b_om = (const float*)d_in[5];
  const float* w_dc = (const float*)d_in[6];
  const float* b_dc = (const float*)d_in[7];
  const float* w1   = (const float*)d_in[8];
  const float* b1   = (const float*)d_in[9];
  const float* w2   = (const float*)d_in[10];
  const float* b2   = (const float*)d_in[11];
  float* out = (float*)d_out;

  const size_t NFULL = (size_t)BB * CCH * HWv;   // 2,097,152
  const size_t NOMT  = (size_t)BB * HWv * OMC;   // 1,048,576
  const size_t NPACK = 4 * KSTEP * 64 * 8;       // 36,864 bf16
  const size_t NPACKOM = 2 * OMKS * 64 * 8;      // 36,864
  float* omt = (float*)d_ws;                     // NOMT f32
  u16* x0bf = (u16*)(omt + NOMT);                // NFULL bf16
  u16* ob   = x0bf + NFULL;                      // NFULL bf16
  u16* z1   = ob + NFULL;                        // NFULL bf16
  u16* yt   = z1;                                // alias: yt dead before z1 written
  u16* pk_dc = z1 + NFULL;
  u16* pk_w1 = pk_dc + NPACK;
  u16* pk_w2 = pk_w1 + NPACK;
  u16* pk_om = pk_w2 + NPACK;
  u16* pk_0  = pk_om + NPACKOM;

  // 0. all weight packs, one launch (592 blocks)
  pack_all_k<<<592, 256, 0, stream>>>(w_dc, w1, w2, w_om, w0,
                                      pk_dc, pk_w1, pk_w2, pk_om, pk_0);
  // 1. fused y-transpose + conv1x1 -> yt, x0bf (NHWC bf16)
  conv1x1y_k<<<(int)((size_t)BB * HWv / 64), 256, 0, stream>>>(
      x, y, pk_0, b0, x0bf, yt);
  // 2. offset/mask conv -> om_t (NHWC f32, stride 32) — raw-tile MFMA
  om2_k<<<(int)((size_t)BB * HWv / 64), 512, 0, stream>>>(x0bf, yt, pk_om, b_om, omt);
  // 3. deformable conv + x0 residual -> ob (NHWC bf16)
  dconv_k<<<(int)((size_t)BB * HWv / DPX), 512, 0, stream>>>(yt, omt, x0bf, pk_dc, b_dc, ob);
  // 4. conv w1 + leaky -> z1 (NHWC bf16)
  rconv_k<1><<<(int)((size_t)BB * HWv / 64), 512, 0, stream>>>(ob, nullptr, pk_w1, b1, z1);
  // 5. conv w2 + residual ob -> out (NCHW f32 final)
  rconv_k<2><<<(int)((size_t)BB * HWv / 64), 512, 0, stream>>>(z1, ob, pk_w2, b2, out);
}

// Round 10
// 65.223 us; speedup vs baseline: 2.0684x; 1.1006x over previous
//
#include <hip/hip_runtime.h>
#include <hip/hip_bf16.h>
#include <math.h>

#define BB 2
#define CCH 64
#define HH 128
#define WWD 128
#define HWv (HH*WWD)
#define KK 9
#define KSTEP 18        // 576/32
#define OMKS 36         // 1152/32
// rconv (3x3 direct conv, 64-px strip)
#define RCOLS 66
#define CSTR 72         // padded 64-ch run stride (bf16): 64 + 8
// om/deform fused (64-px strip)
#define CSTR2 136       // padded 128-ch run stride (bf16): 128 + 8
#define DROW 584        // deform samp row stride (bf16): 576 + 8

typedef __attribute__((ext_vector_type(8))) short bf16x8;
typedef __attribute__((ext_vector_type(4))) float f32x4;
typedef unsigned short u16;
typedef unsigned int u32;

__device__ inline u16 f2bf(float f) {
  __hip_bfloat16 h = __float2bfloat16(f);
  return *reinterpret_cast<u16*>(&h);
}
__device__ inline u32 f2bf2(float lo, float hi) {
  return ((u32)f2bf(hi) << 16) | (u32)f2bf(lo);
}
__device__ inline float bfLO(u32 v) { return __uint_as_float(v << 16); }
__device__ inline float bfHI(u32 v) { return __uint_as_float(v & 0xffff0000u); }
__device__ inline float bf2f(u16 v) { return __uint_as_float((u32)v << 16); }

// ============ ALL weight packs in one launch ===============================
// blocks [0,144) w_dc, [144,288) w1, [288,432) w2 (tap-major, CIN=64)
// blocks [432,576) w_om (tap-major, CIN=128, co<27), [576,592) w0 (ci-major)
__global__ __launch_bounds__(256) void pack_all_k(
    const float* __restrict__ w_dc, const float* __restrict__ w1,
    const float* __restrict__ w2, const float* __restrict__ w_om,
    const float* __restrict__ w0, u16* __restrict__ pk_dc,
    u16* __restrict__ pk_w1, u16* __restrict__ pk_w2,
    u16* __restrict__ pk_om, u16* __restrict__ pk_0) {
  int blk = blockIdx.x;
  int tid = threadIdx.x;
  if (blk < 432) {
    const float* w = blk < 144 ? w_dc : (blk < 288 ? w1 : w2);
    u16* dst = blk < 144 ? pk_dc : (blk < 288 ? pk_w1 : pk_w2);
    int idx = (blk % 144) * 256 + tid;
    int j = idx & 7, l = (idx >> 3) & 63;
    int s = (idx >> 9) % 18, q = idx / 9216;
    int co = q * 16 + (l & 15);
    int kp = s * 32 + (l >> 4) * 8 + j;          // < 576
    dst[idx] = f2bf(w[(co * 64 + (kp & 63)) * 9 + (kp >> 6)]);
  } else if (blk < 576) {
    int idx = (blk - 432) * 256 + tid;
    int j = idx & 7, l = (idx >> 3) & 63;
    int s = (idx >> 9) % 36, q = idx / 18432;
    int co = q * 16 + (l & 15);
    int kp = s * 32 + (l >> 4) * 8 + j;          // < 1152
    pk_om[idx] = (co < 27)
        ? f2bf(w_om[(co * 128 + (kp & 127)) * 9 + (kp >> 7)]) : (u16)0;
  } else {
    int idx = (blk - 576) * 256 + tid;
    int j = idx & 7, l = (idx >> 3) & 63;
    int s = (idx >> 9) & 1, q = idx / 1024;
    int co = q * 16 + (l & 15);
    int k = s * 32 + (l >> 4) * 8 + j;           // < 64
    pk_0[idx] = f2bf(w0[co * 64 + k]);
  }
}

// ==== fused: y NCHW->NHWC bf16 + conv1x1 MFMA (64 px, K=64) -> x0bf ========
__global__ __launch_bounds__(256) void conv1x1y_k(const float* __restrict__ x,
    const float* __restrict__ y, const u16* __restrict__ wpack,
    const float* __restrict__ b0, u16* __restrict__ x0bf,
    u16* __restrict__ yt) {
  #define S1ROW 72
  __shared__ __align__(16) float smem[64 * 65];    // 16,640 B; aliased below
  u16* samp1 = (u16*)smem;                         // needs 9,216 B
  int tid = threadIdx.x;
  int lane = tid & 63, q = tid >> 6;
  int pixbase = blockIdx.x * 64;
  int hwb = pixbase & (HWv - 1);
  int b = pixbase >> 14;

  // ---- phase Y: transpose y for these 64 px ----
  {
    const float* src = y + (size_t)b * CCH * HWv;
    #pragma unroll
    for (int i = 0; i < 16; i++) {
      int ci = i * 4 + q;
      smem[ci * 65 + lane] = src[(size_t)ci * HWv + hwb + lane];
    }
    __syncthreads();
    u32* dst32 = (u32*)(yt + ((size_t)b * HWv + hwb) * 64);
    int lane2 = tid & 31, rr = tid >> 5;
    #pragma unroll
    for (int i = 0; i < 8; i++) {
      int row = i * 8 + rr;
      dst32[row * 32 + lane2] = f2bf2(smem[(2 * lane2) * 65 + row],
                                      smem[(2 * lane2 + 1) * 65 + row]);
    }
    __syncthreads();                               // smem dead -> reuse
  }

  // ---- phase X: conv1x1 ----
  {
    u16 tmp[16];
    #pragma unroll
    for (int i = 0; i < 16; i++) {
      int ci = q * 16 + i;
      tmp[i] = f2bf(x[((size_t)b * CCH + ci) * HWv + hwb + lane]);
    }
    #pragma unroll
    for (int i = 0; i < 2; i++)
      *(bf16x8*)(samp1 + lane * S1ROW + q * 16 + i * 8) = *(bf16x8*)(tmp + i * 8);
  }
  __syncthreads();
  f32x4 acc[4] = {{0,0,0,0},{0,0,0,0},{0,0,0,0},{0,0,0,0}};
  int g = lane >> 4;
  const bf16x8* bp = (const bf16x8*)wpack + (size_t)(q * 2) * 64 + lane;
  #pragma unroll
  for (int s = 0; s < 2; s++) {
    bf16x8 bf = bp[(size_t)s * 64];
    #pragma unroll
    for (int t = 0; t < 4; t++) {
      bf16x8 a = *(const bf16x8*)(samp1 + (t * 16 + (lane & 15)) * S1ROW + g * 8 + s * 32);
      acc[t] = __builtin_amdgcn_mfma_f32_16x16x32_bf16(a, bf, acc[t], 0, 0, 0);
    }
  }
  int co = q * 16 + (lane & 15);
  float bv = b0[co];
  u16* dst = x0bf + ((size_t)b * HWv + hwb + g * 4) * 64 + co;
  #pragma unroll
  for (int t = 0; t < 4; t++)
    #pragma unroll
    for (int r = 0; r < 4; r++)
      dst[(size_t)(t * 16 + r) * 64] = f2bf(acc[t][r] + bv);
}

// ==== FUSED om conv + deform conv, 64-px strip, 512 thr ====================
// phase 1: stage [3][66][128ch] bf16 tile (uint2)
// phase 2: om MFMA (K=1152) -> omv LDS [64px][28] f32 (bias added)
// phase 3: two 32-px halves: prm -> branch-free gather (uint2) -> MFMA -> ob
__global__ __launch_bounds__(512) void omd_k(const u16* __restrict__ x0bf,
    const u16* __restrict__ yt, const u16* __restrict__ pk_om,
    const u16* __restrict__ pk_dc, const float* __restrict__ b_om,
    const float* __restrict__ b_dc, u16* __restrict__ ob) {
  __shared__ __align__(16) u16 A[3 * RCOLS * CSTR2];  // 53,856 B (multi-use)
  __shared__ __align__(16) float omv[64 * 28];        //  7,168 B
  u32* A32 = (u32*)A;
  u32* dsamp32 = (u32*)A;                             // [32][292] u32
  u16* dsamp = A;
  int (*prm)[8] = (int(*)[8])(A + 18688);             // byte 37,376; 9,216 B
  int tid = threadIdx.x;
  int lane = tid & 63, q = tid >> 6;
  int pixbase = blockIdx.x * 64;
  int hwb = pixbase & (HWv - 1);
  int b = pixbase >> 14;
  int h = hwb >> 7, wb = hwb & 127;
  const u32* x0b32 = (const u32*)x0bf + (size_t)b * HWv * 32;
  const u32* yt32  = (const u32*)yt + (size_t)b * HWv * 32;

  // ---- phase 1: stage tile; lane covers 4 ch (uint2); 32-lane group per rc
  {
    int lane2 = tid & 31, hw16 = tid >> 5;
    int cofs = lane2 * 2;
    const u32* srcb = (lane2 < 16) ? (x0b32 + cofs) : (yt32 + cofs - 32);
    #pragma unroll
    for (int i = 0; i < 13; i++) {
      int u = hw16 + 16 * i;
      if (u < 198) {
        int r = u / 66, c = u % 66;
        int hh = h - 1 + r, ww = wb - 1 + c;
        uint2 v = {0u, 0u};
        if ((unsigned)hh < HH && (unsigned)ww < WWD)
          v = *(const uint2*)(srcb + (size_t)(hh * WWD + ww) * 32);
        *(uint2*)(A32 + u * (CSTR2 / 2) + cofs) = v;
      }
    }
  }
  __syncthreads();

  // ---- phase 2: om MFMA; 8 waves = 2 cohalf x 4 pxg
  {
    int cohalf = q & 1, pxg = q >> 1;
    f32x4 acc = {0.f, 0.f, 0.f, 0.f};
    const bf16x8* bp = (const bf16x8*)pk_om + (size_t)(cohalf * OMKS) * 64 + lane;
    #pragma unroll
    for (int s = 0; s < OMKS; s++) {
      int kk = s >> 2;
      int addr = ((kk / 3) * 66 + pxg * 16 + (lane & 15) + (kk % 3)) * CSTR2
                 + (s & 3) * 32 + (lane >> 4) * 8;
      bf16x8 a = *(const bf16x8*)(A + addr);
      acc = __builtin_amdgcn_mfma_f32_16x16x32_bf16(a, bp[(size_t)s * 64], acc, 0, 0, 0);
    }
    int co = cohalf * 16 + (lane & 15);
    if (co < 27) {
      float bv = b_om[co];
      int px = pxg * 16 + (lane >> 4) * 4;
      #pragma unroll
      for (int r = 0; r < 4; r++)
        omv[(px + r) * 28 + co] = acc[r] + bv;
    }
  }
  __syncthreads();                                    // A dead, omv valid

  // ---- phase 3: deform in two 32-px halves
  for (int h2 = 0; h2 < 2; h2++) {
    // prm: 288 threads, one (pix_local, tap) each
    if (tid < 32 * KK) {
      int pl = tid / KK, k = tid % KK;
      const float* omp = omv + (h2 * 32 + pl) * 28;
      float dy = omp[2 * k], dx = omp[2 * k + 1];
      float mk = 2.f / (1.f + expf(-omp[18 + k]));
      float ys = (float)(h - 1 + k / 3) + dy;
      float xs = (float)(wb + h2 * 32 + pl - 1 + k % 3) + dx;
      float y0f = floorf(ys), x0f = floorf(xs);
      float ty = ys - y0f, tx = xs - x0f;
      int yi = (int)y0f, xi = (int)x0f;
      bool y0v = (unsigned)yi < HH, y1v = (unsigned)(yi + 1) < HH;
      bool x0v = (unsigned)xi < WWD, x1v = (unsigned)(xi + 1) < WWD;
      float w00 = (1.f - ty) * (1.f - tx) * mk * ((y0v && x0v) ? 1.f : 0.f);
      float w01 = (1.f - ty) * tx * mk * ((y0v && x1v) ? 1.f : 0.f);
      float w10 = ty * (1.f - tx) * mk * ((y1v && x0v) ? 1.f : 0.f);
      float w11 = ty * tx * mk * ((y1v && x1v) ? 1.f : 0.f);
      int* p = prm[tid];
      // offsets in u32 units of NHWC bf16: row = 128*32, col = 32
      *(int4*)p = make_int4(min(max(yi, 0), HH - 1) * (WWD * 32),
                            min(max(yi + 1, 0), HH - 1) * (WWD * 32),
                            min(max(xi, 0), WWD - 1) * 32,
                            min(max(xi + 1, 0), WWD - 1) * 32);
      *(int4*)(p + 4) = make_int4(__float_as_int(w00), __float_as_int(w01),
                                  __float_as_int(w10), __float_as_int(w11));
    }
    __syncthreads();
    // gather: 16-lane group per (pix,tap), lane covers 4 ch (uint2); 9 iters
    {
      int lane4 = tid & 15, g16 = tid >> 4;          // 32 groups
      const u32* ytb = yt32 + lane4 * 2;
      #pragma unroll
      for (int i = 0; i < 9; i++) {
        int u = g16 + 32 * i;                        // 0..287
        int k = u % 9, pix = u / 9;
        int4 pa = *(const int4*)prm[u];
        int4 pb = *(const int4*)(prm[u] + 4);
        uint2 v00 = *(const uint2*)(ytb + pa.x + pa.z);
        uint2 v01 = *(const uint2*)(ytb + pa.x + pa.w);
        uint2 v10 = *(const uint2*)(ytb + pa.y + pa.z);
        uint2 v11 = *(const uint2*)(ytb + pa.y + pa.w);
        float w00 = __int_as_float(pb.x), w01 = __int_as_float(pb.y);
        float w10 = __int_as_float(pb.z), w11 = __int_as_float(pb.w);
        float a0 = fmaf(bfLO(v00.x), w00, fmaf(bfLO(v01.x), w01,
                   fmaf(bfLO(v10.x), w10, bfLO(v11.x) * w11)));
        float a1 = fmaf(bfHI(v00.x), w00, fmaf(bfHI(v01.x), w01,
                   fmaf(bfHI(v10.x), w10, bfHI(v11.x) * w11)));
        float a2 = fmaf(bfLO(v00.y), w00, fmaf(bfLO(v01.y), w01,
                   fmaf(bfLO(v10.y), w10, bfLO(v11.y) * w11)));
        float a3 = fmaf(bfHI(v00.y), w00, fmaf(bfHI(v01.y), w01,
                   fmaf(bfHI(v10.y), w10, bfHI(v11.y) * w11)));
        uint2 o = {f2bf2(a0, a1), f2bf2(a2, a3)};
        *(uint2*)(dsamp32 + pix * (DROW / 2) + k * 32 + lane4 * 2) = o;
      }
    }
    __syncthreads();
    // deform MFMA: 8 waves = 4 coq x 2 pxg; 16px x 16co each
    {
      int qq = q & 3, pxg = q >> 2;
      f32x4 acc = {0.f, 0.f, 0.f, 0.f};
      const u16* arow = dsamp + (pxg * 16 + (lane & 15)) * DROW + (lane >> 4) * 8;
      const bf16x8* bp = (const bf16x8*)pk_dc + (size_t)(qq * KSTEP) * 64 + lane;
      #pragma unroll
      for (int s = 0; s < KSTEP; s++) {
        bf16x8 a = *(const bf16x8*)(arow + s * 32);
        acc = __builtin_amdgcn_mfma_f32_16x16x32_bf16(a, bp[(size_t)s * 64], acc, 0, 0, 0);
      }
      int co = qq * 16 + (lane & 15);
      int px = h2 * 32 + pxg * 16 + (lane >> 4) * 4;
      float bv = b_dc[co];
      size_t obase = ((size_t)b * HWv + hwb + px) * 64 + co;
      #pragma unroll
      for (int r = 0; r < 4; r++)
        ob[obase + (size_t)r * 64] =
            f2bf(acc[r] + bv + bf2f(x0bf[obase + (size_t)r * 64]));
    }
    __syncthreads();                                 // protect dsamp/prm
  }
}

// ====== 3x3 direct conv, 64-px strip, bf16 NHWC in (uint2 copy stage) =====
// MODE 1: +leaky -> z1 bf16 NHWC. MODE 2: +res(ob bf16) -> out f32 NCHW
template <int MODE>
__global__ __launch_bounds__(512) void rconv_k(const u16* __restrict__ in,
    const u16* __restrict__ res, const u16* __restrict__ wpack,
    const float* __restrict__ bias, void* __restrict__ outp) {
  __shared__ __align__(16) u16 samp[3 * RCOLS * CSTR];  // 28,512 B
  u32* samp32 = (u32*)samp;
  int tid = threadIdx.x;
  int pixbase = blockIdx.x * 64;
  int hwb = pixbase & (HWv - 1);
  int b = pixbase >> 14;
  int h = hwb >> 7, wb = hwb & 127;

  // stage raw tile [3 rows][66 cols][64 ch] bf16 — uint2 copy, 16-lane/rc
  {
    int lane4 = tid & 15, g16 = tid >> 4;            // 32 groups
    const u32* inb = (const u32*)in + (size_t)b * HWv * 32 + lane4 * 2;
    #pragma unroll
    for (int i = 0; i < 7; i++) {
      int u = g16 + 32 * i;
      if (u < 198) {
        int r = u / 66, c = u % 66;
        int hh = h - 1 + r, ww = wb - 1 + c;
        uint2 v = {0u, 0u};
        if ((unsigned)hh < HH && (unsigned)ww < WWD)
          v = *(const uint2*)(inb + (size_t)(hh * WWD + ww) * 32);
        *(uint2*)(samp32 + (r * 66 + c) * (CSTR / 2) + lane4 * 2) = v;
      }
    }
  }
  __syncthreads();

  int lane = tid & 63, q = tid >> 6;
  int copair = q & 1, pxg = q >> 1;           // co-half, px-group (0..3)
  f32x4 acc[2] = {{0,0,0,0},{0,0,0,0}};
  const bf16x8* bp = (const bf16x8*)wpack + (size_t)(copair * 2 * KSTEP) * 64 + lane;
  #pragma unroll
  for (int s = 0; s < KSTEP; s++) {
    int kk = s >> 1;
    int addr = ((kk / 3) * 66 + pxg * 16 + (lane & 15) + (kk % 3)) * CSTR
               + (s & 1) * 32 + (lane >> 4) * 8;
    bf16x8 a = *(const bf16x8*)(samp + addr);
    acc[0] = __builtin_amdgcn_mfma_f32_16x16x32_bf16(a, bp[(size_t)s * 64], acc[0], 0, 0, 0);
    acc[1] = __builtin_amdgcn_mfma_f32_16x16x32_bf16(a, bp[(size_t)(KSTEP + s) * 64], acc[1], 0, 0, 0);
  }

  int px = pxg * 16 + (lane >> 4) * 4;
  if (MODE == 1) {
    u16* outb = (u16*)outp;
    #pragma unroll
    for (int t = 0; t < 2; t++) {
      int co = copair * 32 + t * 16 + (lane & 15);
      float bv = bias[co];
      size_t obase = ((size_t)b * HWv + hwb + px) * 64 + co;
      #pragma unroll
      for (int r = 0; r < 4; r++) {
        float v = acc[t][r] + bv;
        outb[obase + (size_t)r * 64] = f2bf(v >= 0.f ? v : 0.2f * v);
      }
    }
  } else {
    float* outf = (float*)outp;
    float* ot = (float*)samp;                 // [64 co][68] = 17,408 B
    __syncthreads();                          // tile reads done
    #pragma unroll
    for (int t = 0; t < 2; t++) {
      int co = copair * 32 + t * 16 + (lane & 15);
      float bv = bias[co];
      size_t rbase = ((size_t)b * HWv + hwb + px) * 64 + co;
      #pragma unroll
      for (int r = 0; r < 4; r++)
        ot[co * 68 + px + r] = acc[t][r] + bv + bf2f(res[rbase + (size_t)r * 64]);
    }
    __syncthreads();
    int co = tid >> 3, seg = tid & 7;         // 64 co x 8 px-segments
    const float4* src4 = (const float4*)(ot + co * 68 + seg * 8);
    float4 v0 = src4[0], v1 = src4[1];
    float* dst = outf + ((size_t)b * CCH + co) * HWv + hwb + seg * 8;
    *(float4*)dst = v0;
    *(float4*)(dst + 4) = v1;
  }
}

extern "C" void kernel_launch(void* const* d_in, const int* in_sizes, int n_in,
                              void* d_out, int out_size, void* d_ws, size_t ws_size,
                              hipStream_t stream) {
  const float* x    = (const float*)d_in[0];
  const float* y    = (const float*)d_in[1];
  const float* w0   = (const float*)d_in[2];
  const float* b0   = (const float*)d_in[3];
  const float* w_om = (const float*)d_in[4];
  const float* b_om = (const float*)d_in[5];
  const float* w_dc = (const float*)d_in[6];
  const float* b_dc = (const float*)d_in[7];
  const float* w1   = (const float*)d_in[8];
  const float* b1   = (const float*)d_in[9];
  const float* w2   = (const float*)d_in[10];
  const float* b2   = (const float*)d_in[11];
  float* out = (float*)d_out;

  const size_t NFULL = (size_t)BB * CCH * HWv;   // 2,097,152
  const size_t NPACK = 4 * KSTEP * 64 * 8;       // 36,864 bf16
  const size_t NPACKOM = 2 * OMKS * 64 * 8;      // 36,864
  u16* x0bf = (u16*)d_ws;                        // NFULL bf16
  u16* ob   = x0bf + NFULL;                      // NFULL bf16
  u16* z1   = ob + NFULL;                        // NFULL bf16
  u16* yt   = z1;                                // alias: yt dead before z1 written
  u16* pk_dc = z1 + NFULL;
  u16* pk_w1 = pk_dc + NPACK;
  u16* pk_w2 = pk_w1 + NPACK;
  u16* pk_om = pk_w2 + NPACK;
  u16* pk_0  = pk_om + NPACKOM;

  // 0. all weight packs, one launch (592 blocks)
  pack_all_k<<<592, 256, 0, stream>>>(w_dc, w1, w2, w_om, w0,
                                      pk_dc, pk_w1, pk_w2, pk_om, pk_0);
  // 1. fused y-transpose + conv1x1 -> yt, x0bf (NHWC bf16)
  conv1x1y_k<<<(int)((size_t)BB * HWv / 64), 256, 0, stream>>>(
      x, y, pk_0, b0, x0bf, yt);
  // 2. fused om conv + deform conv + x0 residual -> ob (NHWC bf16)
  omd_k<<<(int)((size_t)BB * HWv / 64), 512, 0, stream>>>(
      x0bf, yt, pk_om, pk_dc, b_om, b_dc, ob);
  // 3. conv w1 + leaky -> z1 (NHWC bf16)
  rconv_k<1><<<(int)((size_t)BB * HWv / 64), 512, 0, stream>>>(ob, nullptr, pk_w1, b1, z1);
  // 4. conv w2 + residual ob -> out (NCHW f32 final)
  rconv_k<2><<<(int)((size_t)BB * HWv / 64), 512, 0, stream>>>(z1, ob, pk_w2, b2, out);
}

// Round 11
// 63.926 us; speedup vs baseline: 2.1104x; 1.0203x over previous
//
#include <hip/hip_runtime.h>
#include <hip/hip_bf16.h>
#include <math.h>

#define BB 2
#define CCH 64
#define HH 128
#define WWD 128
#define HWv (HH*WWD)
#define KK 9
#define KSTEP 18        // 576/32
#define OMKS 36         // 1152/32
// 2-row x 32-col tiles: stage [4 rows][34 cols][C]
#define TCOLS 34
#define CSTR 72         // padded 64-ch run stride (bf16): 64 + 8
#define CSTR2 136       // padded 128-ch run stride (bf16): 128 + 8
#define DROW 584        // deform samp row stride (bf16): 576 + 8

typedef __attribute__((ext_vector_type(8))) short bf16x8;
typedef __attribute__((ext_vector_type(4))) float f32x4;
typedef unsigned short u16;
typedef unsigned int u32;

__device__ inline u16 f2bf(float f) {
  __hip_bfloat16 h = __float2bfloat16(f);
  return *reinterpret_cast<u16*>(&h);
}
__device__ inline u32 f2bf2(float lo, float hi) {
  return ((u32)f2bf(hi) << 16) | (u32)f2bf(lo);
}
__device__ inline float bfLO(u32 v) { return __uint_as_float(v << 16); }
__device__ inline float bfHI(u32 v) { return __uint_as_float(v & 0xffff0000u); }
__device__ inline float bf2f(u16 v) { return __uint_as_float((u32)v << 16); }

// ============ ALL weight packs in one launch ===============================
// blocks [0,144) w_dc, [144,288) w1, [288,432) w2 (tap-major, CIN=64)
// blocks [432,576) w_om (tap-major, CIN=128, co<27), [576,592) w0 (ci-major)
__global__ __launch_bounds__(256) void pack_all_k(
    const float* __restrict__ w_dc, const float* __restrict__ w1,
    const float* __restrict__ w2, const float* __restrict__ w_om,
    const float* __restrict__ w0, u16* __restrict__ pk_dc,
    u16* __restrict__ pk_w1, u16* __restrict__ pk_w2,
    u16* __restrict__ pk_om, u16* __restrict__ pk_0) {
  int blk = blockIdx.x;
  int tid = threadIdx.x;
  if (blk < 432) {
    const float* w = blk < 144 ? w_dc : (blk < 288 ? w1 : w2);
    u16* dst = blk < 144 ? pk_dc : (blk < 288 ? pk_w1 : pk_w2);
    int idx = (blk % 144) * 256 + tid;
    int j = idx & 7, l = (idx >> 3) & 63;
    int s = (idx >> 9) % 18, q = idx / 9216;
    int co = q * 16 + (l & 15);
    int kp = s * 32 + (l >> 4) * 8 + j;          // < 576
    dst[idx] = f2bf(w[(co * 64 + (kp & 63)) * 9 + (kp >> 6)]);
  } else if (blk < 576) {
    int idx = (blk - 432) * 256 + tid;
    int j = idx & 7, l = (idx >> 3) & 63;
    int s = (idx >> 9) % 36, q = idx / 18432;
    int co = q * 16 + (l & 15);
    int kp = s * 32 + (l >> 4) * 8 + j;          // < 1152
    pk_om[idx] = (co < 27)
        ? f2bf(w_om[(co * 128 + (kp & 127)) * 9 + (kp >> 7)]) : (u16)0;
  } else {
    int idx = (blk - 576) * 256 + tid;
    int j = idx & 7, l = (idx >> 3) & 63;
    int s = (idx >> 9) & 1, q = idx / 1024;
    int co = q * 16 + (l & 15);
    int k = s * 32 + (l >> 4) * 8 + j;           // < 64
    pk_0[idx] = f2bf(w0[co * 64 + k]);
  }
}

// ==== fused: y NCHW->NHWC bf16 + conv1x1 MFMA (64 px, K=64) -> x0bf ========
__global__ __launch_bounds__(256) void conv1x1y_k(const float* __restrict__ x,
    const float* __restrict__ y, const u16* __restrict__ wpack,
    const float* __restrict__ b0, u16* __restrict__ x0bf,
    u16* __restrict__ yt) {
  #define S1ROW 72
  __shared__ __align__(16) float smem[64 * 65];    // 16,640 B; aliased below
  u16* samp1 = (u16*)smem;                         // needs 9,216 B
  int tid = threadIdx.x;
  int lane = tid & 63, q = tid >> 6;
  int pixbase = blockIdx.x * 64;
  int hwb = pixbase & (HWv - 1);
  int b = pixbase >> 14;

  // ---- phase Y: transpose y for these 64 px ----
  {
    const float* src = y + (size_t)b * CCH * HWv;
    #pragma unroll
    for (int i = 0; i < 16; i++) {
      int ci = i * 4 + q;
      smem[ci * 65 + lane] = src[(size_t)ci * HWv + hwb + lane];
    }
    __syncthreads();
    u32* dst32 = (u32*)(yt + ((size_t)b * HWv + hwb) * 64);
    int lane2 = tid & 31, rr = tid >> 5;
    #pragma unroll
    for (int i = 0; i < 8; i++) {
      int row = i * 8 + rr;
      dst32[row * 32 + lane2] = f2bf2(smem[(2 * lane2) * 65 + row],
                                      smem[(2 * lane2 + 1) * 65 + row]);
    }
    __syncthreads();                               // smem dead -> reuse
  }

  // ---- phase X: conv1x1 ----
  {
    u16 tmp[16];
    #pragma unroll
    for (int i = 0; i < 16; i++) {
      int ci = q * 16 + i;
      tmp[i] = f2bf(x[((size_t)b * CCH + ci) * HWv + hwb + lane]);
    }
    #pragma unroll
    for (int i = 0; i < 2; i++)
      *(bf16x8*)(samp1 + lane * S1ROW + q * 16 + i * 8) = *(bf16x8*)(tmp + i * 8);
  }
  __syncthreads();
  f32x4 acc[4] = {{0,0,0,0},{0,0,0,0},{0,0,0,0},{0,0,0,0}};
  int g = lane >> 4;
  const bf16x8* bp = (const bf16x8*)wpack + (size_t)(q * 2) * 64 + lane;
  #pragma unroll
  for (int s = 0; s < 2; s++) {
    bf16x8 bf = bp[(size_t)s * 64];
    #pragma unroll
    for (int t = 0; t < 4; t++) {
      bf16x8 a = *(const bf16x8*)(samp1 + (t * 16 + (lane & 15)) * S1ROW + g * 8 + s * 32);
      acc[t] = __builtin_amdgcn_mfma_f32_16x16x32_bf16(a, bf, acc[t], 0, 0, 0);
    }
  }
  int co = q * 16 + (lane & 15);
  float bv = b0[co];
  u16* dst = x0bf + ((size_t)b * HWv + hwb + g * 4) * 64 + co;
  #pragma unroll
  for (int t = 0; t < 4; t++)
    #pragma unroll
    for (int r = 0; r < 4; r++)
      dst[(size_t)(t * 16 + r) * 64] = f2bf(acc[t][r] + bv);
}

// ==== FUSED om conv + deform conv, 2-row x 32-col tile, 512 thr ============
// phase 1: stage [4 rows][34 cols][128ch] bf16 (uint2)
// phase 2: om MFMA (K=1152) -> omv LDS [64px][28] f32 (bias added)
// phase 3: two rows: prm -> branch-free gather (uint2) -> MFMA -> ob
__global__ __launch_bounds__(512) void omd_k(const u16* __restrict__ x0bf,
    const u16* __restrict__ yt, const u16* __restrict__ pk_om,
    const u16* __restrict__ pk_dc, const float* __restrict__ b_om,
    const float* __restrict__ b_dc, u16* __restrict__ ob) {
  __shared__ __align__(16) u16 A[18688];           // 37,376 B (stage 36,992 / dsamp)
  __shared__ __align__(16) int prm[288][8];        //  9,216 B
  __shared__ __align__(16) float omv[64 * 28];     //  7,168 B  (total 53,760)
  u32* A32 = (u32*)A;
  u32* dsamp32 = (u32*)A;                          // [32][292] u32
  u16* dsamp = A;
  int tid = threadIdx.x;
  int lane = tid & 63, q = tid >> 6;
  int blk = blockIdx.x;                            // 512 blocks
  int wq = blk & 3, rp = (blk >> 2) & 63, b = blk >> 8;
  int h0 = rp * 2, wb = wq * 32;
  const u32* x0b32 = (const u32*)x0bf + (size_t)b * HWv * 32;
  const u32* yt32  = (const u32*)yt + (size_t)b * HWv * 32;

  // ---- phase 1: stage tile; 16 groups of 32 lanes (uint2 = 4 ch each)
  {
    int lane2 = tid & 31, g16 = tid >> 5;
    int cofs = lane2 * 2;
    const u32* srcb = (lane2 < 16) ? (x0b32 + cofs) : (yt32 + cofs - 32);
    #pragma unroll
    for (int i = 0; i < 9; i++) {
      int u = g16 + 16 * i;
      if (u < 4 * TCOLS) {
        int r = u / TCOLS, c = u % TCOLS;
        int hh = h0 - 1 + r, ww = wb - 1 + c;
        uint2 v = {0u, 0u};
        if ((unsigned)hh < HH && (unsigned)ww < WWD)
          v = *(const uint2*)(srcb + (size_t)(hh * WWD + ww) * 32);
        *(uint2*)(A32 + u * (CSTR2 / 2) + cofs) = v;
      }
    }
  }
  __syncthreads();

  // ---- phase 2: om MFMA; 8 waves = row x colgroup x cohalf
  {
    int r = q & 1, cg = (q >> 1) & 1, cohalf = q >> 2;
    f32x4 acc = {0.f, 0.f, 0.f, 0.f};
    const bf16x8* bp = (const bf16x8*)pk_om + (size_t)(cohalf * OMKS) * 64 + lane;
    #pragma unroll
    for (int s = 0; s < OMKS; s++) {
      int kk = s >> 2;                             // tap
      int addr = ((r + kk / 3) * TCOLS + cg * 16 + (lane & 15) + (kk % 3)) * CSTR2
                 + (s & 3) * 32 + (lane >> 4) * 8;
      bf16x8 a = *(const bf16x8*)(A + addr);
      acc = __builtin_amdgcn_mfma_f32_16x16x32_bf16(a, bp[(size_t)s * 64], acc, 0, 0, 0);
    }
    int co = cohalf * 16 + (lane & 15);
    if (co < 27) {
      float bv = b_om[co];
      int px = r * 32 + cg * 16 + (lane >> 4) * 4;
      #pragma unroll
      for (int j = 0; j < 4; j++)
        omv[(px + j) * 28 + co] = acc[j] + bv;
    }
  }
  __syncthreads();                                 // A dead, omv valid

  // ---- phase 3: deform, one row (32 px) per half
  for (int h2 = 0; h2 < 2; h2++) {
    if (tid < 32 * KK) {
      int pl = tid / KK, k = tid % KK;             // pl = col 0..31
      const float* omp = omv + (h2 * 32 + pl) * 28;
      float dy = omp[2 * k], dx = omp[2 * k + 1];
      float mk = 2.f / (1.f + expf(-omp[18 + k]));
      float ys = (float)(h0 + h2 - 1 + k / 3) + dy;
      float xs = (float)(wb + pl - 1 + k % 3) + dx;
      float y0f = floorf(ys), x0f = floorf(xs);
      float ty = ys - y0f, tx = xs - x0f;
      int yi = (int)y0f, xi = (int)x0f;
      bool y0v = (unsigned)yi < HH, y1v = (unsigned)(yi + 1) < HH;
      bool x0v = (unsigned)xi < WWD, x1v = (unsigned)(xi + 1) < WWD;
      float w00 = (1.f - ty) * (1.f - tx) * mk * ((y0v && x0v) ? 1.f : 0.f);
      float w01 = (1.f - ty) * tx * mk * ((y0v && x1v) ? 1.f : 0.f);
      float w10 = ty * (1.f - tx) * mk * ((y1v && x0v) ? 1.f : 0.f);
      float w11 = ty * tx * mk * ((y1v && x1v) ? 1.f : 0.f);
      int* p = prm[tid];
      // offsets in u32 units of NHWC bf16: row = 128*32, col = 32
      *(int4*)p = make_int4(min(max(yi, 0), HH - 1) * (WWD * 32),
                            min(max(yi + 1, 0), HH - 1) * (WWD * 32),
                            min(max(xi, 0), WWD - 1) * 32,
                            min(max(xi + 1, 0), WWD - 1) * 32);
      *(int4*)(p + 4) = make_int4(__float_as_int(w00), __float_as_int(w01),
                                  __float_as_int(w10), __float_as_int(w11));
    }
    __syncthreads();
    // gather: 16-lane group per (pix,tap), lane covers 4 ch (uint2); 9 iters
    {
      int lane4 = tid & 15, g16 = tid >> 4;        // 32 groups
      const u32* ytb = yt32 + lane4 * 2;
      #pragma unroll
      for (int i = 0; i < 9; i++) {
        int u = g16 + 32 * i;                      // 0..287
        int k = u % 9, pix = u / 9;
        int4 pa = *(const int4*)prm[u];
        int4 pb = *(const int4*)(prm[u] + 4);
        uint2 v00 = *(const uint2*)(ytb + pa.x + pa.z);
        uint2 v01 = *(const uint2*)(ytb + pa.x + pa.w);
        uint2 v10 = *(const uint2*)(ytb + pa.y + pa.z);
        uint2 v11 = *(const uint2*)(ytb + pa.y + pa.w);
        float w00 = __int_as_float(pb.x), w01 = __int_as_float(pb.y);
        float w10 = __int_as_float(pb.z), w11 = __int_as_float(pb.w);
        float a0 = fmaf(bfLO(v00.x), w00, fmaf(bfLO(v01.x), w01,
                   fmaf(bfLO(v10.x), w10, bfLO(v11.x) * w11)));
        float a1 = fmaf(bfHI(v00.x), w00, fmaf(bfHI(v01.x), w01,
                   fmaf(bfHI(v10.x), w10, bfHI(v11.x) * w11)));
        float a2 = fmaf(bfLO(v00.y), w00, fmaf(bfLO(v01.y), w01,
                   fmaf(bfLO(v10.y), w10, bfLO(v11.y) * w11)));
        float a3 = fmaf(bfHI(v00.y), w00, fmaf(bfHI(v01.y), w01,
                   fmaf(bfHI(v10.y), w10, bfHI(v11.y) * w11)));
        uint2 o = {f2bf2(a0, a1), f2bf2(a2, a3)};
        *(uint2*)(dsamp32 + pix * (DROW / 2) + k * 32 + lane4 * 2) = o;
      }
    }
    __syncthreads();
    // deform MFMA: 8 waves = 4 coq x 2 pxg; 16px x 16co each
    {
      int qq = q & 3, pxg = q >> 2;
      f32x4 acc = {0.f, 0.f, 0.f, 0.f};
      const u16* arow = dsamp + (pxg * 16 + (lane & 15)) * DROW + (lane >> 4) * 8;
      const bf16x8* bp = (const bf16x8*)pk_dc + (size_t)(qq * KSTEP) * 64 + lane;
      #pragma unroll
      for (int s = 0; s < KSTEP; s++) {
        bf16x8 a = *(const bf16x8*)(arow + s * 32);
        acc = __builtin_amdgcn_mfma_f32_16x16x32_bf16(a, bp[(size_t)s * 64], acc, 0, 0, 0);
      }
      int co = qq * 16 + (lane & 15);
      int px = pxg * 16 + (lane >> 4) * 4;
      float bv = b_dc[co];
      size_t obase = ((size_t)b * HWv + (h0 + h2) * WWD + wb + px) * 64 + co;
      #pragma unroll
      for (int j = 0; j < 4; j++)
        ob[obase + (size_t)j * 64] =
            f2bf(acc[j] + bv + bf2f(x0bf[obase + (size_t)j * 64]));
    }
    __syncthreads();                               // protect dsamp/prm
  }
}

// ====== 3x3 direct conv, 2-row x 32-col tile, bf16 NHWC in ================
// MODE 1: +leaky -> z1 bf16 NHWC. MODE 2: +res(ob bf16) -> out f32 NCHW
template <int MODE>
__global__ __launch_bounds__(512) void rconv_k(const u16* __restrict__ in,
    const u16* __restrict__ res, const u16* __restrict__ wpack,
    const float* __restrict__ bias, void* __restrict__ outp) {
  __shared__ __align__(16) u16 samp[4 * TCOLS * CSTR];  // 19,584 B
  u32* samp32 = (u32*)samp;
  int tid = threadIdx.x;
  int blk = blockIdx.x;                            // 512 blocks
  int wq = blk & 3, rp = (blk >> 2) & 63, b = blk >> 8;
  int h0 = rp * 2, wb = wq * 32;

  // stage [4 rows][34 cols][64 ch] bf16 — uint2 copy, 32 groups of 16 lanes
  {
    int lane4 = tid & 15, g16 = tid >> 4;
    const u32* inb = (const u32*)in + (size_t)b * HWv * 32 + lane4 * 2;
    #pragma unroll
    for (int i = 0; i < 5; i++) {
      int u = g16 + 32 * i;
      if (u < 4 * TCOLS) {
        int r = u / TCOLS, c = u % TCOLS;
        int hh = h0 - 1 + r, ww = wb - 1 + c;
        uint2 v = {0u, 0u};
        if ((unsigned)hh < HH && (unsigned)ww < WWD)
          v = *(const uint2*)(inb + (size_t)(hh * WWD + ww) * 32);
        *(uint2*)(samp32 + u * (CSTR / 2) + lane4 * 2) = v;
      }
    }
  }
  __syncthreads();

  int lane = tid & 63, q = tid >> 6;
  int r = q & 1, cg = (q >> 1) & 1, copair = q >> 2;
  f32x4 acc[2] = {{0,0,0,0},{0,0,0,0}};
  const bf16x8* bp = (const bf16x8*)wpack + (size_t)(copair * 2 * KSTEP) * 64 + lane;
  #pragma unroll
  for (int s = 0; s < KSTEP; s++) {
    int kk = s >> 1;
    int addr = ((r + kk / 3) * TCOLS + cg * 16 + (lane & 15) + (kk % 3)) * CSTR
               + (s & 1) * 32 + (lane >> 4) * 8;
    bf16x8 a = *(const bf16x8*)(samp + addr);
    acc[0] = __builtin_amdgcn_mfma_f32_16x16x32_bf16(a, bp[(size_t)s * 64], acc[0], 0, 0, 0);
    acc[1] = __builtin_amdgcn_mfma_f32_16x16x32_bf16(a, bp[(size_t)(KSTEP + s) * 64], acc[1], 0, 0, 0);
  }

  int pxc = cg * 16 + (lane >> 4) * 4;             // col within 32
  int hwp = (h0 + r) * WWD + wb + pxc;
  if (MODE == 1) {
    u16* outb = (u16*)outp;
    #pragma unroll
    for (int t = 0; t < 2; t++) {
      int co = copair * 32 + t * 16 + (lane & 15);
      float bv = bias[co];
      size_t obase = ((size_t)b * HWv + hwp) * 64 + co;
      #pragma unroll
      for (int j = 0; j < 4; j++) {
        float v = acc[t][j] + bv;
        outb[obase + (size_t)j * 64] = f2bf(v >= 0.f ? v : 0.2f * v);
      }
    }
  } else {
    float* outf = (float*)outp;
    float* ot = (float*)samp;                      // [64 co][72] = 18,432 B
    __syncthreads();                               // tile reads done
    #pragma unroll
    for (int t = 0; t < 2; t++) {
      int co = copair * 32 + t * 16 + (lane & 15);
      float bv = bias[co];
      size_t rbase = ((size_t)b * HWv + hwp) * 64 + co;
      #pragma unroll
      for (int j = 0; j < 4; j++)
        ot[co * 72 + r * 36 + pxc + j] = acc[t][j] + bv + bf2f(res[rbase + (size_t)j * 64]);
    }
    __syncthreads();
    int co = tid >> 3, seg = tid & 7;              // 2 rows x 4 col-segments
    int r2 = seg >> 2, c8 = (seg & 3) * 8;
    const float4* src4 = (const float4*)(ot + co * 72 + r2 * 36 + c8);
    float4 v0 = src4[0], v1 = src4[1];
    float* dst = outf + ((size_t)b * CCH + co) * HWv + (h0 + r2) * WWD + wb + c8;
    *(float4*)dst = v0;
    *(float4*)(dst + 4) = v1;
  }
}

extern "C" void kernel_launch(void* const* d_in, const int* in_sizes, int n_in,
                              void* d_out, int out_size, void* d_ws, size_t ws_size,
                              hipStream_t stream) {
  const float* x    = (const float*)d_in[0];
  const float* y    = (const float*)d_in[1];
  const float* w0   = (const float*)d_in[2];
  const float* b0   = (const float*)d_in[3];
  const float* w_om = (const float*)d_in[4];
  const float* b_om = (const float*)d_in[5];
  const float* w_dc = (const float*)d_in[6];
  const float* b_dc = (const float*)d_in[7];
  const float* w1   = (const float*)d_in[8];
  const float* b1   = (const float*)d_in[9];
  const float* w2   = (const float*)d_in[10];
  const float* b2   = (const float*)d_in[11];
  float* out = (float*)d_out;

  const size_t NFULL = (size_t)BB * CCH * HWv;   // 2,097,152
  const size_t NPACK = 4 * KSTEP * 64 * 8;       // 36,864 bf16
  const size_t NPACKOM = 2 * OMKS * 64 * 8;      // 36,864
  u16* x0bf = (u16*)d_ws;                        // NFULL bf16
  u16* ob   = x0bf + NFULL;                      // NFULL bf16
  u16* z1   = ob + NFULL;                        // NFULL bf16
  u16* yt   = z1;                                // alias: yt dead before z1 written
  u16* pk_dc = z1 + NFULL;
  u16* pk_w1 = pk_dc + NPACK;
  u16* pk_w2 = pk_w1 + NPACK;
  u16* pk_om = pk_w2 + NPACK;
  u16* pk_0  = pk_om + NPACKOM;

  const int NB = (int)((size_t)BB * HWv / 64);   // 512

  // 0. all weight packs, one launch (592 blocks)
  pack_all_k<<<592, 256, 0, stream>>>(w_dc, w1, w2, w_om, w0,
                                      pk_dc, pk_w1, pk_w2, pk_om, pk_0);
  // 1. fused y-transpose + conv1x1 -> yt, x0bf (NHWC bf16)
  conv1x1y_k<<<NB, 256, 0, stream>>>(x, y, pk_0, b0, x0bf, yt);
  // 2. fused om conv + deform conv + x0 residual -> ob (NHWC bf16)
  omd_k<<<NB, 512, 0, stream>>>(x0bf, yt, pk_om, pk_dc, b_om, b_dc, ob);
  // 3. conv w1 + leaky -> z1 (NHWC bf16)
  rconv_k<1><<<NB, 512, 0, stream>>>(ob, nullptr, pk_w1, b1, z1);
  // 4. conv w2 + residual ob -> out (NCHW f32 final)
  rconv_k<2><<<NB, 512, 0, stream>>>(z1, ob, pk_w2, b2, out);
}

// Round 12
// 63.791 us; speedup vs baseline: 2.1149x; 1.0021x over previous
//
#include <hip/hip_runtime.h>
#include <hip/hip_bf16.h>
#include <math.h>

#define BB 2
#define CCH 64
#define HH 128
#define WWD 128
#define HWv (HH*WWD)
#define KK 9
#define KSTEP 18        // 576/32
#define OMKS 36         // 1152/32
// 2-row x 32-col tiles: stage [4 rows][34 cols][C]
#define TCOLS 34
#define CSTR 72         // padded 64-ch run stride (bf16): 64 + 8
#define CSTR2 136       // padded 128-ch run stride (bf16): 128 + 8
#define DROW 584        // deform samp row stride (bf16): 576 + 8

typedef __attribute__((ext_vector_type(8))) short bf16x8;
typedef __attribute__((ext_vector_type(4))) float f32x4;
typedef unsigned short u16;
typedef unsigned int u32;

__device__ inline u16 f2bf(float f) {
  __hip_bfloat16 h = __float2bfloat16(f);
  return *reinterpret_cast<u16*>(&h);
}
__device__ inline u32 f2bf2(float lo, float hi) {
  return ((u32)f2bf(hi) << 16) | (u32)f2bf(lo);
}
__device__ inline float bfLO(u32 v) { return __uint_as_float(v << 16); }
__device__ inline float bfHI(u32 v) { return __uint_as_float(v & 0xffff0000u); }
__device__ inline float bf2f(u16 v) { return __uint_as_float((u32)v << 16); }

// ============ ALL weight packs in one launch ===============================
// blocks [0,144) w_dc, [144,288) w1, [288,432) w2 (tap-major, CIN=64)
// blocks [432,576) w_om (tap-major, CIN=128, co<27), [576,592) w0 (ci-major)
__global__ __launch_bounds__(256) void pack_all_k(
    const float* __restrict__ w_dc, const float* __restrict__ w1,
    const float* __restrict__ w2, const float* __restrict__ w_om,
    const float* __restrict__ w0, u16* __restrict__ pk_dc,
    u16* __restrict__ pk_w1, u16* __restrict__ pk_w2,
    u16* __restrict__ pk_om, u16* __restrict__ pk_0) {
  int blk = blockIdx.x;
  int tid = threadIdx.x;
  if (blk < 432) {
    const float* w = blk < 144 ? w_dc : (blk < 288 ? w1 : w2);
    u16* dst = blk < 144 ? pk_dc : (blk < 288 ? pk_w1 : pk_w2);
    int idx = (blk % 144) * 256 + tid;
    int j = idx & 7, l = (idx >> 3) & 63;
    int s = (idx >> 9) % 18, q = idx / 9216;
    int co = q * 16 + (l & 15);
    int kp = s * 32 + (l >> 4) * 8 + j;          // < 576
    dst[idx] = f2bf(w[(co * 64 + (kp & 63)) * 9 + (kp >> 6)]);
  } else if (blk < 576) {
    int idx = (blk - 432) * 256 + tid;
    int j = idx & 7, l = (idx >> 3) & 63;
    int s = (idx >> 9) % 36, q = idx / 18432;
    int co = q * 16 + (l & 15);
    int kp = s * 32 + (l >> 4) * 8 + j;          // < 1152
    pk_om[idx] = (co < 27)
        ? f2bf(w_om[(co * 128 + (kp & 127)) * 9 + (kp >> 7)]) : (u16)0;
  } else {
    int idx = (blk - 576) * 256 + tid;
    int j = idx & 7, l = (idx >> 3) & 63;
    int s = (idx >> 9) & 1, q = idx / 1024;
    int co = q * 16 + (l & 15);
    int k = s * 32 + (l >> 4) * 8 + j;           // < 64
    pk_0[idx] = f2bf(w0[co * 64 + k]);
  }
}

// ==== fused: y NCHW->NHWC bf16 + conv1x1 MFMA (64 px, K=64) -> x0bf ========
__global__ __launch_bounds__(256) void conv1x1y_k(const float* __restrict__ x,
    const float* __restrict__ y, const u16* __restrict__ wpack,
    const float* __restrict__ b0, u16* __restrict__ x0bf,
    u16* __restrict__ yt) {
  #define S1ROW 72
  __shared__ __align__(16) float smem[64 * 65];    // 16,640 B; aliased below
  u16* samp1 = (u16*)smem;                         // needs 9,216 B
  int tid = threadIdx.x;
  int lane = tid & 63, q = tid >> 6;
  int pixbase = blockIdx.x * 64;
  int hwb = pixbase & (HWv - 1);
  int b = pixbase >> 14;

  // ---- phase Y: transpose y for these 64 px ----
  {
    const float* src = y + (size_t)b * CCH * HWv;
    #pragma unroll
    for (int i = 0; i < 16; i++) {
      int ci = i * 4 + q;
      smem[ci * 65 + lane] = src[(size_t)ci * HWv + hwb + lane];
    }
    __syncthreads();
    u32* dst32 = (u32*)(yt + ((size_t)b * HWv + hwb) * 64);
    int lane2 = tid & 31, rr = tid >> 5;
    #pragma unroll
    for (int i = 0; i < 8; i++) {
      int row = i * 8 + rr;
      dst32[row * 32 + lane2] = f2bf2(smem[(2 * lane2) * 65 + row],
                                      smem[(2 * lane2 + 1) * 65 + row]);
    }
    __syncthreads();                               // smem dead -> reuse
  }

  // ---- phase X: conv1x1 ----
  {
    u16 tmp[16];
    #pragma unroll
    for (int i = 0; i < 16; i++) {
      int ci = q * 16 + i;
      tmp[i] = f2bf(x[((size_t)b * CCH + ci) * HWv + hwb + lane]);
    }
    #pragma unroll
    for (int i = 0; i < 2; i++)
      *(bf16x8*)(samp1 + lane * S1ROW + q * 16 + i * 8) = *(bf16x8*)(tmp + i * 8);
  }
  __syncthreads();
  f32x4 acc[4] = {{0,0,0,0},{0,0,0,0},{0,0,0,0},{0,0,0,0}};
  int g = lane >> 4;
  const bf16x8* bp = (const bf16x8*)wpack + (size_t)(q * 2) * 64 + lane;
  #pragma unroll
  for (int s = 0; s < 2; s++) {
    bf16x8 bf = bp[(size_t)s * 64];
    #pragma unroll
    for (int t = 0; t < 4; t++) {
      bf16x8 a = *(const bf16x8*)(samp1 + (t * 16 + (lane & 15)) * S1ROW + g * 8 + s * 32);
      acc[t] = __builtin_amdgcn_mfma_f32_16x16x32_bf16(a, bf, acc[t], 0, 0, 0);
    }
  }
  int co = q * 16 + (lane & 15);
  float bv = b0[co];
  u16* dst = x0bf + ((size_t)b * HWv + hwb + g * 4) * 64 + co;
  #pragma unroll
  for (int t = 0; t < 4; t++)
    #pragma unroll
    for (int r = 0; r < 4; r++)
      dst[(size_t)(t * 16 + r) * 64] = f2bf(acc[t][r] + bv);
}

// ==== FUSED om conv + deform conv, 2-row x 32-col tile, 512 thr ============
// phase 1: stage [4 rows][34 cols][128ch] bf16 (uint2)
// phase 2: om MFMA (K=1152) -> omv LDS [64px][28] f32 (bias added)
// phase 3: two rows: prm -> branch-free gather (uint2) -> MFMA -> ob
__global__ __launch_bounds__(512) void omd_k(const u16* __restrict__ x0bf,
    const u16* __restrict__ yt, const u16* __restrict__ pk_om,
    const u16* __restrict__ pk_dc, const float* __restrict__ b_om,
    const float* __restrict__ b_dc, u16* __restrict__ ob) {
  __shared__ __align__(16) u16 A[18688];           // 37,376 B (stage 36,992 / dsamp)
  __shared__ __align__(16) int prm[288][8];        //  9,216 B
  __shared__ __align__(16) float omv[64 * 28];     //  7,168 B  (total 53,760)
  u32* A32 = (u32*)A;
  u32* dsamp32 = (u32*)A;                          // [32][292] u32
  u16* dsamp = A;
  int tid = threadIdx.x;
  int lane = tid & 63, q = tid >> 6;
  int blk = blockIdx.x;                            // 512 blocks
  int wq = blk & 3, rp = (blk >> 2) & 63, b = blk >> 8;
  int h0 = rp * 2, wb = wq * 32;
  const u32* x0b32 = (const u32*)x0bf + (size_t)b * HWv * 32;
  const u32* yt32  = (const u32*)yt + (size_t)b * HWv * 32;

  // ---- phase 1: stage tile; 16 groups of 32 lanes (uint2 = 4 ch each)
  {
    int lane2 = tid & 31, g16 = tid >> 5;
    int cofs = lane2 * 2;
    const u32* srcb = (lane2 < 16) ? (x0b32 + cofs) : (yt32 + cofs - 32);
    #pragma unroll
    for (int i = 0; i < 9; i++) {
      int u = g16 + 16 * i;
      if (u < 4 * TCOLS) {
        int r = u / TCOLS, c = u % TCOLS;
        int hh = h0 - 1 + r, ww = wb - 1 + c;
        uint2 v = {0u, 0u};
        if ((unsigned)hh < HH && (unsigned)ww < WWD)
          v = *(const uint2*)(srcb + (size_t)(hh * WWD + ww) * 32);
        *(uint2*)(A32 + u * (CSTR2 / 2) + cofs) = v;
      }
    }
  }
  __syncthreads();

  // ---- phase 2: om MFMA; 8 waves = row x colgroup x cohalf
  {
    int r = q & 1, cg = (q >> 1) & 1, cohalf = q >> 2;
    f32x4 acc = {0.f, 0.f, 0.f, 0.f};
    const bf16x8* bp = (const bf16x8*)pk_om + (size_t)(cohalf * OMKS) * 64 + lane;
    #pragma unroll
    for (int s = 0; s < OMKS; s++) {
      int kk = s >> 2;                             // tap
      int addr = ((r + kk / 3) * TCOLS + cg * 16 + (lane & 15) + (kk % 3)) * CSTR2
                 + (s & 3) * 32 + (lane >> 4) * 8;
      bf16x8 a = *(const bf16x8*)(A + addr);
      acc = __builtin_amdgcn_mfma_f32_16x16x32_bf16(a, bp[(size_t)s * 64], acc, 0, 0, 0);
    }
    int co = cohalf * 16 + (lane & 15);
    if (co < 27) {
      float bv = b_om[co];
      int px = r * 32 + cg * 16 + (lane >> 4) * 4;
      #pragma unroll
      for (int j = 0; j < 4; j++)
        omv[(px + j) * 28 + co] = acc[j] + bv;
    }
  }
  __syncthreads();                                 // A dead, omv valid

  // ---- phase 3: deform, one row (32 px) per half
  for (int h2 = 0; h2 < 2; h2++) {
    if (tid < 32 * KK) {
      int pl = tid / KK, k = tid % KK;             // pl = col 0..31
      const float* omp = omv + (h2 * 32 + pl) * 28;
      float dy = omp[2 * k], dx = omp[2 * k + 1];
      float mk = 2.f / (1.f + expf(-omp[18 + k]));
      float ys = (float)(h0 + h2 - 1 + k / 3) + dy;
      float xs = (float)(wb + pl - 1 + k % 3) + dx;
      float y0f = floorf(ys), x0f = floorf(xs);
      float ty = ys - y0f, tx = xs - x0f;
      int yi = (int)y0f, xi = (int)x0f;
      bool y0v = (unsigned)yi < HH, y1v = (unsigned)(yi + 1) < HH;
      bool x0v = (unsigned)xi < WWD, x1v = (unsigned)(xi + 1) < WWD;
      float w00 = (1.f - ty) * (1.f - tx) * mk * ((y0v && x0v) ? 1.f : 0.f);
      float w01 = (1.f - ty) * tx * mk * ((y0v && x1v) ? 1.f : 0.f);
      float w10 = ty * (1.f - tx) * mk * ((y1v && x0v) ? 1.f : 0.f);
      float w11 = ty * tx * mk * ((y1v && x1v) ? 1.f : 0.f);
      int* p = prm[tid];
      // offsets in u32 units of NHWC bf16: row = 128*32, col = 32
      *(int4*)p = make_int4(min(max(yi, 0), HH - 1) * (WWD * 32),
                            min(max(yi + 1, 0), HH - 1) * (WWD * 32),
                            min(max(xi, 0), WWD - 1) * 32,
                            min(max(xi + 1, 0), WWD - 1) * 32);
      *(int4*)(p + 4) = make_int4(__float_as_int(w00), __float_as_int(w01),
                                  __float_as_int(w10), __float_as_int(w11));
    }
    __syncthreads();
    // gather: 16-lane group per (pix,tap), lane covers 4 ch (uint2); 9 iters
    {
      int lane4 = tid & 15, g16 = tid >> 4;        // 32 groups
      const u32* ytb = yt32 + lane4 * 2;
      #pragma unroll
      for (int i = 0; i < 9; i++) {
        int u = g16 + 32 * i;                      // 0..287
        int k = u % 9, pix = u / 9;
        int4 pa = *(const int4*)prm[u];
        int4 pb = *(const int4*)(prm[u] + 4);
        uint2 v00 = *(const uint2*)(ytb + pa.x + pa.z);
        uint2 v01 = *(const uint2*)(ytb + pa.x + pa.w);
        uint2 v10 = *(const uint2*)(ytb + pa.y + pa.z);
        uint2 v11 = *(const uint2*)(ytb + pa.y + pa.w);
        float w00 = __int_as_float(pb.x), w01 = __int_as_float(pb.y);
        float w10 = __int_as_float(pb.z), w11 = __int_as_float(pb.w);
        float a0 = fmaf(bfLO(v00.x), w00, fmaf(bfLO(v01.x), w01,
                   fmaf(bfLO(v10.x), w10, bfLO(v11.x) * w11)));
        float a1 = fmaf(bfHI(v00.x), w00, fmaf(bfHI(v01.x), w01,
                   fmaf(bfHI(v10.x), w10, bfHI(v11.x) * w11)));
        float a2 = fmaf(bfLO(v00.y), w00, fmaf(bfLO(v01.y), w01,
                   fmaf(bfLO(v10.y), w10, bfLO(v11.y) * w11)));
        float a3 = fmaf(bfHI(v00.y), w00, fmaf(bfHI(v01.y), w01,
                   fmaf(bfHI(v10.y), w10, bfHI(v11.y) * w11)));
        uint2 o = {f2bf2(a0, a1), f2bf2(a2, a3)};
        *(uint2*)(dsamp32 + pix * (DROW / 2) + k * 32 + lane4 * 2) = o;
      }
    }
    __syncthreads();
    // deform MFMA: 8 waves = 4 coq x 2 pxg; 16px x 16co each
    {
      int qq = q & 3, pxg = q >> 2;
      f32x4 acc = {0.f, 0.f, 0.f, 0.f};
      const u16* arow = dsamp + (pxg * 16 + (lane & 15)) * DROW + (lane >> 4) * 8;
      const bf16x8* bp = (const bf16x8*)pk_dc + (size_t)(qq * KSTEP) * 64 + lane;
      #pragma unroll
      for (int s = 0; s < KSTEP; s++) {
        bf16x8 a = *(const bf16x8*)(arow + s * 32);
        acc = __builtin_amdgcn_mfma_f32_16x16x32_bf16(a, bp[(size_t)s * 64], acc, 0, 0, 0);
      }
      int co = qq * 16 + (lane & 15);
      int px = pxg * 16 + (lane >> 4) * 4;
      float bv = b_dc[co];
      size_t obase = ((size_t)b * HWv + (h0 + h2) * WWD + wb + px) * 64 + co;
      #pragma unroll
      for (int j = 0; j < 4; j++)
        ob[obase + (size_t)j * 64] =
            f2bf(acc[j] + bv + bf2f(x0bf[obase + (size_t)j * 64]));
    }
    __syncthreads();                               // protect dsamp/prm
  }
}

// ====== 3x3 direct conv, 2-row x 32-col tile, bf16 NHWC in ================
// MODE 1: +leaky -> z1 bf16 NHWC. MODE 2: +res(ob bf16) -> out f32 NCHW
template <int MODE>
__global__ __launch_bounds__(512) void rconv_k(const u16* __restrict__ in,
    const u16* __restrict__ res, const u16* __restrict__ wpack,
    const float* __restrict__ bias, void* __restrict__ outp) {
  __shared__ __align__(16) u16 samp[4 * TCOLS * CSTR];  // 19,584 B
  u32* samp32 = (u32*)samp;
  int tid = threadIdx.x;
  int blk = blockIdx.x;                            // 512 blocks
  int wq = blk & 3, rp = (blk >> 2) & 63, b = blk >> 8;
  int h0 = rp * 2, wb = wq * 32;

  // stage [4 rows][34 cols][64 ch] bf16 — uint2 copy, 32 groups of 16 lanes
  {
    int lane4 = tid & 15, g16 = tid >> 4;
    const u32* inb = (const u32*)in + (size_t)b * HWv * 32 + lane4 * 2;
    #pragma unroll
    for (int i = 0; i < 5; i++) {
      int u = g16 + 32 * i;
      if (u < 4 * TCOLS) {
        int r = u / TCOLS, c = u % TCOLS;
        int hh = h0 - 1 + r, ww = wb - 1 + c;
        uint2 v = {0u, 0u};
        if ((unsigned)hh < HH && (unsigned)ww < WWD)
          v = *(const uint2*)(inb + (size_t)(hh * WWD + ww) * 32);
        *(uint2*)(samp32 + u * (CSTR / 2) + lane4 * 2) = v;
      }
    }
  }
  __syncthreads();

  int lane = tid & 63, q = tid >> 6;
  int r = q & 1, cg = (q >> 1) & 1, copair = q >> 2;
  f32x4 acc[2] = {{0,0,0,0},{0,0,0,0}};
  const bf16x8* bp = (const bf16x8*)wpack + (size_t)(copair * 2 * KSTEP) * 64 + lane;
  #pragma unroll
  for (int s = 0; s < KSTEP; s++) {
    int kk = s >> 1;
    int addr = ((r + kk / 3) * TCOLS + cg * 16 + (lane & 15) + (kk % 3)) * CSTR
               + (s & 1) * 32 + (lane >> 4) * 8;
    bf16x8 a = *(const bf16x8*)(samp + addr);
    acc[0] = __builtin_amdgcn_mfma_f32_16x16x32_bf16(a, bp[(size_t)s * 64], acc[0], 0, 0, 0);
    acc[1] = __builtin_amdgcn_mfma_f32_16x16x32_bf16(a, bp[(size_t)(KSTEP + s) * 64], acc[1], 0, 0, 0);
  }

  int pxc = cg * 16 + (lane >> 4) * 4;             // col within 32
  int hwp = (h0 + r) * WWD + wb + pxc;
  if (MODE == 1) {
    u16* outb = (u16*)outp;
    #pragma unroll
    for (int t = 0; t < 2; t++) {
      int co = copair * 32 + t * 16 + (lane & 15);
      float bv = bias[co];
      size_t obase = ((size_t)b * HWv + hwp) * 64 + co;
      #pragma unroll
      for (int j = 0; j < 4; j++) {
        float v = acc[t][j] + bv;
        outb[obase + (size_t)j * 64] = f2bf(v >= 0.f ? v : 0.2f * v);
      }
    }
  } else {
    float* outf = (float*)outp;
    float* ot = (float*)samp;                      // [64 co][72] = 18,432 B
    __syncthreads();                               // tile reads done
    #pragma unroll
    for (int t = 0; t < 2; t++) {
      int co = copair * 32 + t * 16 + (lane & 15);
      float bv = bias[co];
      size_t rbase = ((size_t)b * HWv + hwp) * 64 + co;
      #pragma unroll
      for (int j = 0; j < 4; j++)
        ot[co * 72 + r * 36 + pxc + j] = acc[t][j] + bv + bf2f(res[rbase + (size_t)j * 64]);
    }
    __syncthreads();
    int co = tid >> 3, seg = tid & 7;              // 2 rows x 4 col-segments
    int r2 = seg >> 2, c8 = (seg & 3) * 8;
    const float4* src4 = (const float4*)(ot + co * 72 + r2 * 36 + c8);
    float4 v0 = src4[0], v1 = src4[1];
    float* dst = outf + ((size_t)b * CCH + co) * HWv + (h0 + r2) * WWD + wb + c8;
    *(float4*)dst = v0;
    *(float4*)(dst + 4) = v1;
  }
}

extern "C" void kernel_launch(void* const* d_in, const int* in_sizes, int n_in,
                              void* d_out, int out_size, void* d_ws, size_t ws_size,
                              hipStream_t stream) {
  const float* x    = (const float*)d_in[0];
  const float* y    = (const float*)d_in[1];
  const float* w0   = (const float*)d_in[2];
  const float* b0   = (const float*)d_in[3];
  const float* w_om = (const float*)d_in[4];
  const float* b_om = (const float*)d_in[5];
  const float* w_dc = (const float*)d_in[6];
  const float* b_dc = (const float*)d_in[7];
  const float* w1   = (const float*)d_in[8];
  const float* b1   = (const float*)d_in[9];
  const float* w2   = (const float*)d_in[10];
  const float* b2   = (const float*)d_in[11];
  float* out = (float*)d_out;

  const size_t NFULL = (size_t)BB * CCH * HWv;   // 2,097,152
  const size_t NPACK = 4 * KSTEP * 64 * 8;       // 36,864 bf16
  const size_t NPACKOM = 2 * OMKS * 64 * 8;      // 36,864
  u16* x0bf = (u16*)d_ws;                        // NFULL bf16
  u16* ob   = x0bf + NFULL;                      // NFULL bf16
  u16* z1   = ob + NFULL;                        // NFULL bf16
  u16* yt   = z1;                                // alias: yt dead before z1 written
  u16* pk_dc = z1 + NFULL;
  u16* pk_w1 = pk_dc + NPACK;
  u16* pk_w2 = pk_w1 + NPACK;
  u16* pk_om = pk_w2 + NPACK;
  u16* pk_0  = pk_om + NPACKOM;

  const int NB = (int)((size_t)BB * HWv / 64);   // 512

  // 0. all weight packs, one launch (592 blocks)
  pack_all_k<<<592, 256, 0, stream>>>(w_dc, w1, w2, w_om, w0,
                                      pk_dc, pk_w1, pk_w2, pk_om, pk_0);
  // 1. fused y-transpose + conv1x1 -> yt, x0bf (NHWC bf16)
  conv1x1y_k<<<NB, 256, 0, stream>>>(x, y, pk_0, b0, x0bf, yt);
  // 2. fused om conv + deform conv + x0 residual -> ob (NHWC bf16)
  omd_k<<<NB, 512, 0, stream>>>(x0bf, yt, pk_om, pk_dc, b_om, b_dc, ob);
  // 3. conv w1 + leaky -> z1 (NHWC bf16)
  rconv_k<1><<<NB, 512, 0, stream>>>(ob, nullptr, pk_w1, b1, z1);
  // 4. conv w2 + residual ob -> out (NCHW f32 final)
  rconv_k<2><<<NB, 512, 0, stream>>>(z1, ob, pk_w2, b2, out);
}

// Round 14
// 60.563 us; speedup vs baseline: 2.2276x; 1.0533x over previous
//
#include <hip/hip_runtime.h>
#include <hip/hip_bf16.h>
#include <math.h>

#define BB 2
#define CCH 64
#define HH 128
#define WWD 128
#define HWv (HH*WWD)
#define KK 9
#define KSTEP 18        // 576/32
#define OMKS 36         // 1152/32
// 2-row x 32-col tiles
#define TCOLS 34
#define CSTR 72         // padded 64-ch run stride (bf16): 64 + 8
#define CSTR2 136       // padded 128-ch run stride (bf16): 128 + 8
#define DROW 584        // deform samp row stride (bf16): 576 + 8

typedef __attribute__((ext_vector_type(8))) short bf16x8;
typedef __attribute__((ext_vector_type(4))) float f32x4;
typedef unsigned short u16;
typedef unsigned int u32;

__device__ inline u16 f2bf(float f) {
  __hip_bfloat16 h = __float2bfloat16(f);
  return *reinterpret_cast<u16*>(&h);
}
__device__ inline u32 f2bf2(float lo, float hi) {
  return ((u32)f2bf(hi) << 16) | (u32)f2bf(lo);
}
__device__ inline float bfLO(u32 v) { return __uint_as_float(v << 16); }
__device__ inline float bfHI(u32 v) { return __uint_as_float(v & 0xffff0000u); }
__device__ inline float bf2f(u16 v) { return __uint_as_float((u32)v << 16); }

// ============ ALL weight packs in one launch ===============================
__global__ __launch_bounds__(256) void pack_all_k(
    const float* __restrict__ w_dc, const float* __restrict__ w1,
    const float* __restrict__ w2, const float* __restrict__ w_om,
    const float* __restrict__ w0, u16* __restrict__ pk_dc,
    u16* __restrict__ pk_w1, u16* __restrict__ pk_w2,
    u16* __restrict__ pk_om, u16* __restrict__ pk_0) {
  int blk = blockIdx.x;
  int tid = threadIdx.x;
  if (blk < 432) {
    const float* w = blk < 144 ? w_dc : (blk < 288 ? w1 : w2);
    u16* dst = blk < 144 ? pk_dc : (blk < 288 ? pk_w1 : pk_w2);
    int idx = (blk % 144) * 256 + tid;
    int j = idx & 7, l = (idx >> 3) & 63;
    int s = (idx >> 9) % 18, q = idx / 9216;
    int co = q * 16 + (l & 15);
    int kp = s * 32 + (l >> 4) * 8 + j;          // < 576
    dst[idx] = f2bf(w[(co * 64 + (kp & 63)) * 9 + (kp >> 6)]);
  } else if (blk < 576) {
    int idx = (blk - 432) * 256 + tid;
    int j = idx & 7, l = (idx >> 3) & 63;
    int s = (idx >> 9) % 36, q = idx / 18432;
    int co = q * 16 + (l & 15);
    int kp = s * 32 + (l >> 4) * 8 + j;          // < 1152
    pk_om[idx] = (co < 27)
        ? f2bf(w_om[(co * 128 + (kp & 127)) * 9 + (kp >> 7)]) : (u16)0;
  } else {
    int idx = (blk - 576) * 256 + tid;
    int j = idx & 7, l = (idx >> 3) & 63;
    int s = (idx >> 9) & 1, q = idx / 1024;
    int co = q * 16 + (l & 15);
    int k = s * 32 + (l >> 4) * 8 + j;           // < 64
    pk_0[idx] = f2bf(w0[co * 64 + k]);
  }
}

// ==== fused: y NCHW->NHWC bf16 + conv1x1 MFMA (64 px, K=64) -> x0bf ========
__global__ __launch_bounds__(256) void conv1x1y_k(const float* __restrict__ x,
    const float* __restrict__ y, const u16* __restrict__ wpack,
    const float* __restrict__ b0, u16* __restrict__ x0bf,
    u16* __restrict__ yt) {
  #define S1ROW 72
  __shared__ __align__(16) float smem[64 * 65];    // 16,640 B; aliased below
  u16* samp1 = (u16*)smem;                         // needs 9,216 B
  int tid = threadIdx.x;
  int lane = tid & 63, q = tid >> 6;
  int pixbase = blockIdx.x * 64;
  int hwb = pixbase & (HWv - 1);
  int b = pixbase >> 14;

  // ---- phase Y: transpose y for these 64 px ----
  {
    const float* src = y + (size_t)b * CCH * HWv;
    #pragma unroll
    for (int i = 0; i < 16; i++) {
      int ci = i * 4 + q;
      smem[ci * 65 + lane] = src[(size_t)ci * HWv + hwb + lane];
    }
    __syncthreads();
    u32* dst32 = (u32*)(yt + ((size_t)b * HWv + hwb) * 64);
    int lane2 = tid & 31, rr = tid >> 5;
    #pragma unroll
    for (int i = 0; i < 8; i++) {
      int row = i * 8 + rr;
      dst32[row * 32 + lane2] = f2bf2(smem[(2 * lane2) * 65 + row],
                                      smem[(2 * lane2 + 1) * 65 + row]);
    }
    __syncthreads();                               // smem dead -> reuse
  }

  // ---- phase X: conv1x1 ----
  {
    u16 tmp[16];
    #pragma unroll
    for (int i = 0; i < 16; i++) {
      int ci = q * 16 + i;
      tmp[i] = f2bf(x[((size_t)b * CCH + ci) * HWv + hwb + lane]);
    }
    #pragma unroll
    for (int i = 0; i < 2; i++)
      *(bf16x8*)(samp1 + lane * S1ROW + q * 16 + i * 8) = *(bf16x8*)(tmp + i * 8);
  }
  __syncthreads();
  f32x4 acc[4] = {{0,0,0,0},{0,0,0,0},{0,0,0,0},{0,0,0,0}};
  int g = lane >> 4;
  const bf16x8* bp = (const bf16x8*)wpack + (size_t)(q * 2) * 64 + lane;
  #pragma unroll
  for (int s = 0; s < 2; s++) {
    bf16x8 bf = bp[(size_t)s * 64];
    #pragma unroll
    for (int t = 0; t < 4; t++) {
      bf16x8 a = *(const bf16x8*)(samp1 + (t * 16 + (lane & 15)) * S1ROW + g * 8 + s * 32);
      acc[t] = __builtin_amdgcn_mfma_f32_16x16x32_bf16(a, bf, acc[t], 0, 0, 0);
    }
  }
  int co = q * 16 + (lane & 15);
  float bv = b0[co];
  u16* dst = x0bf + ((size_t)b * HWv + hwb + g * 4) * 64 + co;
  #pragma unroll
  for (int t = 0; t < 4; t++)
    #pragma unroll
    for (int r = 0; r < 4; r++)
      dst[(size_t)(t * 16 + r) * 64] = f2bf(acc[t][r] + bv);
}

// ==== FUSED om conv + deform conv, 2-row x 32-col tile, 512 thr ============
__global__ __launch_bounds__(512) void omd_k(const u16* __restrict__ x0bf,
    const u16* __restrict__ yt, const u16* __restrict__ pk_om,
    const u16* __restrict__ pk_dc, const float* __restrict__ b_om,
    const float* __restrict__ b_dc, u16* __restrict__ ob) {
  __shared__ __align__(16) u16 A[18688];           // 37,376 B (stage / dsamp)
  __shared__ __align__(16) int prm[288][8];        //  9,216 B
  __shared__ __align__(16) float omv[64 * 28];     //  7,168 B
  u32* A32 = (u32*)A;
  u32* dsamp32 = (u32*)A;
  u16* dsamp = A;
  int tid = threadIdx.x;
  int lane = tid & 63, q = tid >> 6;
  int blk = blockIdx.x;                            // 512 blocks
  int wq = blk & 3, rp = (blk >> 2) & 63, b = blk >> 8;
  int h0 = rp * 2, wb = wq * 32;
  const u32* x0b32 = (const u32*)x0bf + (size_t)b * HWv * 32;
  const u32* yt32  = (const u32*)yt + (size_t)b * HWv * 32;

  // ---- phase 1: stage [4][34][128ch]
  {
    int lane2 = tid & 31, g16 = tid >> 5;
    int cofs = lane2 * 2;
    const u32* srcb = (lane2 < 16) ? (x0b32 + cofs) : (yt32 + cofs - 32);
    #pragma unroll
    for (int i = 0; i < 9; i++) {
      int u = g16 + 16 * i;
      if (u < 4 * TCOLS) {
        int r = u / TCOLS, c = u % TCOLS;
        int hh = h0 - 1 + r, ww = wb - 1 + c;
        uint2 v = {0u, 0u};
        if ((unsigned)hh < HH && (unsigned)ww < WWD)
          v = *(const uint2*)(srcb + (size_t)(hh * WWD + ww) * 32);
        *(uint2*)(A32 + u * (CSTR2 / 2) + cofs) = v;
      }
    }
  }
  __syncthreads();

  // ---- phase 2: om MFMA
  {
    int r = q & 1, cg = (q >> 1) & 1, cohalf = q >> 2;
    f32x4 acc = {0.f, 0.f, 0.f, 0.f};
    const bf16x8* bp = (const bf16x8*)pk_om + (size_t)(cohalf * OMKS) * 64 + lane;
    #pragma unroll
    for (int s = 0; s < OMKS; s++) {
      int kk = s >> 2;
      int addr = ((r + kk / 3) * TCOLS + cg * 16 + (lane & 15) + (kk % 3)) * CSTR2
                 + (s & 3) * 32 + (lane >> 4) * 8;
      bf16x8 a = *(const bf16x8*)(A + addr);
      acc = __builtin_amdgcn_mfma_f32_16x16x32_bf16(a, bp[(size_t)s * 64], acc, 0, 0, 0);
    }
    int co = cohalf * 16 + (lane & 15);
    if (co < 27) {
      float bv = b_om[co];
      int px = r * 32 + cg * 16 + (lane >> 4) * 4;
      #pragma unroll
      for (int j = 0; j < 4; j++)
        omv[(px + j) * 28 + co] = acc[j] + bv;
    }
  }
  __syncthreads();

  // ---- phase 3: deform, one row (32 px) per half
  for (int h2 = 0; h2 < 2; h2++) {
    if (tid < 32 * KK) {
      int pl = tid / KK, k = tid % KK;
      const float* omp = omv + (h2 * 32 + pl) * 28;
      float dy = omp[2 * k], dx = omp[2 * k + 1];
      float mk = 2.f / (1.f + expf(-omp[18 + k]));
      float ys = (float)(h0 + h2 - 1 + k / 3) + dy;
      float xs = (float)(wb + pl - 1 + k % 3) + dx;
      float y0f = floorf(ys), x0f = floorf(xs);
      float ty = ys - y0f, tx = xs - x0f;
      int yi = (int)y0f, xi = (int)x0f;
      bool y0v = (unsigned)yi < HH, y1v = (unsigned)(yi + 1) < HH;
      bool x0v = (unsigned)xi < WWD, x1v = (unsigned)(xi + 1) < WWD;
      float w00 = (1.f - ty) * (1.f - tx) * mk * ((y0v && x0v) ? 1.f : 0.f);
      float w01 = (1.f - ty) * tx * mk * ((y0v && x1v) ? 1.f : 0.f);
      float w10 = ty * (1.f - tx) * mk * ((y1v && x0v) ? 1.f : 0.f);
      float w11 = ty * tx * mk * ((y1v && x1v) ? 1.f : 0.f);
      int* p = prm[tid];
      *(int4*)p = make_int4(min(max(yi, 0), HH - 1) * (WWD * 32),
                            min(max(yi + 1, 0), HH - 1) * (WWD * 32),
                            min(max(xi, 0), WWD - 1) * 32,
                            min(max(xi + 1, 0), WWD - 1) * 32);
      *(int4*)(p + 4) = make_int4(__float_as_int(w00), __float_as_int(w01),
                                  __float_as_int(w10), __float_as_int(w11));
    }
    __syncthreads();
    {
      int lane4 = tid & 15, g16 = tid >> 4;
      const u32* ytb = yt32 + lane4 * 2;
      #pragma unroll
      for (int i = 0; i < 9; i++) {
        int u = g16 + 32 * i;
        int k = u % 9, pix = u / 9;
        int4 pa = *(const int4*)prm[u];
        int4 pb = *(const int4*)(prm[u] + 4);
        uint2 v00 = *(const uint2*)(ytb + pa.x + pa.z);
        uint2 v01 = *(const uint2*)(ytb + pa.x + pa.w);
        uint2 v10 = *(const uint2*)(ytb + pa.y + pa.z);
        uint2 v11 = *(const uint2*)(ytb + pa.y + pa.w);
        float w00 = __int_as_float(pb.x), w01 = __int_as_float(pb.y);
        float w10 = __int_as_float(pb.z), w11 = __int_as_float(pb.w);
        float a0 = fmaf(bfLO(v00.x), w00, fmaf(bfLO(v01.x), w01,
                   fmaf(bfLO(v10.x), w10, bfLO(v11.x) * w11)));
        float a1 = fmaf(bfHI(v00.x), w00, fmaf(bfHI(v01.x), w01,
                   fmaf(bfHI(v10.x), w10, bfHI(v11.x) * w11)));
        float a2 = fmaf(bfLO(v00.y), w00, fmaf(bfLO(v01.y), w01,
                   fmaf(bfLO(v10.y), w10, bfLO(v11.y) * w11)));
        float a3 = fmaf(bfHI(v00.y), w00, fmaf(bfHI(v01.y), w01,
                   fmaf(bfHI(v10.y), w10, bfHI(v11.y) * w11)));
        uint2 o = {f2bf2(a0, a1), f2bf2(a2, a3)};
        *(uint2*)(dsamp32 + pix * (DROW / 2) + k * 32 + lane4 * 2) = o;
      }
    }
    __syncthreads();
    {
      int qq = q & 3, pxg = q >> 2;
      f32x4 acc = {0.f, 0.f, 0.f, 0.f};
      const u16* arow = dsamp + (pxg * 16 + (lane & 15)) * DROW + (lane >> 4) * 8;
      const bf16x8* bp = (const bf16x8*)pk_dc + (size_t)(qq * KSTEP) * 64 + lane;
      #pragma unroll
      for (int s = 0; s < KSTEP; s++) {
        bf16x8 a = *(const bf16x8*)(arow + s * 32);
        acc = __builtin_amdgcn_mfma_f32_16x16x32_bf16(a, bp[(size_t)s * 64], acc, 0, 0, 0);
      }
      int co = qq * 16 + (lane & 15);
      int px = pxg * 16 + (lane >> 4) * 4;
      float bv = b_dc[co];
      size_t obase = ((size_t)b * HWv + (h0 + h2) * WWD + wb + px) * 64 + co;
      #pragma unroll
      for (int j = 0; j < 4; j++)
        ob[obase + (size_t)j * 64] =
            f2bf(acc[j] + bv + bf2f(x0bf[obase + (size_t)j * 64]));
    }
    __syncthreads();
  }
}

// ==== FUSED conv-w1+leaky + conv-w2+residual, 2-row x 32-col out ==========
// stage ob [6 rows][36 cols][64ch] -> conv1 z1 for [4][34] halo grid in LDS
// (out-of-image halo z1 is ZEROED: conv2's zero padding) -> conv2 from LDS
// -> +res(ob from stage) -> out f32 NCHW
__global__ __launch_bounds__(512) void rconv12_k(const u16* __restrict__ ob,
    const u16* __restrict__ pk_w1, const u16* __restrict__ pk_w2,
    const float* __restrict__ b1, const float* __restrict__ b2,
    float* __restrict__ outp) {
  #define R2COLS 36
  __shared__ __align__(16) u16 stage[6 * R2COLS * CSTR];  // 31,104 B
  __shared__ __align__(16) u16 zlds[144 * CSTR];          // 20,736 B
  u32* stage32 = (u32*)stage;
  int tid = threadIdx.x;
  int lane = tid & 63, q = tid >> 6;
  int blk = blockIdx.x;                            // 512 blocks
  int wq = blk & 3, rp = (blk >> 2) & 63, b = blk >> 8;
  int h0 = rp * 2, wb = wq * 32;

  // ---- stage ob [6][36][64] bf16, uint2 copy (216 units, 32 groups)
  {
    int lane4 = tid & 15, g16 = tid >> 4;
    const u32* inb = (const u32*)ob + (size_t)b * HWv * 32 + lane4 * 2;
    #pragma unroll
    for (int i = 0; i < 7; i++) {
      int u = g16 + 32 * i;
      if (u < 6 * R2COLS) {
        int r = u / R2COLS, c = u % R2COLS;
        int hh = h0 - 2 + r, ww = wb - 2 + c;
        uint2 v = {0u, 0u};
        if ((unsigned)hh < HH && (unsigned)ww < WWD)
          v = *(const uint2*)(inb + (size_t)(hh * WWD + ww) * 32);
        *(uint2*)(stage32 + u * (CSTR / 2) + lane4 * 2) = v;
      }
    }
  }
  __syncthreads();

  // ---- conv1: z1 = leaky(w1 * ob + b1) on the [4][34]=136 px halo grid
  // 36 tasks = 9 px-groups x 4 co-quadrants; 8 waves round-robin.
  // z1 halo pixels OUTSIDE the image are zeroed (conv2 zero padding).
  #pragma unroll
  for (int t = 0; t < 5; t++) {
    int task = q + 8 * t;
    if (task < 36) {
      int g = task >> 2, coq = task & 3;
      int p = g * 16 + (lane & 15);
      if (p > 135) p = 135;                       // pad px clamp (group 8)
      int r1 = p / 34, c1 = p % 34;
      f32x4 acc = {0.f, 0.f, 0.f, 0.f};
      const bf16x8* bp = (const bf16x8*)pk_w1 + (size_t)(coq * KSTEP) * 64 + lane;
      #pragma unroll
      for (int s = 0; s < KSTEP; s++) {
        int kk = s >> 1;
        int addr = ((r1 + kk / 3) * R2COLS + c1 + kk % 3) * CSTR
                   + (s & 1) * 32 + (lane >> 4) * 8;
        bf16x8 a = *(const bf16x8*)(stage + addr);
        acc = __builtin_amdgcn_mfma_f32_16x16x32_bf16(a, bp[(size_t)s * 64], acc, 0, 0, 0);
      }
      int co = coq * 16 + (lane & 15);
      float bv = b1[co];
      int prow = g * 16 + (lane >> 4) * 4;
      #pragma unroll
      for (int j = 0; j < 4; j++) {
        int pp = prow + j;                        // may reach 143 (unused rows)
        int rr = pp / 34, cc = pp % 34;
        bool inimg = ((unsigned)(h0 - 1 + rr) < HH) && ((unsigned)(wb - 1 + cc) < WWD);
        float v = acc[j] + bv;
        v = v >= 0.f ? v : 0.2f * v;
        zlds[pp * CSTR + co] = inimg ? f2bf(v) : (u16)0;
      }
    }
  }
  __syncthreads();

  // ---- conv2: out = w2 * z1 + b2 + ob   (8 waves = r x cg x copair)
  int r = q & 1, cg = (q >> 1) & 1, copair = q >> 2;
  f32x4 acc2[2] = {{0,0,0,0},{0,0,0,0}};
  const bf16x8* bp2 = (const bf16x8*)pk_w2 + (size_t)(copair * 2 * KSTEP) * 64 + lane;
  #pragma unroll
  for (int s = 0; s < KSTEP; s++) {
    int kk = s >> 1;
    int p = (r + kk / 3) * 34 + cg * 16 + (lane & 15) + (kk % 3);
    int addr = p * CSTR + (s & 1) * 32 + (lane >> 4) * 8;
    bf16x8 a = *(const bf16x8*)(zlds + addr);
    acc2[0] = __builtin_amdgcn_mfma_f32_16x16x32_bf16(a, bp2[(size_t)s * 64], acc2[0], 0, 0, 0);
    acc2[1] = __builtin_amdgcn_mfma_f32_16x16x32_bf16(a, bp2[(size_t)(KSTEP + s) * 64], acc2[1], 0, 0, 0);
  }
  __syncthreads();                                 // zlds reads done -> reuse

  // ---- epilogue: +bias +residual(from stage), transpose to NCHW
  float* ot = (float*)zlds;                        // [64 co][72] f32 = 18,432 B
  int pxc = cg * 16 + (lane >> 4) * 4;             // col within 32
  #pragma unroll
  for (int t = 0; t < 2; t++) {
    int co = copair * 32 + t * 16 + (lane & 15);
    float bv = b2[co];
    #pragma unroll
    for (int j = 0; j < 4; j++) {
      int c = pxc + j;
      u16 resv = stage[((r + 2) * R2COLS + c + 2) * CSTR + co];
      ot[co * 72 + r * 36 + c] = acc2[t][j] + bv + bf2f(resv);
    }
  }
  __syncthreads();
  int co = tid >> 3, seg = tid & 7;                // 2 rows x 4 col-segments
  int r2 = seg >> 2, c8 = (seg & 3) * 8;
  const float4* src4 = (const float4*)(ot + co * 72 + r2 * 36 + c8);
  float4 v0 = src4[0], v1 = src4[1];
  float* dst = outp + ((size_t)b * CCH + co) * HWv + (h0 + r2) * WWD + wb + c8;
  *(float4*)dst = v0;
  *(float4*)(dst + 4) = v1;
}

extern "C" void kernel_launch(void* const* d_in, const int* in_sizes, int n_in,
                              void* d_out, int out_size, void* d_ws, size_t ws_size,
                              hipStream_t stream) {
  const float* x    = (const float*)d_in[0];
  const float* y    = (const float*)d_in[1];
  const float* w0   = (const float*)d_in[2];
  const float* b0   = (const float*)d_in[3];
  const float* w_om = (const float*)d_in[4];
  const float* b_om = (const float*)d_in[5];
  const float* w_dc = (const float*)d_in[6];
  const float* b_dc = (const float*)d_in[7];
  const float* w1   = (const float*)d_in[8];
  const float* b1   = (const float*)d_in[9];
  const float* w2   = (const float*)d_in[10];
  const float* b2   = (const float*)d_in[11];
  float* out = (float*)d_out;

  const size_t NFULL = (size_t)BB * CCH * HWv;   // 2,097,152
  const size_t NPACK = 4 * KSTEP * 64 * 8;       // 36,864 bf16
  const size_t NPACKOM = 2 * OMKS * 64 * 8;      // 36,864
  u16* x0bf = (u16*)d_ws;                        // NFULL bf16
  u16* ob   = x0bf + NFULL;                      // NFULL bf16
  u16* yt   = ob + NFULL;                        // NFULL bf16
  u16* pk_dc = yt + NFULL;
  u16* pk_w1 = pk_dc + NPACK;
  u16* pk_w2 = pk_w1 + NPACK;
  u16* pk_om = pk_w2 + NPACK;
  u16* pk_0  = pk_om + NPACKOM;

  const int NB = (int)((size_t)BB * HWv / 64);   // 512

  // 0. all weight packs, one launch (592 blocks)
  pack_all_k<<<592, 256, 0, stream>>>(w_dc, w1, w2, w_om, w0,
                                      pk_dc, pk_w1, pk_w2, pk_om, pk_0);
  // 1. fused y-transpose + conv1x1 -> yt, x0bf (NHWC bf16)
  conv1x1y_k<<<NB, 256, 0, stream>>>(x, y, pk_0, b0, x0bf, yt);
  // 2. fused om conv + deform conv + x0 residual -> ob (NHWC bf16)
  omd_k<<<NB, 512, 0, stream>>>(x0bf, yt, pk_om, pk_dc, b_om, b_dc, ob);
  // 3. fused conv w1 + leaky + conv w2 + residual -> out (NCHW f32)
  rconv12_k<<<NB, 512, 0, stream>>>(ob, pk_w1, pk_w2, b1, b2, out);
}

// Round 15
// 60.294 us; speedup vs baseline: 2.2375x; 1.0045x over previous
//
#include <hip/hip_runtime.h>
#include <hip/hip_bf16.h>
#include <math.h>

#define BB 2
#define CCH 64
#define HH 128
#define WWD 128
#define HWv (HH*WWD)
#define KK 9
#define KSTEP 18        // 576/32
#define OMKS 36         // 1152/32
// 2-row x 32-col tiles
#define TCOLS 34
#define CSTR 72         // padded 64-ch run stride (bf16): 64 + 8
#define CSTR2 136       // padded 128-ch run stride (bf16): 128 + 8
#define DROW 584        // deform samp row stride (bf16): 576 + 8

typedef __attribute__((ext_vector_type(8))) short bf16x8;
typedef __attribute__((ext_vector_type(4))) float f32x4;
typedef unsigned short u16;
typedef unsigned int u32;

__device__ inline u16 f2bf(float f) {
  __hip_bfloat16 h = __float2bfloat16(f);
  return *reinterpret_cast<u16*>(&h);
}
__device__ inline u32 f2bf2(float lo, float hi) {
  return ((u32)f2bf(hi) << 16) | (u32)f2bf(lo);
}
__device__ inline float bfLO(u32 v) { return __uint_as_float(v << 16); }
__device__ inline float bfHI(u32 v) { return __uint_as_float(v & 0xffff0000u); }
__device__ inline float bf2f(u16 v) { return __uint_as_float((u32)v << 16); }

// ============ ALL weight packs in one launch ===============================
__global__ __launch_bounds__(256) void pack_all_k(
    const float* __restrict__ w_dc, const float* __restrict__ w1,
    const float* __restrict__ w2, const float* __restrict__ w_om,
    const float* __restrict__ w0, u16* __restrict__ pk_dc,
    u16* __restrict__ pk_w1, u16* __restrict__ pk_w2,
    u16* __restrict__ pk_om, u16* __restrict__ pk_0) {
  int blk = blockIdx.x;
  int tid = threadIdx.x;
  if (blk < 432) {
    const float* w = blk < 144 ? w_dc : (blk < 288 ? w1 : w2);
    u16* dst = blk < 144 ? pk_dc : (blk < 288 ? pk_w1 : pk_w2);
    int idx = (blk % 144) * 256 + tid;
    int j = idx & 7, l = (idx >> 3) & 63;
    int s = (idx >> 9) % 18, q = idx / 9216;
    int co = q * 16 + (l & 15);
    int kp = s * 32 + (l >> 4) * 8 + j;          // < 576
    dst[idx] = f2bf(w[(co * 64 + (kp & 63)) * 9 + (kp >> 6)]);
  } else if (blk < 576) {
    int idx = (blk - 432) * 256 + tid;
    int j = idx & 7, l = (idx >> 3) & 63;
    int s = (idx >> 9) % 36, q = idx / 18432;
    int co = q * 16 + (l & 15);
    int kp = s * 32 + (l >> 4) * 8 + j;          // < 1152
    pk_om[idx] = (co < 27)
        ? f2bf(w_om[(co * 128 + (kp & 127)) * 9 + (kp >> 7)]) : (u16)0;
  } else {
    int idx = (blk - 576) * 256 + tid;
    int j = idx & 7, l = (idx >> 3) & 63;
    int s = (idx >> 9) & 1, q = idx / 1024;
    int co = q * 16 + (l & 15);
    int k = s * 32 + (l >> 4) * 8 + j;           // < 64
    pk_0[idx] = f2bf(w0[co * 64 + k]);
  }
}

// ==== fused: y NCHW->NHWC bf16 + conv1x1 MFMA (64 px, K=64) -> x0bf ========
__global__ __launch_bounds__(256) void conv1x1y_k(const float* __restrict__ x,
    const float* __restrict__ y, const u16* __restrict__ wpack,
    const float* __restrict__ b0, u16* __restrict__ x0bf,
    u16* __restrict__ yt) {
  #define S1ROW 72
  __shared__ __align__(16) float smem[64 * 65];    // 16,640 B; aliased below
  u16* samp1 = (u16*)smem;                         // needs 9,216 B
  int tid = threadIdx.x;
  int lane = tid & 63, q = tid >> 6;
  int pixbase = blockIdx.x * 64;
  int hwb = pixbase & (HWv - 1);
  int b = pixbase >> 14;

  // ---- phase Y: transpose y for these 64 px ----
  {
    const float* src = y + (size_t)b * CCH * HWv;
    #pragma unroll
    for (int i = 0; i < 16; i++) {
      int ci = i * 4 + q;
      smem[ci * 65 + lane] = src[(size_t)ci * HWv + hwb + lane];
    }
    __syncthreads();
    u32* dst32 = (u32*)(yt + ((size_t)b * HWv + hwb) * 64);
    int lane2 = tid & 31, rr = tid >> 5;
    #pragma unroll
    for (int i = 0; i < 8; i++) {
      int row = i * 8 + rr;
      dst32[row * 32 + lane2] = f2bf2(smem[(2 * lane2) * 65 + row],
                                      smem[(2 * lane2 + 1) * 65 + row]);
    }
    __syncthreads();                               // smem dead -> reuse
  }

  // ---- phase X: conv1x1 ----
  {
    u16 tmp[16];
    #pragma unroll
    for (int i = 0; i < 16; i++) {
      int ci = q * 16 + i;
      tmp[i] = f2bf(x[((size_t)b * CCH + ci) * HWv + hwb + lane]);
    }
    #pragma unroll
    for (int i = 0; i < 2; i++)
      *(bf16x8*)(samp1 + lane * S1ROW + q * 16 + i * 8) = *(bf16x8*)(tmp + i * 8);
  }
  __syncthreads();
  f32x4 acc[4] = {{0,0,0,0},{0,0,0,0},{0,0,0,0},{0,0,0,0}};
  int g = lane >> 4;
  const bf16x8* bp = (const bf16x8*)wpack + (size_t)(q * 2) * 64 + lane;
  #pragma unroll
  for (int s = 0; s < 2; s++) {
    bf16x8 bf = bp[(size_t)s * 64];
    #pragma unroll
    for (int t = 0; t < 4; t++) {
      bf16x8 a = *(const bf16x8*)(samp1 + (t * 16 + (lane & 15)) * S1ROW + g * 8 + s * 32);
      acc[t] = __builtin_amdgcn_mfma_f32_16x16x32_bf16(a, bf, acc[t], 0, 0, 0);
    }
  }
  int co = q * 16 + (lane & 15);
  float bv = b0[co];
  u16* dst = x0bf + ((size_t)b * HWv + hwb + g * 4) * 64 + co;
  #pragma unroll
  for (int t = 0; t < 4; t++)
    #pragma unroll
    for (int r = 0; r < 4; r++)
      dst[(size_t)(t * 16 + r) * 64] = f2bf(acc[t][r] + bv);
}

// ==== FUSED om conv + deform conv, 2-row x 32-col tile, 512 thr ============
__global__ __launch_bounds__(512) void omd_k(const u16* __restrict__ x0bf,
    const u16* __restrict__ yt, const u16* __restrict__ pk_om,
    const u16* __restrict__ pk_dc, const float* __restrict__ b_om,
    const float* __restrict__ b_dc, u16* __restrict__ ob) {
  __shared__ __align__(16) u16 A[18688];           // 37,376 B (stage / dsamp)
  __shared__ __align__(16) int prm[288][8];        //  9,216 B
  __shared__ __align__(16) float omv[64 * 28];     //  7,168 B
  u32* A32 = (u32*)A;
  u32* dsamp32 = (u32*)A;
  u16* dsamp = A;
  int tid = threadIdx.x;
  int lane = tid & 63, q = tid >> 6;
  int blk = blockIdx.x;                            // 512 blocks
  int wq = blk & 3, rp = (blk >> 2) & 63, b = blk >> 8;
  int h0 = rp * 2, wb = wq * 32;
  const u32* x0b32 = (const u32*)x0bf + (size_t)b * HWv * 32;
  const u32* yt32  = (const u32*)yt + (size_t)b * HWv * 32;

  // ---- phase 1: stage [4][34][128ch]
  {
    int lane2 = tid & 31, g16 = tid >> 5;
    int cofs = lane2 * 2;
    const u32* srcb = (lane2 < 16) ? (x0b32 + cofs) : (yt32 + cofs - 32);
    #pragma unroll
    for (int i = 0; i < 9; i++) {
      int u = g16 + 16 * i;
      if (u < 4 * TCOLS) {
        int r = u / TCOLS, c = u % TCOLS;
        int hh = h0 - 1 + r, ww = wb - 1 + c;
        uint2 v = {0u, 0u};
        if ((unsigned)hh < HH && (unsigned)ww < WWD)
          v = *(const uint2*)(srcb + (size_t)(hh * WWD + ww) * 32);
        *(uint2*)(A32 + u * (CSTR2 / 2) + cofs) = v;
      }
    }
  }
  __syncthreads();

  // ---- phase 2: om MFMA
  {
    int r = q & 1, cg = (q >> 1) & 1, cohalf = q >> 2;
    f32x4 acc = {0.f, 0.f, 0.f, 0.f};
    const bf16x8* bp = (const bf16x8*)pk_om + (size_t)(cohalf * OMKS) * 64 + lane;
    #pragma unroll
    for (int s = 0; s < OMKS; s++) {
      int kk = s >> 2;
      int addr = ((r + kk / 3) * TCOLS + cg * 16 + (lane & 15) + (kk % 3)) * CSTR2
                 + (s & 3) * 32 + (lane >> 4) * 8;
      bf16x8 a = *(const bf16x8*)(A + addr);
      acc = __builtin_amdgcn_mfma_f32_16x16x32_bf16(a, bp[(size_t)s * 64], acc, 0, 0, 0);
    }
    int co = cohalf * 16 + (lane & 15);
    if (co < 27) {
      float bv = b_om[co];
      int px = r * 32 + cg * 16 + (lane >> 4) * 4;
      #pragma unroll
      for (int j = 0; j < 4; j++)
        omv[(px + j) * 28 + co] = acc[j] + bv;
    }
  }
  __syncthreads();

  // ---- phase 3: deform, one row (32 px) per half
  for (int h2 = 0; h2 < 2; h2++) {
    if (tid < 32 * KK) {
      int pl = tid / KK, k = tid % KK;
      const float* omp = omv + (h2 * 32 + pl) * 28;
      float dy = omp[2 * k], dx = omp[2 * k + 1];
      float mk = 2.f / (1.f + expf(-omp[18 + k]));
      float ys = (float)(h0 + h2 - 1 + k / 3) + dy;
      float xs = (float)(wb + pl - 1 + k % 3) + dx;
      float y0f = floorf(ys), x0f = floorf(xs);
      float ty = ys - y0f, tx = xs - x0f;
      int yi = (int)y0f, xi = (int)x0f;
      bool y0v = (unsigned)yi < HH, y1v = (unsigned)(yi + 1) < HH;
      bool x0v = (unsigned)xi < WWD, x1v = (unsigned)(xi + 1) < WWD;
      float w00 = (1.f - ty) * (1.f - tx) * mk * ((y0v && x0v) ? 1.f : 0.f);
      float w01 = (1.f - ty) * tx * mk * ((y0v && x1v) ? 1.f : 0.f);
      float w10 = ty * (1.f - tx) * mk * ((y1v && x0v) ? 1.f : 0.f);
      float w11 = ty * tx * mk * ((y1v && x1v) ? 1.f : 0.f);
      int* p = prm[tid];
      *(int4*)p = make_int4(min(max(yi, 0), HH - 1) * (WWD * 32),
                            min(max(yi + 1, 0), HH - 1) * (WWD * 32),
                            min(max(xi, 0), WWD - 1) * 32,
                            min(max(xi + 1, 0), WWD - 1) * 32);
      *(int4*)(p + 4) = make_int4(__float_as_int(w00), __float_as_int(w01),
                                  __float_as_int(w10), __float_as_int(w11));
    }
    __syncthreads();
    {
      int lane4 = tid & 15, g16 = tid >> 4;
      const u32* ytb = yt32 + lane4 * 2;
      #pragma unroll
      for (int i = 0; i < 9; i++) {
        int u = g16 + 32 * i;
        int k = u % 9, pix = u / 9;
        int4 pa = *(const int4*)prm[u];
        int4 pb = *(const int4*)(prm[u] + 4);
        uint2 v00 = *(const uint2*)(ytb + pa.x + pa.z);
        uint2 v01 = *(const uint2*)(ytb + pa.x + pa.w);
        uint2 v10 = *(const uint2*)(ytb + pa.y + pa.z);
        uint2 v11 = *(const uint2*)(ytb + pa.y + pa.w);
        float w00 = __int_as_float(pb.x), w01 = __int_as_float(pb.y);
        float w10 = __int_as_float(pb.z), w11 = __int_as_float(pb.w);
        float a0 = fmaf(bfLO(v00.x), w00, fmaf(bfLO(v01.x), w01,
                   fmaf(bfLO(v10.x), w10, bfLO(v11.x) * w11)));
        float a1 = fmaf(bfHI(v00.x), w00, fmaf(bfHI(v01.x), w01,
                   fmaf(bfHI(v10.x), w10, bfHI(v11.x) * w11)));
        float a2 = fmaf(bfLO(v00.y), w00, fmaf(bfLO(v01.y), w01,
                   fmaf(bfLO(v10.y), w10, bfLO(v11.y) * w11)));
        float a3 = fmaf(bfHI(v00.y), w00, fmaf(bfHI(v01.y), w01,
                   fmaf(bfHI(v10.y), w10, bfHI(v11.y) * w11)));
        uint2 o = {f2bf2(a0, a1), f2bf2(a2, a3)};
        *(uint2*)(dsamp32 + pix * (DROW / 2) + k * 32 + lane4 * 2) = o;
      }
    }
    __syncthreads();
    {
      int qq = q & 3, pxg = q >> 2;
      f32x4 acc = {0.f, 0.f, 0.f, 0.f};
      const u16* arow = dsamp + (pxg * 16 + (lane & 15)) * DROW + (lane >> 4) * 8;
      const bf16x8* bp = (const bf16x8*)pk_dc + (size_t)(qq * KSTEP) * 64 + lane;
      #pragma unroll
      for (int s = 0; s < KSTEP; s++) {
        bf16x8 a = *(const bf16x8*)(arow + s * 32);
        acc = __builtin_amdgcn_mfma_f32_16x16x32_bf16(a, bp[(size_t)s * 64], acc, 0, 0, 0);
      }
      int co = qq * 16 + (lane & 15);
      int px = pxg * 16 + (lane >> 4) * 4;
      float bv = b_dc[co];
      size_t obase = ((size_t)b * HWv + (h0 + h2) * WWD + wb + px) * 64 + co;
      #pragma unroll
      for (int j = 0; j < 4; j++)
        ob[obase + (size_t)j * 64] =
            f2bf(acc[j] + bv + bf2f(x0bf[obase + (size_t)j * 64]));
    }
    __syncthreads();
  }
}

// ==== FUSED conv-w1+leaky + conv-w2+residual, 2-row x 32-col out ==========
// stage ob [6 rows][36 cols][64ch] -> conv1 z1 for [4][34] halo grid in LDS
// (out-of-image halo z1 is ZEROED: conv2's zero padding) -> conv2 from LDS
// -> +res(ob from stage) -> out f32 NCHW
__global__ __launch_bounds__(512) void rconv12_k(const u16* __restrict__ ob,
    const u16* __restrict__ pk_w1, const u16* __restrict__ pk_w2,
    const float* __restrict__ b1, const float* __restrict__ b2,
    float* __restrict__ outp) {
  #define R2COLS 36
  __shared__ __align__(16) u16 stage[6 * R2COLS * CSTR];  // 31,104 B
  __shared__ __align__(16) u16 zlds[144 * CSTR];          // 20,736 B
  u32* stage32 = (u32*)stage;
  int tid = threadIdx.x;
  int lane = tid & 63, q = tid >> 6;
  int blk = blockIdx.x;                            // 512 blocks
  int wq = blk & 3, rp = (blk >> 2) & 63, b = blk >> 8;
  int h0 = rp * 2, wb = wq * 32;

  // ---- stage ob [6][36][64] bf16, uint2 copy (216 units, 32 groups)
  {
    int lane4 = tid & 15, g16 = tid >> 4;
    const u32* inb = (const u32*)ob + (size_t)b * HWv * 32 + lane4 * 2;
    #pragma unroll
    for (int i = 0; i < 7; i++) {
      int u = g16 + 32 * i;
      if (u < 6 * R2COLS) {
        int r = u / R2COLS, c = u % R2COLS;
        int hh = h0 - 2 + r, ww = wb - 2 + c;
        uint2 v = {0u, 0u};
        if ((unsigned)hh < HH && (unsigned)ww < WWD)
          v = *(const uint2*)(inb + (size_t)(hh * WWD + ww) * 32);
        *(uint2*)(stage32 + u * (CSTR / 2) + lane4 * 2) = v;
      }
    }
  }
  __syncthreads();

  // ---- conv1: z1 = leaky(w1 * ob + b1) on the [4][34]=136 px halo grid
  // 36 tasks = 9 px-groups x 4 co-quadrants; 8 waves round-robin.
  // z1 halo pixels OUTSIDE the image are zeroed (conv2 zero padding).
  #pragma unroll
  for (int t = 0; t < 5; t++) {
    int task = q + 8 * t;
    if (task < 36) {
      int g = task >> 2, coq = task & 3;
      int p = g * 16 + (lane & 15);
      if (p > 135) p = 135;                       // pad px clamp (group 8)
      int r1 = p / 34, c1 = p % 34;
      f32x4 acc = {0.f, 0.f, 0.f, 0.f};
      const bf16x8* bp = (const bf16x8*)pk_w1 + (size_t)(coq * KSTEP) * 64 + lane;
      #pragma unroll
      for (int s = 0; s < KSTEP; s++) {
        int kk = s >> 1;
        int addr = ((r1 + kk / 3) * R2COLS + c1 + kk % 3) * CSTR
                   + (s & 1) * 32 + (lane >> 4) * 8;
        bf16x8 a = *(const bf16x8*)(stage + addr);
        acc = __builtin_amdgcn_mfma_f32_16x16x32_bf16(a, bp[(size_t)s * 64], acc, 0, 0, 0);
      }
      int co = coq * 16 + (lane & 15);
      float bv = b1[co];
      int prow = g * 16 + (lane >> 4) * 4;
      #pragma unroll
      for (int j = 0; j < 4; j++) {
        int pp = prow + j;                        // may reach 143 (unused rows)
        int rr = pp / 34, cc = pp % 34;
        bool inimg = ((unsigned)(h0 - 1 + rr) < HH) && ((unsigned)(wb - 1 + cc) < WWD);
        float v = acc[j] + bv;
        v = v >= 0.f ? v : 0.2f * v;
        zlds[pp * CSTR + co] = inimg ? f2bf(v) : (u16)0;
      }
    }
  }
  __syncthreads();

  // ---- conv2: out = w2 * z1 + b2 + ob   (8 waves = r x cg x copair)
  int r = q & 1, cg = (q >> 1) & 1, copair = q >> 2;
  f32x4 acc2[2] = {{0,0,0,0},{0,0,0,0}};
  const bf16x8* bp2 = (const bf16x8*)pk_w2 + (size_t)(copair * 2 * KSTEP) * 64 + lane;
  #pragma unroll
  for (int s = 0; s < KSTEP; s++) {
    int kk = s >> 1;
    int p = (r + kk / 3) * 34 + cg * 16 + (lane & 15) + (kk % 3);
    int addr = p * CSTR + (s & 1) * 32 + (lane >> 4) * 8;
    bf16x8 a = *(const bf16x8*)(zlds + addr);
    acc2[0] = __builtin_amdgcn_mfma_f32_16x16x32_bf16(a, bp2[(size_t)s * 64], acc2[0], 0, 0, 0);
    acc2[1] = __builtin_amdgcn_mfma_f32_16x16x32_bf16(a, bp2[(size_t)(KSTEP + s) * 64], acc2[1], 0, 0, 0);
  }
  __syncthreads();                                 // zlds reads done -> reuse

  // ---- epilogue: +bias +residual(from stage), transpose to NCHW
  float* ot = (float*)zlds;                        // [64 co][72] f32 = 18,432 B
  int pxc = cg * 16 + (lane >> 4) * 4;             // col within 32
  #pragma unroll
  for (int t = 0; t < 2; t++) {
    int co = copair * 32 + t * 16 + (lane & 15);
    float bv = b2[co];
    #pragma unroll
    for (int j = 0; j < 4; j++) {
      int c = pxc + j;
      u16 resv = stage[((r + 2) * R2COLS + c + 2) * CSTR + co];
      ot[co * 72 + r * 36 + c] = acc2[t][j] + bv + bf2f(resv);
    }
  }
  __syncthreads();
  int co = tid >> 3, seg = tid & 7;                // 2 rows x 4 col-segments
  int r2 = seg >> 2, c8 = (seg & 3) * 8;
  const float4* src4 = (const float4*)(ot + co * 72 + r2 * 36 + c8);
  float4 v0 = src4[0], v1 = src4[1];
  float* dst = outp + ((size_t)b * CCH + co) * HWv + (h0 + r2) * WWD + wb + c8;
  *(float4*)dst = v0;
  *(float4*)(dst + 4) = v1;
}

extern "C" void kernel_launch(void* const* d_in, const int* in_sizes, int n_in,
                              void* d_out, int out_size, void* d_ws, size_t ws_size,
                              hipStream_t stream) {
  const float* x    = (const float*)d_in[0];
  const float* y    = (const float*)d_in[1];
  const float* w0   = (const float*)d_in[2];
  const float* b0   = (const float*)d_in[3];
  const float* w_om = (const float*)d_in[4];
  const float* b_om = (const float*)d_in[5];
  const float* w_dc = (const float*)d_in[6];
  const float* b_dc = (const float*)d_in[7];
  const float* w1   = (const float*)d_in[8];
  const float* b1   = (const float*)d_in[9];
  const float* w2   = (const float*)d_in[10];
  const float* b2   = (const float*)d_in[11];
  float* out = (float*)d_out;

  const size_t NFULL = (size_t)BB * CCH * HWv;   // 2,097,152
  const size_t NPACK = 4 * KSTEP * 64 * 8;       // 36,864 bf16
  const size_t NPACKOM = 2 * OMKS * 64 * 8;      // 36,864
  u16* x0bf = (u16*)d_ws;                        // NFULL bf16
  u16* ob   = x0bf + NFULL;                      // NFULL bf16
  u16* yt   = ob + NFULL;                        // NFULL bf16
  u16* pk_dc = yt + NFULL;
  u16* pk_w1 = pk_dc + NPACK;
  u16* pk_w2 = pk_w1 + NPACK;
  u16* pk_om = pk_w2 + NPACK;
  u16* pk_0  = pk_om + NPACKOM;

  const int NB = (int)((size_t)BB * HWv / 64);   // 512

  // 0. all weight packs, one launch (592 blocks)
  pack_all_k<<<592, 256, 0, stream>>>(w_dc, w1, w2, w_om, w0,
                                      pk_dc, pk_w1, pk_w2, pk_om, pk_0);
  // 1. fused y-transpose + conv1x1 -> yt, x0bf (NHWC bf16)
  conv1x1y_k<<<NB, 256, 0, stream>>>(x, y, pk_0, b0, x0bf, yt);
  // 2. fused om conv + deform conv + x0 residual -> ob (NHWC bf16)
  omd_k<<<NB, 512, 0, stream>>>(x0bf, yt, pk_om, pk_dc, b_om, b_dc, ob);
  // 3. fused conv w1 + leaky + conv w2 + residual -> out (NCHW f32)
  rconv12_k<<<NB, 512, 0, stream>>>(ob, pk_w1, pk_w2, b1, b2, out);
}

// Round 16
// 52.986 us; speedup vs baseline: 2.5461x; 1.1379x over previous
//
#include <hip/hip_runtime.h>
#include <hip/hip_bf16.h>
#include <math.h>

#define BB 2
#define CCH 64
#define HH 128
#define WWD 128
#define HWv (HH*WWD)
#define KK 9
#define KSTEP 18        // 576/32
#define OMKS 36         // 1152/32
// 2-row x 32-col tiles
#define TCOLS 34
#define CSTR 72         // padded 64-ch run stride (bf16): 64 + 8
#define CSTR2 136       // padded 128-ch run stride (bf16): 128 + 8
#define DROW 584        // deform samp row stride (bf16): 576 + 8

typedef __attribute__((ext_vector_type(8))) short bf16x8;
typedef __attribute__((ext_vector_type(4))) float f32x4;
typedef unsigned short u16;
typedef unsigned int u32;

__device__ inline u16 f2bf(float f) {
  __hip_bfloat16 h = __float2bfloat16(f);
  return *reinterpret_cast<u16*>(&h);
}
__device__ inline u32 f2bf2(float lo, float hi) {
  return ((u32)f2bf(hi) << 16) | (u32)f2bf(lo);
}
__device__ inline float bfLO(u32 v) { return __uint_as_float(v << 16); }
__device__ inline float bfHI(u32 v) { return __uint_as_float(v & 0xffff0000u); }
__device__ inline float bf2f(u16 v) { return __uint_as_float((u32)v << 16); }

// ==== kernel 1: blocks [0,512) = y-transpose + conv1x1 (w0 packed in-reg);
//                blocks [512,1088) = weight packs for dc/w1/w2/om ===========
__global__ __launch_bounds__(256) void c1y_pack_k(const float* __restrict__ x,
    const float* __restrict__ y, const float* __restrict__ w0,
    const float* __restrict__ b0, const float* __restrict__ w_dc,
    const float* __restrict__ w1, const float* __restrict__ w2,
    const float* __restrict__ w_om, u16* __restrict__ x0bf,
    u16* __restrict__ yt, u16* __restrict__ pk_dc, u16* __restrict__ pk_w1,
    u16* __restrict__ pk_w2, u16* __restrict__ pk_om) {
  #define S1ROW 72
  __shared__ __align__(16) float smem[64 * 65];    // 16,640 B; aliased below
  int tid = threadIdx.x;

  if (blockIdx.x >= 512) {                         // ---- pack path ----
    int blk = blockIdx.x - 512;                    // 0..575
    if (blk < 432) {
      const float* w = blk < 144 ? w_dc : (blk < 288 ? w1 : w2);
      u16* dst = blk < 144 ? pk_dc : (blk < 288 ? pk_w1 : pk_w2);
      int idx = (blk % 144) * 256 + tid;
      int j = idx & 7, l = (idx >> 3) & 63;
      int s = (idx >> 9) % 18, q = idx / 9216;
      int co = q * 16 + (l & 15);
      int kp = s * 32 + (l >> 4) * 8 + j;          // < 576
      dst[idx] = f2bf(w[(co * 64 + (kp & 63)) * 9 + (kp >> 6)]);
    } else {
      int idx = (blk - 432) * 256 + tid;
      int j = idx & 7, l = (idx >> 3) & 63;
      int s = (idx >> 9) % 36, q = idx / 18432;
      int co = q * 16 + (l & 15);
      int kp = s * 32 + (l >> 4) * 8 + j;          // < 1152
      pk_om[idx] = (co < 27)
          ? f2bf(w_om[(co * 128 + (kp & 127)) * 9 + (kp >> 7)]) : (u16)0;
    }
    return;
  }

  // ---- conv1x1y path ----
  u16* samp1 = (u16*)smem;                         // needs 9,216 B
  int lane = tid & 63, q = tid >> 6;
  int pixbase = blockIdx.x * 64;
  int hwb = pixbase & (HWv - 1);
  int b = pixbase >> 14;
  int co = q * 16 + (lane & 15);
  int g = lane >> 4;

  // w0 fragments in-register (L2-resident 16 KB table)
  bf16x8 wfrag[2];
  #pragma unroll
  for (int s = 0; s < 2; s++) {
    const float* wp = w0 + co * 64 + s * 32 + g * 8;
    u16 tw[8];
    #pragma unroll
    for (int j = 0; j < 8; j++) tw[j] = f2bf(wp[j]);
    wfrag[s] = *(bf16x8*)tw;
  }

  // ---- phase Y: transpose y for these 64 px ----
  {
    const float* src = y + (size_t)b * CCH * HWv;
    #pragma unroll
    for (int i = 0; i < 16; i++) {
      int ci = i * 4 + q;
      smem[ci * 65 + lane] = src[(size_t)ci * HWv + hwb + lane];
    }
    __syncthreads();
    u32* dst32 = (u32*)(yt + ((size_t)b * HWv + hwb) * 64);
    int lane2 = tid & 31, rr = tid >> 5;
    #pragma unroll
    for (int i = 0; i < 8; i++) {
      int row = i * 8 + rr;
      dst32[row * 32 + lane2] = f2bf2(smem[(2 * lane2) * 65 + row],
                                      smem[(2 * lane2 + 1) * 65 + row]);
    }
    __syncthreads();                               // smem dead -> reuse
  }

  // ---- phase X: conv1x1 ----
  {
    u16 tmp[16];
    #pragma unroll
    for (int i = 0; i < 16; i++) {
      int ci = q * 16 + i;
      tmp[i] = f2bf(x[((size_t)b * CCH + ci) * HWv + hwb + lane]);
    }
    #pragma unroll
    for (int i = 0; i < 2; i++)
      *(bf16x8*)(samp1 + lane * S1ROW + q * 16 + i * 8) = *(bf16x8*)(tmp + i * 8);
  }
  __syncthreads();
  f32x4 acc[4] = {{0,0,0,0},{0,0,0,0},{0,0,0,0},{0,0,0,0}};
  #pragma unroll
  for (int s = 0; s < 2; s++) {
    #pragma unroll
    for (int t = 0; t < 4; t++) {
      bf16x8 a = *(const bf16x8*)(samp1 + (t * 16 + (lane & 15)) * S1ROW + g * 8 + s * 32);
      acc[t] = __builtin_amdgcn_mfma_f32_16x16x32_bf16(a, wfrag[s], acc[t], 0, 0, 0);
    }
  }
  float bv = b0[co];
  u16* dst = x0bf + ((size_t)b * HWv + hwb + g * 4) * 64 + co;
  #pragma unroll
  for (int t = 0; t < 4; t++)
    #pragma unroll
    for (int r = 0; r < 4; r++)
      dst[(size_t)(t * 16 + r) * 64] = f2bf(acc[t][r] + bv);
}

// ==== FUSED om conv + deform conv, 2-row x 32-col tile, 512 thr ============
// XCD-swizzled blocks; single prm pass for both rows.
__global__ __launch_bounds__(512) void omd_k(const u16* __restrict__ x0bf,
    const u16* __restrict__ yt, const u16* __restrict__ pk_om,
    const u16* __restrict__ pk_dc, const float* __restrict__ b_om,
    const float* __restrict__ b_dc, u16* __restrict__ ob) {
  __shared__ __align__(16) u16 A[18688];           // 37,376 B (stage / dsamp)
  __shared__ __align__(16) int prm[576][8];        // 18,432 B (both rows)
  __shared__ __align__(16) float omv[64 * 28];     //  7,168 B   (tot 62,976)
  u32* A32 = (u32*)A;
  u32* dsamp32 = (u32*)A;
  u16* dsamp = A;
  int tid = threadIdx.x;
  int lane = tid & 63, q = tid >> 6;
  int blk = (blockIdx.x & 7) * 64 + (blockIdx.x >> 3);   // XCD swizzle (512)
  int wq = blk & 3, rp = (blk >> 2) & 63, b = blk >> 8;
  int h0 = rp * 2, wb = wq * 32;
  const u32* x0b32 = (const u32*)x0bf + (size_t)b * HWv * 32;
  const u32* yt32  = (const u32*)yt + (size_t)b * HWv * 32;

  // ---- phase 1: stage [4][34][128ch]
  {
    int lane2 = tid & 31, g16 = tid >> 5;
    int cofs = lane2 * 2;
    const u32* srcb = (lane2 < 16) ? (x0b32 + cofs) : (yt32 + cofs - 32);
    #pragma unroll
    for (int i = 0; i < 9; i++) {
      int u = g16 + 16 * i;
      if (u < 4 * TCOLS) {
        int r = u / TCOLS, c = u % TCOLS;
        int hh = h0 - 1 + r, ww = wb - 1 + c;
        uint2 v = {0u, 0u};
        if ((unsigned)hh < HH && (unsigned)ww < WWD)
          v = *(const uint2*)(srcb + (size_t)(hh * WWD + ww) * 32);
        *(uint2*)(A32 + u * (CSTR2 / 2) + cofs) = v;
      }
    }
  }
  __syncthreads();

  // ---- phase 2: om MFMA
  {
    int r = q & 1, cg = (q >> 1) & 1, cohalf = q >> 2;
    f32x4 acc = {0.f, 0.f, 0.f, 0.f};
    const bf16x8* bp = (const bf16x8*)pk_om + (size_t)(cohalf * OMKS) * 64 + lane;
    #pragma unroll
    for (int s = 0; s < OMKS; s++) {
      int kk = s >> 2;
      int addr = ((r + kk / 3) * TCOLS + cg * 16 + (lane & 15) + (kk % 3)) * CSTR2
                 + (s & 3) * 32 + (lane >> 4) * 8;
      bf16x8 a = *(const bf16x8*)(A + addr);
      acc = __builtin_amdgcn_mfma_f32_16x16x32_bf16(a, bp[(size_t)s * 64], acc, 0, 0, 0);
    }
    int co = cohalf * 16 + (lane & 15);
    if (co < 27) {
      float bv = b_om[co];
      int px = r * 32 + cg * 16 + (lane >> 4) * 4;
      #pragma unroll
      for (int j = 0; j < 4; j++)
        omv[(px + j) * 28 + co] = acc[j] + bv;
    }
  }
  __syncthreads();

  // ---- phase 3a: prm for BOTH rows (576 entries over 512 threads)
  #pragma unroll
  for (int t = 0; t < 2; t++) {
    int u = tid + 512 * t;
    if (u < 576) {
      int pl = u / KK, k = u % KK;                 // pl 0..63
      int r2 = pl >> 5, cl = pl & 31;
      const float* omp = omv + pl * 28;
      float dy = omp[2 * k], dx = omp[2 * k + 1];
      float mk = 2.f / (1.f + expf(-omp[18 + k]));
      float ys = (float)(h0 + r2 - 1 + k / 3) + dy;
      float xs = (float)(wb + cl - 1 + k % 3) + dx;
      float y0f = floorf(ys), x0f = floorf(xs);
      float ty = ys - y0f, tx = xs - x0f;
      int yi = (int)y0f, xi = (int)x0f;
      bool y0v = (unsigned)yi < HH, y1v = (unsigned)(yi + 1) < HH;
      bool x0v = (unsigned)xi < WWD, x1v = (unsigned)(xi + 1) < WWD;
      float w00 = (1.f - ty) * (1.f - tx) * mk * ((y0v && x0v) ? 1.f : 0.f);
      float w01 = (1.f - ty) * tx * mk * ((y0v && x1v) ? 1.f : 0.f);
      float w10 = ty * (1.f - tx) * mk * ((y1v && x0v) ? 1.f : 0.f);
      float w11 = ty * tx * mk * ((y1v && x1v) ? 1.f : 0.f);
      int* p = prm[u];
      // offsets in u32 units of NHWC bf16: row = 128*32, col = 32
      *(int4*)p = make_int4(min(max(yi, 0), HH - 1) * (WWD * 32),
                            min(max(yi + 1, 0), HH - 1) * (WWD * 32),
                            min(max(xi, 0), WWD - 1) * 32,
                            min(max(xi + 1, 0), WWD - 1) * 32);
      *(int4*)(p + 4) = make_int4(__float_as_int(w00), __float_as_int(w01),
                                  __float_as_int(w10), __float_as_int(w11));
    }
  }
  __syncthreads();

  // ---- phase 3b/3c: per row: gather -> MFMA -> ob
  #pragma unroll
  for (int h2 = 0; h2 < 2; h2++) {
    {
      int lane4 = tid & 15, g16 = tid >> 4;
      const u32* ytb = yt32 + lane4 * 2;
      #pragma unroll
      for (int i = 0; i < 9; i++) {
        int u = g16 + 32 * i;                      // 0..287
        int k = u % 9, pix = u / 9;
        const int* pp = prm[h2 * 288 + u];
        int4 pa = *(const int4*)pp;
        int4 pb = *(const int4*)(pp + 4);
        uint2 v00 = *(const uint2*)(ytb + pa.x + pa.z);
        uint2 v01 = *(const uint2*)(ytb + pa.x + pa.w);
        uint2 v10 = *(const uint2*)(ytb + pa.y + pa.z);
        uint2 v11 = *(const uint2*)(ytb + pa.y + pa.w);
        float w00 = __int_as_float(pb.x), w01 = __int_as_float(pb.y);
        float w10 = __int_as_float(pb.z), w11 = __int_as_float(pb.w);
        float a0 = fmaf(bfLO(v00.x), w00, fmaf(bfLO(v01.x), w01,
                   fmaf(bfLO(v10.x), w10, bfLO(v11.x) * w11)));
        float a1 = fmaf(bfHI(v00.x), w00, fmaf(bfHI(v01.x), w01,
                   fmaf(bfHI(v10.x), w10, bfHI(v11.x) * w11)));
        float a2 = fmaf(bfLO(v00.y), w00, fmaf(bfLO(v01.y), w01,
                   fmaf(bfLO(v10.y), w10, bfLO(v11.y) * w11)));
        float a3 = fmaf(bfHI(v00.y), w00, fmaf(bfHI(v01.y), w01,
                   fmaf(bfHI(v10.y), w10, bfHI(v11.y) * w11)));
        uint2 o = {f2bf2(a0, a1), f2bf2(a2, a3)};
        *(uint2*)(dsamp32 + pix * (DROW / 2) + k * 32 + lane4 * 2) = o;
      }
    }
    __syncthreads();
    {
      int qq = q & 3, pxg = q >> 2;
      f32x4 acc = {0.f, 0.f, 0.f, 0.f};
      const u16* arow = dsamp + (pxg * 16 + (lane & 15)) * DROW + (lane >> 4) * 8;
      const bf16x8* bp = (const bf16x8*)pk_dc + (size_t)(qq * KSTEP) * 64 + lane;
      #pragma unroll
      for (int s = 0; s < KSTEP; s++) {
        bf16x8 a = *(const bf16x8*)(arow + s * 32);
        acc = __builtin_amdgcn_mfma_f32_16x16x32_bf16(a, bp[(size_t)s * 64], acc, 0, 0, 0);
      }
      int co = qq * 16 + (lane & 15);
      int px = pxg * 16 + (lane >> 4) * 4;
      float bv = b_dc[co];
      size_t obase = ((size_t)b * HWv + (h0 + h2) * WWD + wb + px) * 64 + co;
      #pragma unroll
      for (int j = 0; j < 4; j++)
        ob[obase + (size_t)j * 64] =
            f2bf(acc[j] + bv + bf2f(x0bf[obase + (size_t)j * 64]));
    }
    if (h2 == 0) __syncthreads();                  // protect dsamp for row 1
  }
}

// ==== FUSED conv-w1+leaky + conv-w2+residual, 2-row x 32-col out ==========
__global__ __launch_bounds__(512) void rconv12_k(const u16* __restrict__ ob,
    const u16* __restrict__ pk_w1, const u16* __restrict__ pk_w2,
    const float* __restrict__ b1, const float* __restrict__ b2,
    float* __restrict__ outp) {
  #define R2COLS 36
  __shared__ __align__(16) u16 stage[6 * R2COLS * CSTR];  // 31,104 B
  __shared__ __align__(16) u16 zlds[144 * CSTR];          // 20,736 B
  u32* stage32 = (u32*)stage;
  int tid = threadIdx.x;
  int lane = tid & 63, q = tid >> 6;
  int blk = (blockIdx.x & 7) * 64 + (blockIdx.x >> 3);   // XCD swizzle (512)
  int wq = blk & 3, rp = (blk >> 2) & 63, b = blk >> 8;
  int h0 = rp * 2, wb = wq * 32;

  // ---- stage ob [6][36][64] bf16, uint2 copy (216 units, 32 groups)
  {
    int lane4 = tid & 15, g16 = tid >> 4;
    const u32* inb = (const u32*)ob + (size_t)b * HWv * 32 + lane4 * 2;
    #pragma unroll
    for (int i = 0; i < 7; i++) {
      int u = g16 + 32 * i;
      if (u < 6 * R2COLS) {
        int r = u / R2COLS, c = u % R2COLS;
        int hh = h0 - 2 + r, ww = wb - 2 + c;
        uint2 v = {0u, 0u};
        if ((unsigned)hh < HH && (unsigned)ww < WWD)
          v = *(const uint2*)(inb + (size_t)(hh * WWD + ww) * 32);
        *(uint2*)(stage32 + u * (CSTR / 2) + lane4 * 2) = v;
      }
    }
  }
  __syncthreads();

  // ---- conv1: z1 = leaky(w1 * ob + b1) on the [4][34]=136 px halo grid
  // z1 halo pixels OUTSIDE the image are zeroed (conv2 zero padding).
  #pragma unroll
  for (int t = 0; t < 5; t++) {
    int task = q + 8 * t;
    if (task < 36) {
      int g = task >> 2, coq = task & 3;
      int p = g * 16 + (lane & 15);
      if (p > 135) p = 135;                       // pad px clamp (group 8)
      int r1 = p / 34, c1 = p % 34;
      f32x4 acc = {0.f, 0.f, 0.f, 0.f};
      const bf16x8* bp = (const bf16x8*)pk_w1 + (size_t)(coq * KSTEP) * 64 + lane;
      #pragma unroll
      for (int s = 0; s < KSTEP; s++) {
        int kk = s >> 1;
        int addr = ((r1 + kk / 3) * R2COLS + c1 + kk % 3) * CSTR
                   + (s & 1) * 32 + (lane >> 4) * 8;
        bf16x8 a = *(const bf16x8*)(stage + addr);
        acc = __builtin_amdgcn_mfma_f32_16x16x32_bf16(a, bp[(size_t)s * 64], acc, 0, 0, 0);
      }
      int co = coq * 16 + (lane & 15);
      float bv = b1[co];
      int prow = g * 16 + (lane >> 4) * 4;
      #pragma unroll
      for (int j = 0; j < 4; j++) {
        int pp = prow + j;                        // may reach 143 (unused rows)
        int rr = pp / 34, cc = pp % 34;
        bool inimg = ((unsigned)(h0 - 1 + rr) < HH) && ((unsigned)(wb - 1 + cc) < WWD);
        float v = acc[j] + bv;
        v = v >= 0.f ? v : 0.2f * v;
        zlds[pp * CSTR + co] = inimg ? f2bf(v) : (u16)0;
      }
    }
  }
  __syncthreads();

  // ---- conv2: out = w2 * z1 + b2 + ob   (8 waves = r x cg x copair)
  int r = q & 1, cg = (q >> 1) & 1, copair = q >> 2;
  f32x4 acc2[2] = {{0,0,0,0},{0,0,0,0}};
  const bf16x8* bp2 = (const bf16x8*)pk_w2 + (size_t)(copair * 2 * KSTEP) * 64 + lane;
  #pragma unroll
  for (int s = 0; s < KSTEP; s++) {
    int kk = s >> 1;
    int p = (r + kk / 3) * 34 + cg * 16 + (lane & 15) + (kk % 3);
    int addr = p * CSTR + (s & 1) * 32 + (lane >> 4) * 8;
    bf16x8 a = *(const bf16x8*)(zlds + addr);
    acc2[0] = __builtin_amdgcn_mfma_f32_16x16x32_bf16(a, bp2[(size_t)s * 64], acc2[0], 0, 0, 0);
    acc2[1] = __builtin_amdgcn_mfma_f32_16x16x32_bf16(a, bp2[(size_t)(KSTEP + s) * 64], acc2[1], 0, 0, 0);
  }
  __syncthreads();                                 // zlds reads done -> reuse

  // ---- epilogue: +bias +residual(from stage), transpose to NCHW
  float* ot = (float*)zlds;                        // [64 co][72] f32 = 18,432 B
  int pxc = cg * 16 + (lane >> 4) * 4;             // col within 32
  #pragma unroll
  for (int t = 0; t < 2; t++) {
    int co = copair * 32 + t * 16 + (lane & 15);
    float bv = b2[co];
    #pragma unroll
    for (int j = 0; j < 4; j++) {
      int c = pxc + j;
      u16 resv = stage[((r + 2) * R2COLS + c + 2) * CSTR + co];
      ot[co * 72 + r * 36 + c] = acc2[t][j] + bv + bf2f(resv);
    }
  }
  __syncthreads();
  int co = tid >> 3, seg = tid & 7;                // 2 rows x 4 col-segments
  int r2 = seg >> 2, c8 = (seg & 3) * 8;
  const float4* src4 = (const float4*)(ot + co * 72 + r2 * 36 + c8);
  float4 v0 = src4[0], v1 = src4[1];
  float* dst = outp + ((size_t)b * CCH + co) * HWv + (h0 + r2) * WWD + wb + c8;
  *(float4*)dst = v0;
  *(float4*)(dst + 4) = v1;
}

extern "C" void kernel_launch(void* const* d_in, const int* in_sizes, int n_in,
                              void* d_out, int out_size, void* d_ws, size_t ws_size,
                              hipStream_t stream) {
  const float* x    = (const float*)d_in[0];
  const float* y    = (const float*)d_in[1];
  const float* w0   = (const float*)d_in[2];
  const float* b0   = (const float*)d_in[3];
  const float* w_om = (const float*)d_in[4];
  const float* b_om = (const float*)d_in[5];
  const float* w_dc = (const float*)d_in[6];
  const float* b_dc = (const float*)d_in[7];
  const float* w1   = (const float*)d_in[8];
  const float* b1   = (const float*)d_in[9];
  const float* w2   = (const float*)d_in[10];
  const float* b2   = (const float*)d_in[11];
  float* out = (float*)d_out;

  const size_t NFULL = (size_t)BB * CCH * HWv;   // 2,097,152
  const size_t NPACK = 4 * KSTEP * 64 * 8;       // 36,864 bf16
  u16* x0bf = (u16*)d_ws;                        // NFULL bf16
  u16* ob   = x0bf + NFULL;                      // NFULL bf16
  u16* yt   = ob + NFULL;                        // NFULL bf16
  u16* pk_dc = yt + NFULL;
  u16* pk_w1 = pk_dc + NPACK;
  u16* pk_w2 = pk_w1 + NPACK;
  u16* pk_om = pk_w2 + NPACK;

  const int NB = (int)((size_t)BB * HWv / 64);   // 512

  // 1. fused y-transpose + conv1x1 (+ weight packs in extra blocks)
  c1y_pack_k<<<NB + 576, 256, 0, stream>>>(x, y, w0, b0, w_dc, w1, w2, w_om,
                                           x0bf, yt, pk_dc, pk_w1, pk_w2, pk_om);
  // 2. fused om conv + deform conv + x0 residual -> ob (NHWC bf16)
  omd_k<<<NB, 512, 0, stream>>>(x0bf, yt, pk_om, pk_dc, b_om, b_dc, ob);
  // 3. fused conv w1 + leaky + conv w2 + residual -> out (NCHW f32)
  rconv12_k<<<NB, 512, 0, stream>>>(ob, pk_w1, pk_w2, b1, b2, out);
}